// Round 4
// baseline (585.787 us; speedup 1.0000x reference)
//
#include <hip/hip_runtime.h>
#include <hip/hip_bf16.h>
#include <cstdint>

typedef unsigned short u16;
typedef unsigned int   u32;
typedef __attribute__((ext_vector_type(8))) short bf16x8;   // 8 bf16 = 4 VGPRs
typedef __attribute__((ext_vector_type(4))) float f32x4;

#define MFMA16(a,b,c) __builtin_amdgcn_mfma_f32_16x16x32_bf16((a),(b),(c),0,0,0)

#define BSZ    4
#define SEQ    2048
#define DMODEL 1024
#define NHEAD  16
#define HDIM   64
#define MTOT   (BSZ*SEQ)   // 8192

// native conversion: compiler lowers to v_cvt_pk_bf16_f32 when paired (m240)
__device__ __forceinline__ u16 f2bf(float f) {
  __hip_bfloat16 h = __float2bfloat16(f);
  return __builtin_bit_cast(u16, h);
}

typedef __attribute__((address_space(1))) void g1v;
typedef __attribute__((address_space(3))) void l3v;
// async global->LDS, 16B/lane. LDS dest is wave-uniform base (HW adds lane*16B).
__device__ __forceinline__ void gload16(const void* g, void* l) {
  __builtin_amdgcn_global_load_lds((g1v*)(uintptr_t)g, (l3v*)(u32)(uintptr_t)l, 16, 0, 0);
}

// ---------------- pack: fp32 -> bf16 activations ----------------
__global__ void pack_act(const float* __restrict__ in, u16* __restrict__ out, int n4) {
  int i = blockIdx.x * blockDim.x + threadIdx.x;
  if (i >= n4) return;
  float4 v = ((const float4*)in)[i];
  u32 lo = (u32)f2bf(v.x) | ((u32)f2bf(v.y) << 16);
  u32 hi = (u32)f2bf(v.z) | ((u32)f2bf(v.w) << 16);
  ((uint2*)out)[i] = make_uint2(lo, hi);
}

// ---------------- pack: weights -> Bt[n][k] bf16 (transposed) ----------------
__global__ void pack_w(const float* __restrict__ src, u16* __restrict__ dst, int per_head) {
  __shared__ float tile[64][65];
  int kt = blockIdx.x * 64, nt = blockIdx.y * 64;
  int tx = threadIdx.x & 63, ty = threadIdx.x >> 6;
  for (int kk = ty; kk < 64; kk += 4) {
    int k = kt + kk, n = nt + tx;
    float v = per_head ? src[(size_t)(n >> 6) * (DMODEL * HDIM) + (size_t)k * HDIM + (n & 63)]
                       : src[(size_t)k * DMODEL + n];
    tile[kk][tx] = v;
  }
  __syncthreads();
  for (int nn = ty; nn < 64; nn += 4)
    dst[(size_t)(nt + nn) * DMODEL + kt + tx] = f2bf(tile[tx][nn]);
}

// ---------------- GEMM: C[M,N] = (A[M,K] @ Bt[N,K]^T + bias) * scale ----------------
// m97 structure: 128x128 tile, BK=32, 4 waves, global_load_lds(16B).
// EPI 0: bf16 [M][N]; 1: bf16 Vt[(b*16+h)*64+e][s]; 2: f32 [M][N]
template <int EPI>
__global__ __launch_bounds__(256, 2)
void gemm_bt(const u16* __restrict__ A, const u16* __restrict__ Bt,
             const float* __restrict__ bias, void* __restrict__ Cout, float scale)
{
  __shared__ u16 As[128 * 32];
  __shared__ u16 Bs[128 * 32];
  const int lane = threadIdx.x & 63, wid = threadIdx.x >> 6;
  const int m0 = blockIdx.y * 128, n0 = blockIdx.x * 128;

  const int srow = wid * 32 + (lane >> 2);
  const int scol = (lane & 3) * 8;
  const u16* gA = A  + (size_t)(m0 + srow) * DMODEL + scol;
  const u16* gB = Bt + (size_t)(n0 + srow) * DMODEL + scol;
  u16* lA0 = &As[(wid * 32) * 32];
  u16* lA1 = &As[(wid * 32 + 16) * 32];
  u16* lB0 = &Bs[(wid * 32) * 32];
  u16* lB1 = &Bs[(wid * 32 + 16) * 32];

  const int fr = lane & 15, quad = lane >> 4, fk = quad * 8;
  const int wr = (wid >> 1) * 64, wc = (wid & 1) * 64;

  f32x4 acc[4][4] = {};

  for (int kt = 0; kt < DMODEL / 32; ++kt) {
    __syncthreads();
    gload16(gA,               lA0);
    gload16(gA + 16 * DMODEL, lA1);
    gload16(gB,               lB0);
    gload16(gB + 16 * DMODEL, lB1);
    gA += 32; gB += 32;
    __syncthreads();

    bf16x8 af[4], bfr[4];
#pragma unroll
    for (int i = 0; i < 4; ++i) {
      af[i]  = *(const bf16x8*)&As[(wr + i * 16 + fr) * 32 + fk];
      bfr[i] = *(const bf16x8*)&Bs[(wc + i * 16 + fr) * 32 + fk];
    }
#pragma unroll
    for (int i = 0; i < 4; ++i)
#pragma unroll
      for (int j = 0; j < 4; ++j)
        acc[i][j] = MFMA16(af[i], bfr[j], acc[i][j]);
  }

  // C/D layout: col = lane&15, row = (lane>>4)*4 + reg
#pragma unroll
  for (int i = 0; i < 4; ++i) {
    int row0 = m0 + wr + i * 16 + quad * 4;
#pragma unroll
    for (int j = 0; j < 4; ++j) {
      int col = n0 + wc + j * 16 + fr;
      float bv = bias[col];
      float v0 = (acc[i][j][0] + bv) * scale, v1 = (acc[i][j][1] + bv) * scale;
      float v2 = (acc[i][j][2] + bv) * scale, v3 = (acc[i][j][3] + bv) * scale;
      if constexpr (EPI == 2) {
        float* C = (float*)Cout;
        C[(size_t)(row0 + 0) * DMODEL + col] = v0;
        C[(size_t)(row0 + 1) * DMODEL + col] = v1;
        C[(size_t)(row0 + 2) * DMODEL + col] = v2;
        C[(size_t)(row0 + 3) * DMODEL + col] = v3;
      } else if constexpr (EPI == 0) {
        u16* C = (u16*)Cout;
        C[(size_t)(row0 + 0) * DMODEL + col] = f2bf(v0);
        C[(size_t)(row0 + 1) * DMODEL + col] = f2bf(v1);
        C[(size_t)(row0 + 2) * DMODEL + col] = f2bf(v2);
        C[(size_t)(row0 + 3) * DMODEL + col] = f2bf(v3);
      } else {
        u16* C = (u16*)Cout;
        int bi = row0 >> 11, s = row0 & 2047;
        size_t vtr = ((size_t)(bi * NHEAD + (col >> 6)) * HDIM + (col & 63)) * SEQ + s;
        *(uint2*)&C[vtr] = make_uint2((u32)f2bf(v0) | ((u32)f2bf(v1) << 16),
                                      (u32)f2bf(v2) | ((u32)f2bf(v3) << 16));
      }
    }
  }
}

// ---------------- flash attention v4 ----------------
// grid flattened (SEQ/128 * B*H) = 1024 blocks, XCD-swizzled (head's K/V stays in one
// XCD's L2); exactly one residency round at 4 blocks/CU (40 KB LDS).
// 4 waves/block; wave owns 32 q-rows as two 16-row MFMA fragments sharing the K/V
// LDS tiles (fixed per-step costs amortized 2x). KVBLK=64, double-buffered
// global_load_lds staging with 16B-chunk XOR swizzle. Q pre-scaled by 0.125*log2e;
// exp2-domain softmax; T13 defer-max; per-lane partial row-sums reduced once at end.
// P handoff per fragment through an 8KB/wave LDS tile (same-wave DS ops are in-order).
__global__ __launch_bounds__(256, 4)
void attn_kernel(const u16* __restrict__ Q, const u16* __restrict__ K,
                 const u16* __restrict__ Vt, u16* __restrict__ O, int causal)
{
  __shared__ u16 Ks[2][64 * 64];   // [key][dim], swizzled
  __shared__ u16 Vs[2][64 * 64];   // [d][s_local], swizzled
  __shared__ u16 plds[4][16 * 64]; // per-wave P [q][key], swizzled, reused per fragment
  const int lane = threadIdx.x & 63, wid = threadIdx.x >> 6;
  const int fr = lane & 15, quad = lane >> 4;

  // flat = [bh_hi:3][qb:4][xcd:3]; per XCD: 16 q-blocks of one head, heavy-first.
  const int flat = blockIdx.x;
  const int bh = ((flat >> 7) << 3) | (flat & 7);
  const int qb = 15 - ((flat >> 3) & 15);
  const int b = bh >> 4, h = bh & 15;
  const int q0 = qb * 128;
  const int qw = q0 + wid * 32;

  bf16x8 aq[2][2];
#pragma unroll
  for (int g = 0; g < 2; ++g) {
    const u16* qp = Q + (size_t)(b * SEQ + qw + g * 16 + fr) * DMODEL + h * HDIM + quad * 8;
    aq[g][0] = *(const bf16x8*)qp;
    aq[g][1] = *(const bf16x8*)(qp + 32);
  }

  const int srow = wid * 16 + (lane >> 3);  // + i*8
  const int jl = lane & 7;
  const u16* kg = K + (size_t)b * SEQ * DMODEL + h * HDIM;
  const u16* vg = Vt + (size_t)bh * HDIM * SEQ;

  f32x4 oacc[2][4] = {};
  f32x4 sa[2][4];
  float mrow[2][4]  = {{-1e30f, -1e30f, -1e30f, -1e30f}, {-1e30f, -1e30f, -1e30f, -1e30f}};
  float lpart[2][4] = {};

  const int nsteps = (causal ? (q0 + 128) : SEQ) >> 6;

#pragma unroll
  for (int i = 0; i < 2; ++i) {
    int r2 = srow + i * 8;
    int jg = jl ^ (r2 & 7);
    gload16(kg + (size_t)r2 * DMODEL + jg * 8, &Ks[0][(wid * 16 + i * 8) * 64]);
    gload16(vg + (size_t)r2 * SEQ + jg * 8,    &Vs[0][(wid * 16 + i * 8) * 64]);
  }
  __syncthreads();

  for (int t = 0; t < nsteps; ++t) {
    const int cur = t & 1;
    const int kb = t * 64;
    if (t + 1 < nsteps) {
      const int kb2 = kb + 64;
#pragma unroll
      for (int i = 0; i < 2; ++i) {
        int r2 = srow + i * 8;
        int jg = jl ^ (r2 & 7);
        gload16(kg + (size_t)(kb2 + r2) * DMODEL + jg * 8, &Ks[cur ^ 1][(wid * 16 + i * 8) * 64]);
        gload16(vg + (size_t)r2 * SEQ + kb2 + jg * 8,      &Vs[cur ^ 1][(wid * 16 + i * 8) * 64]);
      }
    }
    // QK^T: S[32q][64key], K-fragments shared by both q-fragments
    __builtin_amdgcn_s_setprio(1);
#pragma unroll
    for (int nb = 0; nb < 4; ++nb) {
      int key = nb * 16 + fr;
      const u16* kr = &Ks[cur][key * 64];
      bf16x8 k0 = *(const bf16x8*)&kr[((quad    ) ^ (key & 7)) * 8];
      bf16x8 k1 = *(const bf16x8*)&kr[((quad + 4) ^ (key & 7)) * 8];
      f32x4 s0 = {};
      s0 = MFMA16(aq[0][0], k0, s0);
      s0 = MFMA16(aq[0][1], k1, s0);
      sa[0][nb] = s0;
      f32x4 s1 = {};
      s1 = MFMA16(aq[1][0], k0, s1);
      s1 = MFMA16(aq[1][1], k1, s1);
      sa[1][nb] = s1;
    }
    __builtin_amdgcn_s_setprio(0);
    if (causal && kb + 64 > qw) {      // wave-uniform; diagonal blocks only
#pragma unroll
      for (int nb = 0; nb < 4; ++nb) {
        int col = kb + nb * 16 + fr;
#pragma unroll
        for (int r = 0; r < 4; ++r) {
          if (col > qw + quad * 4 + r)      sa[0][nb][r] = -1e30f;
          if (col > qw + 16 + quad * 4 + r) sa[1][nb][r] = -1e30f;
        }
      }
    }

    // ---- defer-max check over both fragments ----
    float lm[2][4];
#pragma unroll
    for (int g = 0; g < 2; ++g)
#pragma unroll
      for (int r = 0; r < 4; ++r)
        lm[g][r] = fmaxf(fmaxf(sa[g][0][r], sa[g][1][r]), fmaxf(sa[g][2][r], sa[g][3][r]));
    int ok = 1;
#pragma unroll
    for (int g = 0; g < 2; ++g)
#pragma unroll
      for (int r = 0; r < 4; ++r)
        ok &= (lm[g][r] <= mrow[g][r] + 11.f);
    if (!__all(ok)) {
#pragma unroll
      for (int g = 0; g < 2; ++g)
#pragma unroll
        for (int r = 0; r < 4; ++r) {
          float mx = lm[g][r];
          mx = fmaxf(mx, __shfl_xor(mx, 1));
          mx = fmaxf(mx, __shfl_xor(mx, 2));
          mx = fmaxf(mx, __shfl_xor(mx, 4));
          mx = fmaxf(mx, __shfl_xor(mx, 8));
          float mnew = fmaxf(mrow[g][r], mx);
          float a = __builtin_amdgcn_exp2f(mrow[g][r] - mnew);
          mrow[g][r] = mnew;
          lpart[g][r] *= a;
          oacc[g][0][r] *= a; oacc[g][1][r] *= a;
          oacc[g][2][r] *= a; oacc[g][3][r] *= a;
        }
    }

    // ---- per fragment: exp2 + P-write + PV (plds reused; same-wave DS in-order) ----
#pragma unroll
    for (int g = 0; g < 2; ++g) {
#pragma unroll
      for (int r = 0; r < 4; ++r) {
        float p0 = __builtin_amdgcn_exp2f(sa[g][0][r] - mrow[g][r]);
        float p1 = __builtin_amdgcn_exp2f(sa[g][1][r] - mrow[g][r]);
        float p2 = __builtin_amdgcn_exp2f(sa[g][2][r] - mrow[g][r]);
        float p3 = __builtin_amdgcn_exp2f(sa[g][3][r] - mrow[g][r]);
        lpart[g][r] += (p0 + p1) + (p2 + p3);
        int row = quad * 4 + r;
        u16* pr = &plds[wid][row * 64];
        pr[(((fr >> 3)    ) ^ (row & 7)) * 8 + (fr & 7)] = f2bf(p0);
        pr[(((fr >> 3) + 2) ^ (row & 7)) * 8 + (fr & 7)] = f2bf(p1);
        pr[(((fr >> 3) + 4) ^ (row & 7)) * 8 + (fr & 7)] = f2bf(p2);
        pr[(((fr >> 3) + 6) ^ (row & 7)) * 8 + (fr & 7)] = f2bf(p3);
      }
      asm volatile("s_waitcnt lgkmcnt(0)" ::: "memory");
      bf16x8 pa0 = *(const bf16x8*)&plds[wid][fr * 64 + ((quad    ) ^ (fr & 7)) * 8];
      bf16x8 pa1 = *(const bf16x8*)&plds[wid][fr * 64 + ((quad + 4) ^ (fr & 7)) * 8];
      __builtin_amdgcn_s_setprio(1);
#pragma unroll
      for (int db = 0; db < 4; ++db) {
        int d = db * 16 + fr;
        const u16* vr = &Vs[cur][d * 64];
        bf16x8 v0 = *(const bf16x8*)&vr[((quad    ) ^ (d & 7)) * 8];
        bf16x8 v1 = *(const bf16x8*)&vr[((quad + 4) ^ (d & 7)) * 8];
        oacc[g][db] = MFMA16(pa0, v0, oacc[g][db]);
        oacc[g][db] = MFMA16(pa1, v1, oacc[g][db]);
      }
      __builtin_amdgcn_s_setprio(0);
    }
    __syncthreads();   // buf[cur] reads done; buf[cur^1] staging drained
  }

#pragma unroll
  for (int g = 0; g < 2; ++g) {
    u16* op = O + (size_t)(b * SEQ + qw + g * 16 + quad * 4) * DMODEL + h * HDIM + fr;
#pragma unroll
    for (int r = 0; r < 4; ++r) {
      float s = lpart[g][r];
      s += __shfl_xor(s, 1);
      s += __shfl_xor(s, 2);
      s += __shfl_xor(s, 4);
      s += __shfl_xor(s, 8);
      float inv = 1.0f / s;
#pragma unroll
      for (int db = 0; db < 4; ++db)
        op[(size_t)r * DMODEL + db * 16] = f2bf(oacc[g][db][r] * inv);
    }
  }
}

// ---------------- launcher ----------------
extern "C" void kernel_launch(void* const* d_in, const int* in_sizes, int n_in,
                              void* d_out, int out_size, void* d_ws, size_t ws_size,
                              hipStream_t stream)
{
  const float* x   = (const float*)d_in[0];
  const float* ek  = (const float*)d_in[1];
  const float* ev  = (const float*)d_in[2];
  const float* Wq1 = (const float*)d_in[3];
  const float* bq1 = (const float*)d_in[4];
  const float* Wk1 = (const float*)d_in[5];
  const float* bk1 = (const float*)d_in[6];
  const float* Wv1 = (const float*)d_in[7];
  const float* bv1 = (const float*)d_in[8];
  const float* Wo1 = (const float*)d_in[9];
  const float* bo1 = (const float*)d_in[10];
  const float* Wq2 = (const float*)d_in[11];
  const float* bq2 = (const float*)d_in[12];
  const float* Wk2 = (const float*)d_in[13];
  const float* bk2 = (const float*)d_in[14];
  const float* Wv2 = (const float*)d_in[15];
  const float* bv2 = (const float*)d_in[16];
  const float* Wo2 = (const float*)d_in[17];
  const float* bo2 = (const float*)d_in[18];

  char* ws = (char*)d_ws;
  u16* wt  = (u16*)ws;
  u16* xb  = (u16*)(ws + (16u << 20));
  u16* ekb = (u16*)(ws + (32u << 20));
  u16* evb = (u16*)(ws + (48u << 20));
  u16* qb  = (u16*)(ws + (64u << 20));
  u16* kkb = (u16*)(ws + (80u << 20));
  u16* vtb = (u16*)(ws + (96u << 20));
  u16* hb  = (u16*)(ws + (112u << 20));
  u16* ob  = xb;   // x dead after layer-1 projections

  const int NW = DMODEL * DMODEL;
  const int n4 = MTOT * DMODEL / 4;
  const float qscale = 0.125f * 1.4426950408889634f;   // 1/sqrt(HD) * log2(e)

  pack_act<<<n4 / 256, 256, 0, stream>>>(x,  xb,  n4);
  pack_act<<<n4 / 256, 256, 0, stream>>>(ek, ekb, n4);
  pack_act<<<n4 / 256, 256, 0, stream>>>(ev, evb, n4);

  dim3 wg(16, 16);
  pack_w<<<wg, 256, 0, stream>>>(Wq1, wt + 0 * NW, 1);
  pack_w<<<wg, 256, 0, stream>>>(Wk1, wt + 1 * NW, 1);
  pack_w<<<wg, 256, 0, stream>>>(Wv1, wt + 2 * NW, 1);
  pack_w<<<wg, 256, 0, stream>>>(Wo1, wt + 3 * NW, 0);
  pack_w<<<wg, 256, 0, stream>>>(Wq2, wt + 4 * NW, 1);
  pack_w<<<wg, 256, 0, stream>>>(Wk2, wt + 5 * NW, 1);
  pack_w<<<wg, 256, 0, stream>>>(Wv2, wt + 6 * NW, 1);
  pack_w<<<wg, 256, 0, stream>>>(Wo2, wt + 7 * NW, 0);

  dim3 gg(DMODEL / 128, MTOT / 128);
  const int ablocks = (SEQ / 128) * BSZ * NHEAD;   // 1024, flattened + swizzled

  // layer 1: causal self-attention
  gemm_bt<0><<<gg, 256, 0, stream>>>(xb,  wt + 0 * NW, bq1, qb,  qscale);
  gemm_bt<0><<<gg, 256, 0, stream>>>(xb,  wt + 1 * NW, bk1, kkb, 1.0f);
  gemm_bt<1><<<gg, 256, 0, stream>>>(xb,  wt + 2 * NW, bv1, vtb, 1.0f);
  attn_kernel<<<ablocks, 256, 0, stream>>>(qb, kkb, vtb, ob, 1);
  gemm_bt<0><<<gg, 256, 0, stream>>>(ob,  wt + 3 * NW, bo1, hb,  1.0f);

  // layer 2: cross attention
  gemm_bt<0><<<gg, 256, 0, stream>>>(hb,  wt + 4 * NW, bq2, qb,  qscale);
  gemm_bt<0><<<gg, 256, 0, stream>>>(ekb, wt + 5 * NW, bk2, kkb, 1.0f);
  gemm_bt<1><<<gg, 256, 0, stream>>>(evb, wt + 6 * NW, bv2, vtb, 1.0f);
  attn_kernel<<<ablocks, 256, 0, stream>>>(qb, kkb, vtb, ob, 0);
  gemm_bt<2><<<gg, 256, 0, stream>>>(ob,  wt + 7 * NW, bo2, d_out, 1.0f);
}

// Round 5
// 488.916 us; speedup vs baseline: 1.1981x; 1.1981x over previous
//
#include <hip/hip_runtime.h>
#include <hip/hip_bf16.h>
#include <cstdint>

typedef unsigned short u16;
typedef unsigned int   u32;
typedef __attribute__((ext_vector_type(8))) short bf16x8;   // 8 bf16 = 4 VGPRs
typedef __attribute__((ext_vector_type(4))) float f32x4;

#define MFMA16(a,b,c) __builtin_amdgcn_mfma_f32_16x16x32_bf16((a),(b),(c),0,0,0)

#define BSZ    4
#define SEQ    2048
#define DMODEL 1024
#define NHEAD  16
#define HDIM   64
#define MTOT   (BSZ*SEQ)   // 8192

// native conversion: compiler lowers to v_cvt_pk_bf16_f32 when paired (m240)
__device__ __forceinline__ u16 f2bf(float f) {
  __hip_bfloat16 h = __float2bfloat16(f);
  return __builtin_bit_cast(u16, h);
}

typedef __attribute__((address_space(1))) void g1v;
typedef __attribute__((address_space(3))) void l3v;
// async global->LDS, 16B/lane. LDS dest is wave-uniform base (HW adds lane*16B).
__device__ __forceinline__ void gload16(const void* g, void* l) {
  __builtin_amdgcn_global_load_lds((g1v*)(uintptr_t)g, (l3v*)(u32)(uintptr_t)l, 16, 0, 0);
}

// ---------------- pack: fp32 -> bf16 activations ----------------
__global__ void pack_act(const float* __restrict__ in, u16* __restrict__ out, int n4) {
  int i = blockIdx.x * blockDim.x + threadIdx.x;
  if (i >= n4) return;
  float4 v = ((const float4*)in)[i];
  u32 lo = (u32)f2bf(v.x) | ((u32)f2bf(v.y) << 16);
  u32 hi = (u32)f2bf(v.z) | ((u32)f2bf(v.w) << 16);
  ((uint2*)out)[i] = make_uint2(lo, hi);
}

// ---------------- pack: weights -> Bt[n][k] bf16 (transposed) ----------------
__global__ void pack_w(const float* __restrict__ src, u16* __restrict__ dst, int per_head) {
  __shared__ float tile[64][65];
  int kt = blockIdx.x * 64, nt = blockIdx.y * 64;
  int tx = threadIdx.x & 63, ty = threadIdx.x >> 6;
  for (int kk = ty; kk < 64; kk += 4) {
    int k = kt + kk, n = nt + tx;
    float v = per_head ? src[(size_t)(n >> 6) * (DMODEL * HDIM) + (size_t)k * HDIM + (n & 63)]
                       : src[(size_t)k * DMODEL + n];
    tile[kk][tx] = v;
  }
  __syncthreads();
  for (int nn = ty; nn < 64; nn += 4)
    dst[(size_t)(nt + nn) * DMODEL + kt + tx] = f2bf(tile[tx][nn]);
}

// ---------------- GEMM: C[M,N] = (A[M,K] @ Bt[N,K]^T + bias) * scale ----------------
// m97 structure: 128x128 tile, BK=32, 4 waves, global_load_lds(16B).
// EPI 0: bf16 [M][N]; 1: bf16 Vt[(b*16+h)*64+e][s]; 2: f32 [M][N]
template <int EPI>
__global__ __launch_bounds__(256, 2)
void gemm_bt(const u16* __restrict__ A, const u16* __restrict__ Bt,
             const float* __restrict__ bias, void* __restrict__ Cout, float scale)
{
  __shared__ u16 As[128 * 32];
  __shared__ u16 Bs[128 * 32];
  const int lane = threadIdx.x & 63, wid = threadIdx.x >> 6;
  const int m0 = blockIdx.y * 128, n0 = blockIdx.x * 128;

  const int srow = wid * 32 + (lane >> 2);
  const int scol = (lane & 3) * 8;
  const u16* gA = A  + (size_t)(m0 + srow) * DMODEL + scol;
  const u16* gB = Bt + (size_t)(n0 + srow) * DMODEL + scol;
  u16* lA0 = &As[(wid * 32) * 32];
  u16* lA1 = &As[(wid * 32 + 16) * 32];
  u16* lB0 = &Bs[(wid * 32) * 32];
  u16* lB1 = &Bs[(wid * 32 + 16) * 32];

  const int fr = lane & 15, quad = lane >> 4, fk = quad * 8;
  const int wr = (wid >> 1) * 64, wc = (wid & 1) * 64;

  f32x4 acc[4][4] = {};

  for (int kt = 0; kt < DMODEL / 32; ++kt) {
    __syncthreads();
    gload16(gA,               lA0);
    gload16(gA + 16 * DMODEL, lA1);
    gload16(gB,               lB0);
    gload16(gB + 16 * DMODEL, lB1);
    gA += 32; gB += 32;
    __syncthreads();

    bf16x8 af[4], bfr[4];
#pragma unroll
    for (int i = 0; i < 4; ++i) {
      af[i]  = *(const bf16x8*)&As[(wr + i * 16 + fr) * 32 + fk];
      bfr[i] = *(const bf16x8*)&Bs[(wc + i * 16 + fr) * 32 + fk];
    }
#pragma unroll
    for (int i = 0; i < 4; ++i)
#pragma unroll
      for (int j = 0; j < 4; ++j)
        acc[i][j] = MFMA16(af[i], bfr[j], acc[i][j]);
  }

  // C/D layout: col = lane&15, row = (lane>>4)*4 + reg
#pragma unroll
  for (int i = 0; i < 4; ++i) {
    int row0 = m0 + wr + i * 16 + quad * 4;
#pragma unroll
    for (int j = 0; j < 4; ++j) {
      int col = n0 + wc + j * 16 + fr;
      float bv = bias[col];
      float v0 = (acc[i][j][0] + bv) * scale, v1 = (acc[i][j][1] + bv) * scale;
      float v2 = (acc[i][j][2] + bv) * scale, v3 = (acc[i][j][3] + bv) * scale;
      if constexpr (EPI == 2) {
        float* C = (float*)Cout;
        C[(size_t)(row0 + 0) * DMODEL + col] = v0;
        C[(size_t)(row0 + 1) * DMODEL + col] = v1;
        C[(size_t)(row0 + 2) * DMODEL + col] = v2;
        C[(size_t)(row0 + 3) * DMODEL + col] = v3;
      } else if constexpr (EPI == 0) {
        u16* C = (u16*)Cout;
        C[(size_t)(row0 + 0) * DMODEL + col] = f2bf(v0);
        C[(size_t)(row0 + 1) * DMODEL + col] = f2bf(v1);
        C[(size_t)(row0 + 2) * DMODEL + col] = f2bf(v2);
        C[(size_t)(row0 + 3) * DMODEL + col] = f2bf(v3);
      } else {
        u16* C = (u16*)Cout;
        int bi = row0 >> 11, s = row0 & 2047;
        size_t vtr = ((size_t)(bi * NHEAD + (col >> 6)) * HDIM + (col & 63)) * SEQ + s;
        *(uint2*)&C[vtr] = make_uint2((u32)f2bf(v0) | ((u32)f2bf(v1) << 16),
                                      (u32)f2bf(v2) | ((u32)f2bf(v3) << 16));
      }
    }
  }
}

// ---------------- flash attention v5 ----------------
// 1024 blocks = exactly one residency round at 4 blocks/CU (40 KB LDS).
// Each block processes TWO complementary 64-row q-tiles sequentially:
// qb = {31-pair, pair}. Causal => every block runs exactly 33 K-steps (perfect
// balance; was 1..32 variable => ~2x makespan loss). Cross => uniform 64 steps.
// XCD swizzle: flat = [bh_hi:3][pair:4][xcd:3]; a head's K/V panel stays in one
// XCD's L2. Per wave: 16 q-rows. KVBLK=64, double-buffered global_load_lds with
// 16B-chunk XOR swizzle. Q pre-scaled by 0.125*log2e; exp2-domain softmax;
// T13 defer-max; per-lane partial row-sums reduced once per tile at the end.
__global__ __launch_bounds__(256, 4)
void attn_kernel(const u16* __restrict__ Q, const u16* __restrict__ K,
                 const u16* __restrict__ Vt, u16* __restrict__ O, int causal)
{
  __shared__ u16 Ks[2][64 * 64];   // [key][dim], swizzled
  __shared__ u16 Vs[2][64 * 64];   // [d][s_local], swizzled
  __shared__ u16 plds[4][16 * 64]; // per-wave P [q][key], swizzled
  const int lane = threadIdx.x & 63, wid = threadIdx.x >> 6;
  const int fr = lane & 15, quad = lane >> 4;

  const int flat = blockIdx.x;
  const int bh = ((flat >> 7) << 3) | (flat & 7);
  const int pair = (flat >> 3) & 15;
  const int b = bh >> 4, h = bh & 15;

  const int srow = wid * 16 + (lane >> 3);  // + i*8
  const int jl = lane & 7;
  const u16* kg = K + (size_t)b * SEQ * DMODEL + h * HDIM;
  const u16* vg = Vt + (size_t)bh * HDIM * SEQ;

  for (int tile = 0; tile < 2; ++tile) {
    const int qb = tile == 0 ? (31 - pair) : pair;
    const int q0 = qb * 64;
    const int qw = q0 + wid * 16;

    const u16* qp = Q + (size_t)(b * SEQ + qw + fr) * DMODEL + h * HDIM + quad * 8;
    bf16x8 aq0 = *(const bf16x8*)qp;
    bf16x8 aq1 = *(const bf16x8*)(qp + 32);

    f32x4 oacc[4] = {};
    f32x4 sa[4];
    float mrow[4]  = {-1e30f, -1e30f, -1e30f, -1e30f};
    float lpart[4] = {0.f, 0.f, 0.f, 0.f};

    const int nsteps = (causal ? (q0 + 64) : SEQ) >> 6;

#pragma unroll
    for (int i = 0; i < 2; ++i) {
      int r2 = srow + i * 8;
      int jg = jl ^ (r2 & 7);
      gload16(kg + (size_t)r2 * DMODEL + jg * 8, &Ks[0][(wid * 16 + i * 8) * 64]);
      gload16(vg + (size_t)r2 * SEQ + jg * 8,    &Vs[0][(wid * 16 + i * 8) * 64]);
    }
    __syncthreads();

    for (int t = 0; t < nsteps; ++t) {
      const int cur = t & 1;
      const int kb = t * 64;
      if (t + 1 < nsteps) {
        const int kb2 = kb + 64;
#pragma unroll
        for (int i = 0; i < 2; ++i) {
          int r2 = srow + i * 8;
          int jg = jl ^ (r2 & 7);
          gload16(kg + (size_t)(kb2 + r2) * DMODEL + jg * 8, &Ks[cur ^ 1][(wid * 16 + i * 8) * 64]);
          gload16(vg + (size_t)r2 * SEQ + kb2 + jg * 8,      &Vs[cur ^ 1][(wid * 16 + i * 8) * 64]);
        }
      }
      // QK^T: S[16q][64key]
      __builtin_amdgcn_s_setprio(1);
#pragma unroll
      for (int nb = 0; nb < 4; ++nb) {
        int key = nb * 16 + fr;
        const u16* kr = &Ks[cur][key * 64];
        bf16x8 k0 = *(const bf16x8*)&kr[((quad    ) ^ (key & 7)) * 8];
        bf16x8 k1 = *(const bf16x8*)&kr[((quad + 4) ^ (key & 7)) * 8];
        f32x4 s = {};
        s = MFMA16(aq0, k0, s);
        s = MFMA16(aq1, k1, s);
        sa[nb] = s;
      }
      __builtin_amdgcn_s_setprio(0);
      if (causal && kb + 64 > qw) {      // wave-uniform; diagonal blocks only
#pragma unroll
        for (int nb = 0; nb < 4; ++nb) {
          int col = kb + nb * 16 + fr;
#pragma unroll
          for (int r = 0; r < 4; ++r)
            if (col > qw + quad * 4 + r) sa[nb][r] = -1e30f;
        }
      }

      // ---- softmax: defer-max fast path ----
      float lm[4];
#pragma unroll
      for (int r = 0; r < 4; ++r)
        lm[r] = fmaxf(fmaxf(sa[0][r], sa[1][r]), fmaxf(sa[2][r], sa[3][r]));
      int ok = (lm[0] <= mrow[0] + 11.f) & (lm[1] <= mrow[1] + 11.f) &
               (lm[2] <= mrow[2] + 11.f) & (lm[3] <= mrow[3] + 11.f);
      if (!__all(ok)) {
#pragma unroll
        for (int r = 0; r < 4; ++r) {
          float mx = lm[r];
          mx = fmaxf(mx, __shfl_xor(mx, 1));
          mx = fmaxf(mx, __shfl_xor(mx, 2));
          mx = fmaxf(mx, __shfl_xor(mx, 4));
          mx = fmaxf(mx, __shfl_xor(mx, 8));
          float mnew = fmaxf(mrow[r], mx);
          float a = __builtin_amdgcn_exp2f(mrow[r] - mnew);
          mrow[r] = mnew;
          lpart[r] *= a;
          oacc[0][r] *= a; oacc[1][r] *= a; oacc[2][r] *= a; oacc[3][r] *= a;
        }
      }
#pragma unroll
      for (int r = 0; r < 4; ++r) {
        float p0 = __builtin_amdgcn_exp2f(sa[0][r] - mrow[r]);
        float p1 = __builtin_amdgcn_exp2f(sa[1][r] - mrow[r]);
        float p2 = __builtin_amdgcn_exp2f(sa[2][r] - mrow[r]);
        float p3 = __builtin_amdgcn_exp2f(sa[3][r] - mrow[r]);
        lpart[r] += (p0 + p1) + (p2 + p3);
        int row = quad * 4 + r;
        u16* pr = &plds[wid][row * 64];
        pr[(((fr >> 3)    ) ^ (row & 7)) * 8 + (fr & 7)] = f2bf(p0);
        pr[(((fr >> 3) + 2) ^ (row & 7)) * 8 + (fr & 7)] = f2bf(p1);
        pr[(((fr >> 3) + 4) ^ (row & 7)) * 8 + (fr & 7)] = f2bf(p2);
        pr[(((fr >> 3) + 6) ^ (row & 7)) * 8 + (fr & 7)] = f2bf(p3);
      }
      asm volatile("s_waitcnt lgkmcnt(0)" ::: "memory");
      bf16x8 pa0 = *(const bf16x8*)&plds[wid][fr * 64 + ((quad    ) ^ (fr & 7)) * 8];
      bf16x8 pa1 = *(const bf16x8*)&plds[wid][fr * 64 + ((quad + 4) ^ (fr & 7)) * 8];
      __builtin_amdgcn_s_setprio(1);
#pragma unroll
      for (int db = 0; db < 4; ++db) {
        int d = db * 16 + fr;
        const u16* vr = &Vs[cur][d * 64];
        bf16x8 v0 = *(const bf16x8*)&vr[((quad    ) ^ (d & 7)) * 8];
        bf16x8 v1 = *(const bf16x8*)&vr[((quad + 4) ^ (d & 7)) * 8];
        oacc[db] = MFMA16(pa0, v0, oacc[db]);
        oacc[db] = MFMA16(pa1, v1, oacc[db]);
      }
      __builtin_amdgcn_s_setprio(0);
      __syncthreads();   // buf[cur] reads done; buf[cur^1] staging drained
    }

    u16* op = O + (size_t)(b * SEQ + qw + quad * 4) * DMODEL + h * HDIM + fr;
#pragma unroll
    for (int r = 0; r < 4; ++r) {
      float s = lpart[r];
      s += __shfl_xor(s, 1);
      s += __shfl_xor(s, 2);
      s += __shfl_xor(s, 4);
      s += __shfl_xor(s, 8);
      float inv = 1.0f / s;
#pragma unroll
      for (int db = 0; db < 4; ++db)
        op[(size_t)r * DMODEL + db * 16] = f2bf(oacc[db][r] * inv);
    }
    // next tile's prologue staging is safe: all LDS reads of this tile were
    // fenced by the final in-loop __syncthreads; epilogue touches no LDS.
  }
}

// ---------------- launcher ----------------
extern "C" void kernel_launch(void* const* d_in, const int* in_sizes, int n_in,
                              void* d_out, int out_size, void* d_ws, size_t ws_size,
                              hipStream_t stream)
{
  const float* x   = (const float*)d_in[0];
  const float* ek  = (const float*)d_in[1];
  const float* ev  = (const float*)d_in[2];
  const float* Wq1 = (const float*)d_in[3];
  const float* bq1 = (const float*)d_in[4];
  const float* Wk1 = (const float*)d_in[5];
  const float* bk1 = (const float*)d_in[6];
  const float* Wv1 = (const float*)d_in[7];
  const float* bv1 = (const float*)d_in[8];
  const float* Wo1 = (const float*)d_in[9];
  const float* bo1 = (const float*)d_in[10];
  const float* Wq2 = (const float*)d_in[11];
  const float* bq2 = (const float*)d_in[12];
  const float* Wk2 = (const float*)d_in[13];
  const float* bk2 = (const float*)d_in[14];
  const float* Wv2 = (const float*)d_in[15];
  const float* bv2 = (const float*)d_in[16];
  const float* Wo2 = (const float*)d_in[17];
  const float* bo2 = (const float*)d_in[18];

  char* ws = (char*)d_ws;
  u16* wt  = (u16*)ws;
  u16* xb  = (u16*)(ws + (16u << 20));
  u16* ekb = (u16*)(ws + (32u << 20));
  u16* evb = (u16*)(ws + (48u << 20));
  u16* qb  = (u16*)(ws + (64u << 20));
  u16* kkb = (u16*)(ws + (80u << 20));
  u16* vtb = (u16*)(ws + (96u << 20));
  u16* hb  = (u16*)(ws + (112u << 20));
  u16* ob  = xb;   // x dead after layer-1 projections

  const int NW = DMODEL * DMODEL;
  const int n4 = MTOT * DMODEL / 4;
  const float qscale = 0.125f * 1.4426950408889634f;   // 1/sqrt(HD) * log2(e)

  pack_act<<<n4 / 256, 256, 0, stream>>>(x,  xb,  n4);
  pack_act<<<n4 / 256, 256, 0, stream>>>(ek, ekb, n4);
  pack_act<<<n4 / 256, 256, 0, stream>>>(ev, evb, n4);

  dim3 wg(16, 16);
  pack_w<<<wg, 256, 0, stream>>>(Wq1, wt + 0 * NW, 1);
  pack_w<<<wg, 256, 0, stream>>>(Wk1, wt + 1 * NW, 1);
  pack_w<<<wg, 256, 0, stream>>>(Wv1, wt + 2 * NW, 1);
  pack_w<<<wg, 256, 0, stream>>>(Wo1, wt + 3 * NW, 0);
  pack_w<<<wg, 256, 0, stream>>>(Wq2, wt + 4 * NW, 1);
  pack_w<<<wg, 256, 0, stream>>>(Wk2, wt + 5 * NW, 1);
  pack_w<<<wg, 256, 0, stream>>>(Wv2, wt + 6 * NW, 1);
  pack_w<<<wg, 256, 0, stream>>>(Wo2, wt + 7 * NW, 0);

  dim3 gg(DMODEL / 128, MTOT / 128);
  const int ablocks = (SEQ / 128) * BSZ * NHEAD;   // 1024: pair-blocks, XCD-swizzled

  // layer 1: causal self-attention
  gemm_bt<0><<<gg, 256, 0, stream>>>(xb,  wt + 0 * NW, bq1, qb,  qscale);
  gemm_bt<0><<<gg, 256, 0, stream>>>(xb,  wt + 1 * NW, bk1, kkb, 1.0f);
  gemm_bt<1><<<gg, 256, 0, stream>>>(xb,  wt + 2 * NW, bv1, vtb, 1.0f);
  attn_kernel<<<ablocks, 256, 0, stream>>>(qb, kkb, vtb, ob, 1);
  gemm_bt<0><<<gg, 256, 0, stream>>>(ob,  wt + 3 * NW, bo1, hb,  1.0f);

  // layer 2: cross attention
  gemm_bt<0><<<gg, 256, 0, stream>>>(hb,  wt + 4 * NW, bq2, qb,  qscale);
  gemm_bt<0><<<gg, 256, 0, stream>>>(ekb, wt + 5 * NW, bk2, kkb, 1.0f);
  gemm_bt<1><<<gg, 256, 0, stream>>>(evb, wt + 6 * NW, bv2, vtb, 1.0f);
  attn_kernel<<<ablocks, 256, 0, stream>>>(qb, kkb, vtb, ob, 0);
  gemm_bt<2><<<gg, 256, 0, stream>>>(ob,  wt + 7 * NW, bo2, d_out, 1.0f);
}

// Round 6
// 476.442 us; speedup vs baseline: 1.2295x; 1.0262x over previous
//
#include <hip/hip_runtime.h>
#include <hip/hip_bf16.h>
#include <cstdint>

typedef unsigned short u16;
typedef unsigned int   u32;
typedef __attribute__((ext_vector_type(8))) short bf16x8;   // 8 bf16 = 4 VGPRs
typedef __attribute__((ext_vector_type(4))) short bf16x4;   // 4 bf16 = 2 VGPRs
typedef __attribute__((ext_vector_type(4))) float f32x4;

#define MFMA16(a,b,c)    __builtin_amdgcn_mfma_f32_16x16x32_bf16((a),(b),(c),0,0,0)
#define MFMA16K16(a,b,c) __builtin_amdgcn_mfma_f32_16x16x16bf16_1k((a),(b),(c),0,0,0)

#define BSZ    4
#define SEQ    2048
#define DMODEL 1024
#define NHEAD  16
#define HDIM   64
#define MTOT   (BSZ*SEQ)   // 8192
#define MASKV  (-3.0e38f)  // finite: exp2(MASKV - m) == 0, no inf-inf NaN

// native conversion: compiler lowers to v_cvt_pk_bf16_f32 when paired (m240)
__device__ __forceinline__ u16 f2bf(float f) {
  __hip_bfloat16 h = __float2bfloat16(f);
  return __builtin_bit_cast(u16, h);
}

typedef __attribute__((address_space(1))) void g1v;
typedef __attribute__((address_space(3))) void l3v;
// async global->LDS, 16B/lane. LDS dest is wave-uniform base (HW adds lane*16B).
__device__ __forceinline__ void gload16(const void* g, void* l) {
  __builtin_amdgcn_global_load_lds((g1v*)(uintptr_t)g, (l3v*)(u32)(uintptr_t)l, 16, 0, 0);
}

// ---------------- pack: fp32 -> bf16 activations ----------------
__global__ void pack_act(const float* __restrict__ in, u16* __restrict__ out, int n4) {
  int i = blockIdx.x * blockDim.x + threadIdx.x;
  if (i >= n4) return;
  float4 v = ((const float4*)in)[i];
  u32 lo = (u32)f2bf(v.x) | ((u32)f2bf(v.y) << 16);
  u32 hi = (u32)f2bf(v.z) | ((u32)f2bf(v.w) << 16);
  ((uint2*)out)[i] = make_uint2(lo, hi);
}

// ---------------- pack: weights -> Bt[n][k] bf16 (transposed) ----------------
__global__ void pack_w(const float* __restrict__ src, u16* __restrict__ dst, int per_head) {
  __shared__ float tile[64][65];
  int kt = blockIdx.x * 64, nt = blockIdx.y * 64;
  int tx = threadIdx.x & 63, ty = threadIdx.x >> 6;
  for (int kk = ty; kk < 64; kk += 4) {
    int k = kt + kk, n = nt + tx;
    float v = per_head ? src[(size_t)(n >> 6) * (DMODEL * HDIM) + (size_t)k * HDIM + (n & 63)]
                       : src[(size_t)k * DMODEL + n];
    tile[kk][tx] = v;
  }
  __syncthreads();
  for (int nn = ty; nn < 64; nn += 4)
    dst[(size_t)(nt + nn) * DMODEL + kt + tx] = f2bf(tile[tx][nn]);
}

// ---------------- GEMM: C[M,N] = (A[M,K] @ Bt[N,K]^T + bias) * scale ----------------
template <int EPI>
__global__ __launch_bounds__(256, 2)
void gemm_bt(const u16* __restrict__ A, const u16* __restrict__ Bt,
             const float* __restrict__ bias, void* __restrict__ Cout, float scale)
{
  __shared__ u16 As[128 * 32];
  __shared__ u16 Bs[128 * 32];
  const int lane = threadIdx.x & 63, wid = threadIdx.x >> 6;
  const int m0 = blockIdx.y * 128, n0 = blockIdx.x * 128;

  const int srow = wid * 32 + (lane >> 2);
  const int scol = (lane & 3) * 8;
  const u16* gA = A  + (size_t)(m0 + srow) * DMODEL + scol;
  const u16* gB = Bt + (size_t)(n0 + srow) * DMODEL + scol;
  u16* lA0 = &As[(wid * 32) * 32];
  u16* lA1 = &As[(wid * 32 + 16) * 32];
  u16* lB0 = &Bs[(wid * 32) * 32];
  u16* lB1 = &Bs[(wid * 32 + 16) * 32];

  const int fr = lane & 15, quad = lane >> 4, fk = quad * 8;
  const int wr = (wid >> 1) * 64, wc = (wid & 1) * 64;

  f32x4 acc[4][4] = {};

  for (int kt = 0; kt < DMODEL / 32; ++kt) {
    __syncthreads();
    gload16(gA,               lA0);
    gload16(gA + 16 * DMODEL, lA1);
    gload16(gB,               lB0);
    gload16(gB + 16 * DMODEL, lB1);
    gA += 32; gB += 32;
    __syncthreads();

    bf16x8 af[4], bfr[4];
#pragma unroll
    for (int i = 0; i < 4; ++i) {
      af[i]  = *(const bf16x8*)&As[(wr + i * 16 + fr) * 32 + fk];
      bfr[i] = *(const bf16x8*)&Bs[(wc + i * 16 + fr) * 32 + fk];
    }
#pragma unroll
    for (int i = 0; i < 4; ++i)
#pragma unroll
      for (int j = 0; j < 4; ++j)
        acc[i][j] = MFMA16(af[i], bfr[j], acc[i][j]);
  }

#pragma unroll
  for (int i = 0; i < 4; ++i) {
    int row0 = m0 + wr + i * 16 + quad * 4;
#pragma unroll
    for (int j = 0; j < 4; ++j) {
      int col = n0 + wc + j * 16 + fr;
      float bv = bias[col];
      float v0 = (acc[i][j][0] + bv) * scale, v1 = (acc[i][j][1] + bv) * scale;
      float v2 = (acc[i][j][2] + bv) * scale, v3 = (acc[i][j][3] + bv) * scale;
      if constexpr (EPI == 2) {
        float* C = (float*)Cout;
        C[(size_t)(row0 + 0) * DMODEL + col] = v0;
        C[(size_t)(row0 + 1) * DMODEL + col] = v1;
        C[(size_t)(row0 + 2) * DMODEL + col] = v2;
        C[(size_t)(row0 + 3) * DMODEL + col] = v3;
      } else if constexpr (EPI == 0) {
        u16* C = (u16*)Cout;
        C[(size_t)(row0 + 0) * DMODEL + col] = f2bf(v0);
        C[(size_t)(row0 + 1) * DMODEL + col] = f2bf(v1);
        C[(size_t)(row0 + 2) * DMODEL + col] = f2bf(v2);
        C[(size_t)(row0 + 3) * DMODEL + col] = f2bf(v3);
      } else {
        u16* C = (u16*)Cout;
        int bi = row0 >> 11, s = row0 & 2047;
        size_t vtr = ((size_t)(bi * NHEAD + (col >> 6)) * HDIM + (col & 63)) * SEQ + s;
        *(uint2*)&C[vtr] = make_uint2((u32)f2bf(v0) | ((u32)f2bf(v1) << 16),
                                      (u32)f2bf(v2) | ((u32)f2bf(v3) << 16));
      }
    }
  }
}

// ---------------- flash attention v6: split-K waves, zero-shuffle P ----------------
// 1024 blocks (pairing: qb {31-pair, pair} => causal = uniform 33 steps/block).
// Waves 2x2 (wq x wk): wave owns 32 q-rows x 32 keys of each 64-key step.
// Swapped QK^T (S^T = mfma(K,Q)) puts P^T[key=quad*4+r][q=fr] in regs = exact
// A-frag of mfma_16x16x16bf16_1k => PV straight from registers, no P-LDS.
// LDS/block-step: 32KB vs 72KB before (was the measured BW ceiling).
// 2-way split-K merge (m,l,O) once per tile through freed K-buffer LDS.
__global__ __launch_bounds__(256, 4)
void attn_kernel(const u16* __restrict__ Q, const u16* __restrict__ K,
                 const u16* __restrict__ Vt, u16* __restrict__ O, int causal)
{
  __shared__ u16 KV[4][64 * 64];   // [0,1]=K dbuf, [2,3]=V dbuf; merge reuses as f32
  const int lane = threadIdx.x & 63, wid = threadIdx.x >> 6;
  const int fr = lane & 15, quad = lane >> 4;
  const int wq = wid >> 1, wk = wid & 1;

  const int flat = blockIdx.x;
  const int bh = ((flat >> 7) << 3) | (flat & 7);
  const int pair = (flat >> 3) & 15;
  const int b = bh >> 4, h = bh & 15;

  const int srow = wid * 16 + (lane >> 3);  // staging rows, + i*8
  const int jl = lane & 7;
  const u16* kg = K + (size_t)b * SEQ * DMODEL + h * HDIM;
  const u16* vg = Vt + (size_t)bh * HDIM * SEQ;
  float* mbuf = (float*)&KV[0][0];          // 2*64*50*4 = 25.6KB <= 32KB (K bufs)

  for (int tile = 0; tile < 2; ++tile) {
    const int qb = tile == 0 ? (31 - pair) : pair;
    const int q0 = qb * 64;
    const int qbase = q0 + wq * 32;

    // Q B-frags: lane holds Q[q=qbase+nb*16+fr][dim=quad*8+j (+32*half)]
    bf16x8 aq[2][2];
#pragma unroll
    for (int nb = 0; nb < 2; ++nb) {
      const u16* qp = Q + (size_t)(b * SEQ + qbase + nb * 16 + fr) * DMODEL + h * HDIM + quad * 8;
      aq[nb][0] = *(const bf16x8*)qp;
      aq[nb][1] = *(const bf16x8*)(qp + 32);
    }

    f32x4 oacc[2][4] = {};
    float mrow[2] = {-1e30f, -1e30f};
    float lp[2]   = {0.f, 0.f};

    const int nsteps = (causal ? (q0 + 64) : SEQ) >> 6;

#pragma unroll
    for (int i = 0; i < 2; ++i) {
      int r2 = srow + i * 8;
      int jg = jl ^ (r2 & 7);
      gload16(kg + (size_t)r2 * DMODEL + jg * 8, &KV[0][(wid * 16 + i * 8) * 64]);
      gload16(vg + (size_t)r2 * SEQ + jg * 8,    &KV[2][(wid * 16 + i * 8) * 64]);
    }
    __syncthreads();

    for (int t = 0; t < nsteps; ++t) {
      const int cur = t & 1;
      const int kb = t * 64;
      if (t + 1 < nsteps) {
        const int kb2 = kb + 64;
#pragma unroll
        for (int i = 0; i < 2; ++i) {
          int r2 = srow + i * 8;
          int jg = jl ^ (r2 & 7);
          gload16(kg + (size_t)(kb2 + r2) * DMODEL + jg * 8, &KV[cur ^ 1][(wid * 16 + i * 8) * 64]);
          gload16(vg + (size_t)r2 * SEQ + kb2 + jg * 8,      &KV[2 + (cur ^ 1)][(wid * 16 + i * 8) * 64]);
        }
      }
      // K A-frags: wave's 32 keys = 2 blocks of 16; A[key=fr][dim=quad*8+j]
      const u16* kr0 = &KV[cur][(wk * 32 + fr) * 64];
      const u16* kr1 = &KV[cur][(wk * 32 + 16 + fr) * 64];
      bf16x8 kf00 = *(const bf16x8*)&kr0[((quad    ) ^ (fr & 7)) * 8];
      bf16x8 kf01 = *(const bf16x8*)&kr0[((quad + 4) ^ (fr & 7)) * 8];
      bf16x8 kf10 = *(const bf16x8*)&kr1[((quad    ) ^ (fr & 7)) * 8];
      bf16x8 kf11 = *(const bf16x8*)&kr1[((quad + 4) ^ (fr & 7)) * 8];

      // swapped QK^T: sa[kblk][nb][r] = S[key=kb+wk*32+kblk*16+quad*4+r][q=qbase+nb*16+fr]
      f32x4 sa[2][2];
      __builtin_amdgcn_s_setprio(1);
#pragma unroll
      for (int nb = 0; nb < 2; ++nb) {
        f32x4 s0 = {};
        s0 = MFMA16(kf00, aq[nb][0], s0);
        s0 = MFMA16(kf01, aq[nb][1], s0);
        sa[0][nb] = s0;
        f32x4 s1 = {};
        s1 = MFMA16(kf10, aq[nb][0], s1);
        s1 = MFMA16(kf11, aq[nb][1], s1);
        sa[1][nb] = s1;
      }
      __builtin_amdgcn_s_setprio(0);

      if (causal && kb + wk * 32 + 31 > qbase) {   // wave-uniform diagonal check
#pragma unroll
        for (int kblk = 0; kblk < 2; ++kblk)
#pragma unroll
          for (int nb = 0; nb < 2; ++nb) {
            int key = kb + wk * 32 + kblk * 16 + quad * 4;
            int q   = qbase + nb * 16 + fr;
#pragma unroll
            for (int r = 0; r < 4; ++r)
              if (key + r > q) sa[kblk][nb][r] = MASKV;
          }
      }

      // ---- defer-max softmax (lane-local partials over its 8 keys per q) ----
      float lm[2];
#pragma unroll
      for (int nb = 0; nb < 2; ++nb) {
        f32x4 mx4 = sa[0][nb];
        mx4[0] = fmaxf(mx4[0], sa[1][nb][0]); mx4[1] = fmaxf(mx4[1], sa[1][nb][1]);
        mx4[2] = fmaxf(mx4[2], sa[1][nb][2]); mx4[3] = fmaxf(mx4[3], sa[1][nb][3]);
        lm[nb] = fmaxf(fmaxf(mx4[0], mx4[1]), fmaxf(mx4[2], mx4[3]));
      }
      int ok = (lm[0] <= mrow[0] + 11.f) & (lm[1] <= mrow[1] + 11.f);
      if (!__all(ok)) {
#pragma unroll
        for (int nb = 0; nb < 2; ++nb) {
          float mx = lm[nb];
          mx = fmaxf(mx, __shfl_xor(mx, 16));
          mx = fmaxf(mx, __shfl_xor(mx, 32));   // wave-consistent max across quads
          float mnew = fmaxf(mrow[nb], mx);
          float a = __builtin_amdgcn_exp2f(mrow[nb] - mnew);
          mrow[nb] = mnew;
          lp[nb] *= a;
          // oacc rows q=nb*16+quad*4+r need a from state-lane fr'=quad*4+r
#pragma unroll
          for (int r = 0; r < 4; ++r) {
            float ar = __shfl(a, (lane & 48) | (quad * 4 + r));
            oacc[nb][0][r] *= ar; oacc[nb][1][r] *= ar;
            oacc[nb][2][r] *= ar; oacc[nb][3][r] *= ar;
          }
        }
      }

      // exp2 + pack P^T straight into K=16 A-frags (no LDS, no shuffles)
      bf16x4 pa[2][2];
#pragma unroll
      for (int kblk = 0; kblk < 2; ++kblk)
#pragma unroll
        for (int nb = 0; nb < 2; ++nb) {
          float p0 = __builtin_amdgcn_exp2f(sa[kblk][nb][0] - mrow[nb]);
          float p1 = __builtin_amdgcn_exp2f(sa[kblk][nb][1] - mrow[nb]);
          float p2 = __builtin_amdgcn_exp2f(sa[kblk][nb][2] - mrow[nb]);
          float p3 = __builtin_amdgcn_exp2f(sa[kblk][nb][3] - mrow[nb]);
          lp[nb] += (p0 + p1) + (p2 + p3);
          bf16x4 pk;
          pk[0] = (short)f2bf(p0); pk[1] = (short)f2bf(p1);
          pk[2] = (short)f2bf(p2); pk[3] = (short)f2bf(p3);
          pa[kblk][nb] = pk;
        }

      // PV: B-frag V[key=quad*4+j][d=db*16+fr] as b64 from swizzled Vt tile
      const int vcb = wk * 4 + (quad >> 1);
      const int vwi = (quad & 1) * 4;
      __builtin_amdgcn_s_setprio(1);
#pragma unroll
      for (int db = 0; db < 4; ++db) {
        const u16* vr = &KV[2 + cur][(db * 16 + fr) * 64];
        bf16x4 v0 = *(const bf16x4*)&vr[(((vcb    ) ^ (fr & 7)) * 8) + vwi];
        bf16x4 v1 = *(const bf16x4*)&vr[(((vcb + 2) ^ (fr & 7)) * 8) + vwi];
        oacc[0][db] = MFMA16K16(pa[0][0], v0, oacc[0][db]);
        oacc[0][db] = MFMA16K16(pa[1][0], v1, oacc[0][db]);
        oacc[1][db] = MFMA16K16(pa[0][1], v0, oacc[1][db]);
        oacc[1][db] = MFMA16K16(pa[1][1], v1, oacc[1][db]);
      }
      __builtin_amdgcn_s_setprio(0);
      __syncthreads();   // buf[cur] reads done; buf[cur^1] staging drained
    }

    // ---- tile epilogue: finalize within wave, 2-way split-K merge across wk ----
#pragma unroll
    for (int nb = 0; nb < 2; ++nb) {
      lp[nb] += __shfl_xor(lp[nb], 16);
      lp[nb] += __shfl_xor(lp[nb], 32);
    }
    float mr2[2][4], lr2[2][4];
#pragma unroll
    for (int nb = 0; nb < 2; ++nb)
#pragma unroll
      for (int r = 0; r < 4; ++r) {
        int src = (lane & 48) | (quad * 4 + r);
        mr2[nb][r] = __shfl(mrow[nb], src);
        lr2[nb][r] = __shfl(lp[nb],   src);
      }
    float* mp = mbuf + (size_t)(wq * 64 + lane) * 50;
    if (wk) {
#pragma unroll
      for (int nb = 0; nb < 2; ++nb)
#pragma unroll
        for (int db = 0; db < 4; ++db) {
          *(float2*)&mp[(nb * 4 + db) * 4 + 0] = make_float2(oacc[nb][db][0], oacc[nb][db][1]);
          *(float2*)&mp[(nb * 4 + db) * 4 + 2] = make_float2(oacc[nb][db][2], oacc[nb][db][3]);
        }
#pragma unroll
      for (int nb = 0; nb < 2; ++nb) {
        *(float2*)&mp[32 + nb * 4 + 0] = make_float2(mr2[nb][0], mr2[nb][1]);
        *(float2*)&mp[32 + nb * 4 + 2] = make_float2(mr2[nb][2], mr2[nb][3]);
        *(float2*)&mp[40 + nb * 4 + 0] = make_float2(lr2[nb][0], lr2[nb][1]);
        *(float2*)&mp[40 + nb * 4 + 2] = make_float2(lr2[nb][2], lr2[nb][3]);
      }
    }
    __syncthreads();
    if (!wk) {
      float w0[2][4], w1[2][4];
#pragma unroll
      for (int nb = 0; nb < 2; ++nb)
#pragma unroll
        for (int r = 0; r < 4; ++r) {
          float m1 = mp[32 + nb * 4 + r];
          float l1 = mp[40 + nb * 4 + r];
          float M  = fmaxf(mr2[nb][r], m1);
          float c0 = __builtin_amdgcn_exp2f(mr2[nb][r] - M);
          float c1 = __builtin_amdgcn_exp2f(m1 - M);
          float inv = 1.0f / (lr2[nb][r] * c0 + l1 * c1);
          w0[nb][r] = c0 * inv;
          w1[nb][r] = c1 * inv;
        }
#pragma unroll
      for (int nb = 0; nb < 2; ++nb) {
        u16* op = O + (size_t)(b * SEQ + qbase + nb * 16 + quad * 4) * DMODEL + h * HDIM + fr;
#pragma unroll
        for (int db = 0; db < 4; ++db) {
          float2 oa = *(float2*)&mp[(nb * 4 + db) * 4 + 0];
          float2 ob = *(float2*)&mp[(nb * 4 + db) * 4 + 2];
          float o1[4] = {oa.x, oa.y, ob.x, ob.y};
#pragma unroll
          for (int r = 0; r < 4; ++r)
            op[(size_t)r * DMODEL + db * 16] =
                f2bf(oacc[nb][db][r] * w0[nb][r] + o1[r] * w1[nb][r]);
        }
      }
    }
    __syncthreads();   // merge reads done before next tile's staging reuses KV
  }
}

// ---------------- launcher ----------------
extern "C" void kernel_launch(void* const* d_in, const int* in_sizes, int n_in,
                              void* d_out, int out_size, void* d_ws, size_t ws_size,
                              hipStream_t stream)
{
  const float* x   = (const float*)d_in[0];
  const float* ek  = (const float*)d_in[1];
  const float* ev  = (const float*)d_in[2];
  const float* Wq1 = (const float*)d_in[3];
  const float* bq1 = (const float*)d_in[4];
  const float* Wk1 = (const float*)d_in[5];
  const float* bk1 = (const float*)d_in[6];
  const float* Wv1 = (const float*)d_in[7];
  const float* bv1 = (const float*)d_in[8];
  const float* Wo1 = (const float*)d_in[9];
  const float* bo1 = (const float*)d_in[10];
  const float* Wq2 = (const float*)d_in[11];
  const float* bq2 = (const float*)d_in[12];
  const float* Wk2 = (const float*)d_in[13];
  const float* bk2 = (const float*)d_in[14];
  const float* Wv2 = (const float*)d_in[15];
  const float* bv2 = (const float*)d_in[16];
  const float* Wo2 = (const float*)d_in[17];
  const float* bo2 = (const float*)d_in[18];

  char* ws = (char*)d_ws;
  u16* wt  = (u16*)ws;
  u16* xb  = (u16*)(ws + (16u << 20));
  u16* ekb = (u16*)(ws + (32u << 20));
  u16* evb = (u16*)(ws + (48u << 20));
  u16* qb  = (u16*)(ws + (64u << 20));
  u16* kkb = (u16*)(ws + (80u << 20));
  u16* vtb = (u16*)(ws + (96u << 20));
  u16* hb  = (u16*)(ws + (112u << 20));
  u16* ob  = xb;   // x dead after layer-1 projections

  const int NW = DMODEL * DMODEL;
  const int n4 = MTOT * DMODEL / 4;
  const float qscale = 0.125f * 1.4426950408889634f;   // 1/sqrt(HD) * log2(e)

  pack_act<<<n4 / 256, 256, 0, stream>>>(x,  xb,  n4);
  pack_act<<<n4 / 256, 256, 0, stream>>>(ek, ekb, n4);
  pack_act<<<n4 / 256, 256, 0, stream>>>(ev, evb, n4);

  dim3 wg(16, 16);
  pack_w<<<wg, 256, 0, stream>>>(Wq1, wt + 0 * NW, 1);
  pack_w<<<wg, 256, 0, stream>>>(Wk1, wt + 1 * NW, 1);
  pack_w<<<wg, 256, 0, stream>>>(Wv1, wt + 2 * NW, 1);
  pack_w<<<wg, 256, 0, stream>>>(Wo1, wt + 3 * NW, 0);
  pack_w<<<wg, 256, 0, stream>>>(Wq2, wt + 4 * NW, 1);
  pack_w<<<wg, 256, 0, stream>>>(Wk2, wt + 5 * NW, 1);
  pack_w<<<wg, 256, 0, stream>>>(Wv2, wt + 6 * NW, 1);
  pack_w<<<wg, 256, 0, stream>>>(Wo2, wt + 7 * NW, 0);

  dim3 gg(DMODEL / 128, MTOT / 128);
  const int ablocks = (SEQ / 128) * BSZ * NHEAD;   // 1024 pair-blocks, XCD-swizzled

  // layer 1: causal self-attention
  gemm_bt<0><<<gg, 256, 0, stream>>>(xb,  wt + 0 * NW, bq1, qb,  qscale);
  gemm_bt<0><<<gg, 256, 0, stream>>>(xb,  wt + 1 * NW, bk1, kkb, 1.0f);
  gemm_bt<1><<<gg, 256, 0, stream>>>(xb,  wt + 2 * NW, bv1, vtb, 1.0f);
  attn_kernel<<<ablocks, 256, 0, stream>>>(qb, kkb, vtb, ob, 1);
  gemm_bt<0><<<gg, 256, 0, stream>>>(ob,  wt + 3 * NW, bo1, hb,  1.0f);

  // layer 2: cross attention
  gemm_bt<0><<<gg, 256, 0, stream>>>(hb,  wt + 4 * NW, bq2, qb,  qscale);
  gemm_bt<0><<<gg, 256, 0, stream>>>(ekb, wt + 5 * NW, bk2, kkb, 1.0f);
  gemm_bt<1><<<gg, 256, 0, stream>>>(evb, wt + 6 * NW, bv2, vtb, 1.0f);
  attn_kernel<<<ablocks, 256, 0, stream>>>(qb, kkb, vtb, ob, 0);
  gemm_bt<2><<<gg, 256, 0, stream>>>(ob,  wt + 7 * NW, bo2, d_out, 1.0f);
}

// Round 7
// 456.618 us; speedup vs baseline: 1.2829x; 1.0434x over previous
//
#include <hip/hip_runtime.h>
#include <hip/hip_bf16.h>
#include <cstdint>

typedef unsigned short u16;
typedef unsigned int   u32;
typedef __attribute__((ext_vector_type(8))) short bf16x8;   // 8 bf16 = 4 VGPRs
typedef __attribute__((ext_vector_type(4))) short bf16x4;   // 4 bf16 = 2 VGPRs
typedef __attribute__((ext_vector_type(4))) float f32x4;

#define MFMA16(a,b,c)    __builtin_amdgcn_mfma_f32_16x16x32_bf16((a),(b),(c),0,0,0)
#define MFMA16K16(a,b,c) __builtin_amdgcn_mfma_f32_16x16x16bf16_1k((a),(b),(c),0,0,0)

#define BSZ    4
#define SEQ    2048
#define DMODEL 1024
#define NHEAD  16
#define HDIM   64
#define MTOT   (BSZ*SEQ)   // 8192
#define MASKV  (-3.0e38f)  // finite: exp2(MASKV - m) == 0, no inf-inf NaN

// native conversion: compiler lowers to v_cvt_pk_bf16_f32 when paired (m240)
__device__ __forceinline__ u16 f2bf(float f) {
  __hip_bfloat16 h = __float2bfloat16(f);
  return __builtin_bit_cast(u16, h);
}

typedef __attribute__((address_space(1))) void g1v;
typedef __attribute__((address_space(3))) void l3v;
// async global->LDS, 16B/lane. LDS dest is wave-uniform base (HW adds lane*16B).
__device__ __forceinline__ void gload16(const void* g, void* l) {
  __builtin_amdgcn_global_load_lds((g1v*)(uintptr_t)g, (l3v*)(u32)(uintptr_t)l, 16, 0, 0);
}

// ---------------- pack: fp32 -> bf16 activations ----------------
__global__ void pack_act(const float* __restrict__ in, u16* __restrict__ out, int n4) {
  int i = blockIdx.x * blockDim.x + threadIdx.x;
  if (i >= n4) return;
  float4 v = ((const float4*)in)[i];
  u32 lo = (u32)f2bf(v.x) | ((u32)f2bf(v.y) << 16);
  u32 hi = (u32)f2bf(v.z) | ((u32)f2bf(v.w) << 16);
  ((uint2*)out)[i] = make_uint2(lo, hi);
}

// ---------------- pack: weights -> Bt[n][k] bf16 (transposed) ----------------
__global__ void pack_w(const float* __restrict__ src, u16* __restrict__ dst, int per_head) {
  __shared__ float tile[64][65];
  int kt = blockIdx.x * 64, nt = blockIdx.y * 64;
  int tx = threadIdx.x & 63, ty = threadIdx.x >> 6;
  for (int kk = ty; kk < 64; kk += 4) {
    int k = kt + kk, n = nt + tx;
    float v = per_head ? src[(size_t)(n >> 6) * (DMODEL * HDIM) + (size_t)k * HDIM + (n & 63)]
                       : src[(size_t)k * DMODEL + n];
    tile[kk][tx] = v;
  }
  __syncthreads();
  for (int nn = ty; nn < 64; nn += 4)
    dst[(size_t)(nt + nn) * DMODEL + kt + tx] = f2bf(tile[tx][nn]);
}

// ---------------- GEMM: C[M,N] = (A[M,K] @ Bt[N,K]^T + bias) * scale ----------------
// m97 structure, 1D grid with XCD swizzle: each XCD owns 8 contiguous m-tiles
// x all 8 n-tiles (A-panel 2MB + Bt 2MB L2-resident per XCD).
template <int EPI>
__global__ __launch_bounds__(256, 2)
void gemm_bt(const u16* __restrict__ A, const u16* __restrict__ Bt,
             const float* __restrict__ bias, void* __restrict__ Cout, float scale)
{
  __shared__ u16 As[128 * 32];
  __shared__ u16 Bs[128 * 32];
  const int lane = threadIdx.x & 63, wid = threadIdx.x >> 6;
  const int wg = ((blockIdx.x & 7) << 6) | (blockIdx.x >> 3);  // [xcd:3][seq:6]
  const int m0 = (wg >> 3) * 128, n0 = (wg & 7) * 128;

  const int srow = wid * 32 + (lane >> 2);
  const int scol = (lane & 3) * 8;
  const u16* gA = A  + (size_t)(m0 + srow) * DMODEL + scol;
  const u16* gB = Bt + (size_t)(n0 + srow) * DMODEL + scol;
  u16* lA0 = &As[(wid * 32) * 32];
  u16* lA1 = &As[(wid * 32 + 16) * 32];
  u16* lB0 = &Bs[(wid * 32) * 32];
  u16* lB1 = &Bs[(wid * 32 + 16) * 32];

  const int fr = lane & 15, quad = lane >> 4, fk = quad * 8;
  const int wr = (wid >> 1) * 64, wc = (wid & 1) * 64;

  f32x4 acc[4][4] = {};

  for (int kt = 0; kt < DMODEL / 32; ++kt) {
    __syncthreads();
    gload16(gA,               lA0);
    gload16(gA + 16 * DMODEL, lA1);
    gload16(gB,               lB0);
    gload16(gB + 16 * DMODEL, lB1);
    gA += 32; gB += 32;
    __syncthreads();

    bf16x8 af[4], bfr[4];
#pragma unroll
    for (int i = 0; i < 4; ++i) {
      af[i]  = *(const bf16x8*)&As[(wr + i * 16 + fr) * 32 + fk];
      bfr[i] = *(const bf16x8*)&Bs[(wc + i * 16 + fr) * 32 + fk];
    }
#pragma unroll
    for (int i = 0; i < 4; ++i)
#pragma unroll
      for (int j = 0; j < 4; ++j)
        acc[i][j] = MFMA16(af[i], bfr[j], acc[i][j]);
  }

#pragma unroll
  for (int i = 0; i < 4; ++i) {
    int row0 = m0 + wr + i * 16 + quad * 4;
#pragma unroll
    for (int j = 0; j < 4; ++j) {
      int col = n0 + wc + j * 16 + fr;
      float bv = bias[col];
      float v0 = (acc[i][j][0] + bv) * scale, v1 = (acc[i][j][1] + bv) * scale;
      float v2 = (acc[i][j][2] + bv) * scale, v3 = (acc[i][j][3] + bv) * scale;
      if constexpr (EPI == 2) {
        float* C = (float*)Cout;
        C[(size_t)(row0 + 0) * DMODEL + col] = v0;
        C[(size_t)(row0 + 1) * DMODEL + col] = v1;
        C[(size_t)(row0 + 2) * DMODEL + col] = v2;
        C[(size_t)(row0 + 3) * DMODEL + col] = v3;
      } else if constexpr (EPI == 0) {
        u16* C = (u16*)Cout;
        C[(size_t)(row0 + 0) * DMODEL + col] = f2bf(v0);
        C[(size_t)(row0 + 1) * DMODEL + col] = f2bf(v1);
        C[(size_t)(row0 + 2) * DMODEL + col] = f2bf(v2);
        C[(size_t)(row0 + 3) * DMODEL + col] = f2bf(v3);
      } else {
        u16* C = (u16*)Cout;
        int bi = row0 >> 11, s = row0 & 2047;
        size_t vtr = ((size_t)(bi * NHEAD + (col >> 6)) * HDIM + (col & 63)) * SEQ + s;
        *(uint2*)&C[vtr] = make_uint2((u32)f2bf(v0) | ((u32)f2bf(v1) << 16),
                                      (u32)f2bf(v2) | ((u32)f2bf(v3) << 16));
      }
    }
  }
}

// ---------------- flash attention v7: v6 + unroll-by-2 (compile-time cur) ----------------
// Split-K waves 2x2 (wq x wk), swapped QK^T, zero-shuffle P into K=16 PV.
// Unrolled steps make every LDS address loop-invariant (hoisted); staging uses
// running global pointers. 1024 pair-blocks (causal = uniform 33 steps), XCD-swizzled.

#define ATTN_STEP(CUR, TT)                                                      \
  do {                                                                          \
    const int kb_ = (TT) * 64;                                                  \
    if ((TT) + 1 < nsteps) {                                                    \
      gload16(kpre0, &KV[(CUR) ^ 1][(wid * 16 + 0) * 64]);                      \
      gload16(kpre1, &KV[(CUR) ^ 1][(wid * 16 + 8) * 64]);                      \
      gload16(vpre0, &KV[2 + ((CUR) ^ 1)][(wid * 16 + 0) * 64]);                \
      gload16(vpre1, &KV[2 + ((CUR) ^ 1)][(wid * 16 + 8) * 64]);                \
      kpre0 += 64 * DMODEL; kpre1 += 64 * DMODEL; vpre0 += 64; vpre1 += 64;     \
    }                                                                           \
    const u16* kr0_ = &KV[(CUR)][(wk * 32 + fr) * 64];                          \
    const u16* kr1_ = kr0_ + 16 * 64;                                           \
    bf16x8 kf00 = *(const bf16x8*)&kr0_[xk0];                                   \
    bf16x8 kf01 = *(const bf16x8*)&kr0_[xk1];                                   \
    bf16x8 kf10 = *(const bf16x8*)&kr1_[xk0];                                   \
    bf16x8 kf11 = *(const bf16x8*)&kr1_[xk1];                                   \
    f32x4 sa[2][2];                                                             \
    __builtin_amdgcn_s_setprio(1);                                              \
    _Pragma("unroll")                                                           \
    for (int nb = 0; nb < 2; ++nb) {                                            \
      f32x4 s0 = {};                                                            \
      s0 = MFMA16(kf00, aq[nb][0], s0);                                         \
      s0 = MFMA16(kf01, aq[nb][1], s0);                                         \
      sa[0][nb] = s0;                                                           \
      f32x4 s1 = {};                                                            \
      s1 = MFMA16(kf10, aq[nb][0], s1);                                         \
      s1 = MFMA16(kf11, aq[nb][1], s1);                                         \
      sa[1][nb] = s1;                                                           \
    }                                                                           \
    __builtin_amdgcn_s_setprio(0);                                              \
    if (causal && kb_ + wk * 32 + 31 > qbase) {                                 \
      _Pragma("unroll")                                                         \
      for (int kblk = 0; kblk < 2; ++kblk)                                      \
        _Pragma("unroll")                                                       \
        for (int nb = 0; nb < 2; ++nb) {                                        \
          int key = kb_ + wk * 32 + kblk * 16 + quad * 4;                       \
          int q   = qbase + nb * 16 + fr;                                       \
          _Pragma("unroll")                                                     \
          for (int r = 0; r < 4; ++r)                                           \
            if (key + r > q) sa[kblk][nb][r] = MASKV;                           \
        }                                                                       \
    }                                                                           \
    float lm[2];                                                                \
    _Pragma("unroll")                                                           \
    for (int nb = 0; nb < 2; ++nb) {                                            \
      f32x4 mx4 = sa[0][nb];                                                    \
      mx4[0] = fmaxf(mx4[0], sa[1][nb][0]); mx4[1] = fmaxf(mx4[1], sa[1][nb][1]);\
      mx4[2] = fmaxf(mx4[2], sa[1][nb][2]); mx4[3] = fmaxf(mx4[3], sa[1][nb][3]);\
      lm[nb] = fmaxf(fmaxf(mx4[0], mx4[1]), fmaxf(mx4[2], mx4[3]));             \
    }                                                                           \
    int ok = (lm[0] <= mrow[0] + 11.f) & (lm[1] <= mrow[1] + 11.f);             \
    if (!__all(ok)) {                                                           \
      _Pragma("unroll")                                                         \
      for (int nb = 0; nb < 2; ++nb) {                                          \
        float mx = lm[nb];                                                      \
        mx = fmaxf(mx, __shfl_xor(mx, 16));                                     \
        mx = fmaxf(mx, __shfl_xor(mx, 32));                                     \
        float mnew = fmaxf(mrow[nb], mx);                                       \
        float a = __builtin_amdgcn_exp2f(mrow[nb] - mnew);                      \
        mrow[nb] = mnew;                                                        \
        lp[nb] *= a;                                                            \
        _Pragma("unroll")                                                       \
        for (int r = 0; r < 4; ++r) {                                           \
          float ar = __shfl(a, (lane & 48) | (quad * 4 + r));                   \
          oacc[nb][0][r] *= ar; oacc[nb][1][r] *= ar;                           \
          oacc[nb][2][r] *= ar; oacc[nb][3][r] *= ar;                           \
        }                                                                       \
      }                                                                         \
    }                                                                           \
    bf16x4 pa[2][2];                                                            \
    _Pragma("unroll")                                                           \
    for (int kblk = 0; kblk < 2; ++kblk)                                        \
      _Pragma("unroll")                                                         \
      for (int nb = 0; nb < 2; ++nb) {                                          \
        float p0 = __builtin_amdgcn_exp2f(sa[kblk][nb][0] - mrow[nb]);          \
        float p1 = __builtin_amdgcn_exp2f(sa[kblk][nb][1] - mrow[nb]);          \
        float p2 = __builtin_amdgcn_exp2f(sa[kblk][nb][2] - mrow[nb]);          \
        float p3 = __builtin_amdgcn_exp2f(sa[kblk][nb][3] - mrow[nb]);          \
        lp[nb] += (p0 + p1) + (p2 + p3);                                        \
        bf16x4 pk;                                                              \
        pk[0] = (short)f2bf(p0); pk[1] = (short)f2bf(p1);                       \
        pk[2] = (short)f2bf(p2); pk[3] = (short)f2bf(p3);                       \
        pa[kblk][nb] = pk;                                                      \
      }                                                                         \
    __builtin_amdgcn_s_setprio(1);                                              \
    _Pragma("unroll")                                                           \
    for (int db = 0; db < 4; ++db) {                                            \
      const u16* vr = &KV[2 + (CUR)][(db * 16 + fr) * 64];                      \
      bf16x4 v0 = *(const bf16x4*)&vr[xv0];                                     \
      bf16x4 v1 = *(const bf16x4*)&vr[xv1];                                     \
      oacc[0][db] = MFMA16K16(pa[0][0], v0, oacc[0][db]);                       \
      oacc[0][db] = MFMA16K16(pa[1][0], v1, oacc[0][db]);                       \
      oacc[1][db] = MFMA16K16(pa[0][1], v0, oacc[1][db]);                       \
      oacc[1][db] = MFMA16K16(pa[1][1], v1, oacc[1][db]);                       \
    }                                                                           \
    __builtin_amdgcn_s_setprio(0);                                              \
    __syncthreads();                                                            \
  } while (0)

__global__ __launch_bounds__(256, 4)
void attn_kernel(const u16* __restrict__ Q, const u16* __restrict__ K,
                 const u16* __restrict__ Vt, u16* __restrict__ O, int causal)
{
  __shared__ u16 KV[4][64 * 64];   // [0,1]=K dbuf, [2,3]=V dbuf; merge reuses as f32
  const int lane = threadIdx.x & 63, wid = threadIdx.x >> 6;
  const int fr = lane & 15, quad = lane >> 4;
  const int wq = wid >> 1, wk = wid & 1;

  const int flat = blockIdx.x;
  const int bh = ((flat >> 7) << 3) | (flat & 7);
  const int pair = (flat >> 3) & 15;
  const int b = bh >> 4, h = bh & 15;

  // loop-invariant swizzled LDS byte-element offsets
  const int xk0 = ((quad    ) ^ (fr & 7)) * 8;
  const int xk1 = ((quad + 4) ^ (fr & 7)) * 8;
  const int vcb = wk * 4 + (quad >> 1);
  const int vwi = (quad & 1) * 4;
  const int xv0 = (((vcb    ) ^ (fr & 7)) * 8) + vwi;
  const int xv1 = (((vcb + 2) ^ (fr & 7)) * 8) + vwi;

  const int srow = wid * 16 + (lane >> 3);
  const int jg = (lane & 7) ^ (srow & 7);   // same for srow and srow+8
  const u16* kg = K + (size_t)b * SEQ * DMODEL + h * HDIM;
  const u16* vg = Vt + (size_t)bh * HDIM * SEQ;
  const u16* ks0 = kg + (size_t)srow * DMODEL + jg * 8;
  const u16* ks1 = ks0 + (size_t)8 * DMODEL;
  const u16* vs0 = vg + (size_t)srow * SEQ + jg * 8;
  const u16* vs1 = vs0 + (size_t)8 * SEQ;
  float* mbuf = (float*)&KV[0][0];          // merge scratch in K bufs

  for (int tile = 0; tile < 2; ++tile) {
    const int qb = tile == 0 ? (31 - pair) : pair;
    const int q0 = qb * 64;
    const int qbase = q0 + wq * 32;

    bf16x8 aq[2][2];
#pragma unroll
    for (int nb = 0; nb < 2; ++nb) {
      const u16* qp = Q + (size_t)(b * SEQ + qbase + nb * 16 + fr) * DMODEL + h * HDIM + quad * 8;
      aq[nb][0] = *(const bf16x8*)qp;
      aq[nb][1] = *(const bf16x8*)(qp + 32);
    }

    f32x4 oacc[2][4] = {};
    float mrow[2] = {-1e30f, -1e30f};
    float lp[2]   = {0.f, 0.f};

    const int nsteps = (causal ? (q0 + 64) : SEQ) >> 6;

    // prologue: stage tile 0 into bufs {0, 2}
    gload16(ks0, &KV[0][(wid * 16 + 0) * 64]);
    gload16(ks1, &KV[0][(wid * 16 + 8) * 64]);
    gload16(vs0, &KV[2][(wid * 16 + 0) * 64]);
    gload16(vs1, &KV[2][(wid * 16 + 8) * 64]);
    const u16* kpre0 = ks0 + 64 * DMODEL;
    const u16* kpre1 = ks1 + 64 * DMODEL;
    const u16* vpre0 = vs0 + 64;
    const u16* vpre1 = vs1 + 64;
    __syncthreads();

    int t = 0;
    while (t + 2 <= nsteps) {
      ATTN_STEP(0, t);
      ATTN_STEP(1, t + 1);
      t += 2;
    }
    if (t < nsteps) ATTN_STEP(0, t);

    // ---- tile epilogue: finalize within wave, 2-way split-K merge across wk ----
#pragma unroll
    for (int nb = 0; nb < 2; ++nb) {
      lp[nb] += __shfl_xor(lp[nb], 16);
      lp[nb] += __shfl_xor(lp[nb], 32);
    }
    float mr2[2][4], lr2[2][4];
#pragma unroll
    for (int nb = 0; nb < 2; ++nb)
#pragma unroll
      for (int r = 0; r < 4; ++r) {
        int src = (lane & 48) | (quad * 4 + r);
        mr2[nb][r] = __shfl(mrow[nb], src);
        lr2[nb][r] = __shfl(lp[nb],   src);
      }
    float* mp = mbuf + (size_t)(wq * 64 + lane) * 50;
    if (wk) {
#pragma unroll
      for (int nb = 0; nb < 2; ++nb)
#pragma unroll
        for (int db = 0; db < 4; ++db) {
          *(float2*)&mp[(nb * 4 + db) * 4 + 0] = make_float2(oacc[nb][db][0], oacc[nb][db][1]);
          *(float2*)&mp[(nb * 4 + db) * 4 + 2] = make_float2(oacc[nb][db][2], oacc[nb][db][3]);
        }
#pragma unroll
      for (int nb = 0; nb < 2; ++nb) {
        *(float2*)&mp[32 + nb * 4 + 0] = make_float2(mr2[nb][0], mr2[nb][1]);
        *(float2*)&mp[32 + nb * 4 + 2] = make_float2(mr2[nb][2], mr2[nb][3]);
        *(float2*)&mp[40 + nb * 4 + 0] = make_float2(lr2[nb][0], lr2[nb][1]);
        *(float2*)&mp[40 + nb * 4 + 2] = make_float2(lr2[nb][2], lr2[nb][3]);
      }
    }
    __syncthreads();
    if (!wk) {
      float w0[2][4], w1[2][4];
#pragma unroll
      for (int nb = 0; nb < 2; ++nb)
#pragma unroll
        for (int r = 0; r < 4; ++r) {
          float m1 = mp[32 + nb * 4 + r];
          float l1 = mp[40 + nb * 4 + r];
          float M  = fmaxf(mr2[nb][r], m1);
          float c0 = __builtin_amdgcn_exp2f(mr2[nb][r] - M);
          float c1 = __builtin_amdgcn_exp2f(m1 - M);
          float inv = 1.0f / (lr2[nb][r] * c0 + l1 * c1);
          w0[nb][r] = c0 * inv;
          w1[nb][r] = c1 * inv;
        }
#pragma unroll
      for (int nb = 0; nb < 2; ++nb) {
        u16* op = O + (size_t)(b * SEQ + qbase + nb * 16 + quad * 4) * DMODEL + h * HDIM + fr;
#pragma unroll
        for (int db = 0; db < 4; ++db) {
          float2 oa = *(float2*)&mp[(nb * 4 + db) * 4 + 0];
          float2 ob = *(float2*)&mp[(nb * 4 + db) * 4 + 2];
          float o1[4] = {oa.x, oa.y, ob.x, ob.y};
#pragma unroll
          for (int r = 0; r < 4; ++r)
            op[(size_t)r * DMODEL + db * 16] =
                f2bf(oacc[nb][db][r] * w0[nb][r] + o1[r] * w1[nb][r]);
        }
      }
    }
    __syncthreads();   // merge reads done before next tile's staging reuses KV
  }
}

// ---------------- launcher ----------------
extern "C" void kernel_launch(void* const* d_in, const int* in_sizes, int n_in,
                              void* d_out, int out_size, void* d_ws, size_t ws_size,
                              hipStream_t stream)
{
  const float* x   = (const float*)d_in[0];
  const float* ek  = (const float*)d_in[1];
  const float* ev  = (const float*)d_in[2];
  const float* Wq1 = (const float*)d_in[3];
  const float* bq1 = (const float*)d_in[4];
  const float* Wk1 = (const float*)d_in[5];
  const float* bk1 = (const float*)d_in[6];
  const float* Wv1 = (const float*)d_in[7];
  const float* bv1 = (const float*)d_in[8];
  const float* Wo1 = (const float*)d_in[9];
  const float* bo1 = (const float*)d_in[10];
  const float* Wq2 = (const float*)d_in[11];
  const float* bq2 = (const float*)d_in[12];
  const float* Wk2 = (const float*)d_in[13];
  const float* bk2 = (const float*)d_in[14];
  const float* Wv2 = (const float*)d_in[15];
  const float* bv2 = (const float*)d_in[16];
  const float* Wo2 = (const float*)d_in[17];
  const float* bo2 = (const float*)d_in[18];

  char* ws = (char*)d_ws;
  u16* wt  = (u16*)ws;
  u16* xb  = (u16*)(ws + (16u << 20));
  u16* ekb = (u16*)(ws + (32u << 20));
  u16* evb = (u16*)(ws + (48u << 20));
  u16* qb  = (u16*)(ws + (64u << 20));
  u16* kkb = (u16*)(ws + (80u << 20));
  u16* vtb = (u16*)(ws + (96u << 20));
  u16* hb  = (u16*)(ws + (112u << 20));
  u16* ob  = xb;   // x dead after layer-1 projections

  const int NW = DMODEL * DMODEL;
  const int n4 = MTOT * DMODEL / 4;
  const float qscale = 0.125f * 1.4426950408889634f;   // 1/sqrt(HD) * log2(e)

  pack_act<<<n4 / 256, 256, 0, stream>>>(x,  xb,  n4);
  pack_act<<<n4 / 256, 256, 0, stream>>>(ek, ekb, n4);
  pack_act<<<n4 / 256, 256, 0, stream>>>(ev, evb, n4);

  dim3 wg(16, 16);
  pack_w<<<wg, 256, 0, stream>>>(Wq1, wt + 0 * NW, 1);
  pack_w<<<wg, 256, 0, stream>>>(Wk1, wt + 1 * NW, 1);
  pack_w<<<wg, 256, 0, stream>>>(Wv1, wt + 2 * NW, 1);
  pack_w<<<wg, 256, 0, stream>>>(Wo1, wt + 3 * NW, 0);
  pack_w<<<wg, 256, 0, stream>>>(Wq2, wt + 4 * NW, 1);
  pack_w<<<wg, 256, 0, stream>>>(Wk2, wt + 5 * NW, 1);
  pack_w<<<wg, 256, 0, stream>>>(Wv2, wt + 6 * NW, 1);
  pack_w<<<wg, 256, 0, stream>>>(Wo2, wt + 7 * NW, 0);

  const int gblocks = (MTOT / 128) * (DMODEL / 128);   // 512, XCD-swizzled in-kernel
  const int ablocks = (SEQ / 128) * BSZ * NHEAD;       // 1024 pair-blocks

  // layer 1: causal self-attention
  gemm_bt<0><<<gblocks, 256, 0, stream>>>(xb,  wt + 0 * NW, bq1, qb,  qscale);
  gemm_bt<0><<<gblocks, 256, 0, stream>>>(xb,  wt + 1 * NW, bk1, kkb, 1.0f);
  gemm_bt<1><<<gblocks, 256, 0, stream>>>(xb,  wt + 2 * NW, bv1, vtb, 1.0f);
  attn_kernel<<<ablocks, 256, 0, stream>>>(qb, kkb, vtb, ob, 1);
  gemm_bt<0><<<gblocks, 256, 0, stream>>>(ob,  wt + 3 * NW, bo1, hb,  1.0f);

  // layer 2: cross attention
  gemm_bt<0><<<gblocks, 256, 0, stream>>>(hb,  wt + 4 * NW, bq2, qb,  qscale);
  gemm_bt<0><<<gblocks, 256, 0, stream>>>(ekb, wt + 5 * NW, bk2, kkb, 1.0f);
  gemm_bt<1><<<gblocks, 256, 0, stream>>>(evb, wt + 6 * NW, bv2, vtb, 1.0f);
  attn_kernel<<<ablocks, 256, 0, stream>>>(qb, kkb, vtb, ob, 0);
  gemm_bt<2><<<gblocks, 256, 0, stream>>>(ob,  wt + 7 * NW, bo2, d_out, 1.0f);
}

// Round 8
// 448.922 us; speedup vs baseline: 1.3049x; 1.0171x over previous
//
#include <hip/hip_runtime.h>
#include <hip/hip_bf16.h>
#include <cstdint>

typedef unsigned short u16;
typedef unsigned int   u32;
typedef __attribute__((ext_vector_type(8))) short bf16x8;   // 8 bf16 = 4 VGPRs
typedef __attribute__((ext_vector_type(4))) short bf16x4;   // 4 bf16 = 2 VGPRs
typedef __attribute__((ext_vector_type(4))) float f32x4;

#define MFMA16(a,b,c)    __builtin_amdgcn_mfma_f32_16x16x32_bf16((a),(b),(c),0,0,0)
#define MFMA16K16(a,b,c) __builtin_amdgcn_mfma_f32_16x16x16bf16_1k((a),(b),(c),0,0,0)

#define BSZ    4
#define SEQ    2048
#define DMODEL 1024
#define NHEAD  16
#define HDIM   64
#define MTOT   (BSZ*SEQ)   // 8192
#define MASKV  (-3.0e38f)  // finite: exp2(MASKV - m) == 0, no inf-inf NaN

// native conversion: compiler lowers to v_cvt_pk_bf16_f32 when paired (m240)
__device__ __forceinline__ u16 f2bf(float f) {
  __hip_bfloat16 h = __float2bfloat16(f);
  return __builtin_bit_cast(u16, h);
}

typedef __attribute__((address_space(1))) void g1v;
typedef __attribute__((address_space(3))) void l3v;
// async global->LDS, 16B/lane. LDS dest is wave-uniform base (HW adds lane*16B).
__device__ __forceinline__ void gload16(const void* g, void* l) {
  __builtin_amdgcn_global_load_lds((g1v*)(uintptr_t)g, (l3v*)(u32)(uintptr_t)l, 16, 0, 0);
}

// ---------------- pack: fp32 -> bf16 activations ----------------
__global__ void pack_act(const float* __restrict__ in, u16* __restrict__ out, int n4) {
  int i = blockIdx.x * blockDim.x + threadIdx.x;
  if (i >= n4) return;
  float4 v = ((const float4*)in)[i];
  u32 lo = (u32)f2bf(v.x) | ((u32)f2bf(v.y) << 16);
  u32 hi = (u32)f2bf(v.z) | ((u32)f2bf(v.w) << 16);
  ((uint2*)out)[i] = make_uint2(lo, hi);
}

// ---------------- pack: weights -> Bt[n][k] bf16 (transposed) ----------------
__global__ void pack_w(const float* __restrict__ src, u16* __restrict__ dst, int per_head) {
  __shared__ float tile[64][65];
  int kt = blockIdx.x * 64, nt = blockIdx.y * 64;
  int tx = threadIdx.x & 63, ty = threadIdx.x >> 6;
  for (int kk = ty; kk < 64; kk += 4) {
    int k = kt + kk, n = nt + tx;
    float v = per_head ? src[(size_t)(n >> 6) * (DMODEL * HDIM) + (size_t)k * HDIM + (n & 63)]
                       : src[(size_t)k * DMODEL + n];
    tile[kk][tx] = v;
  }
  __syncthreads();
  for (int nn = ty; nn < 64; nn += 4)
    dst[(size_t)(nt + nn) * DMODEL + kt + tx] = f2bf(tile[tx][nn]);
}

// ---------------- GEMM: C[M,N] = (A[M,K] @ Bt[N,K]^T + bias) * scale ----------------
// m97 structure, 1D grid, XCD-swizzled. EPI 1 stores Vt with s-permuted layout:
// within each 32-key group, key (b:1|c:2|r:2) -> position (c:2|b:1|r:2), so the
// attention PV b128 read gets both kblk halves contiguously.
template <int EPI>
__global__ __launch_bounds__(256, 2)
void gemm_bt(const u16* __restrict__ A, const u16* __restrict__ Bt,
             const float* __restrict__ bias, void* __restrict__ Cout, float scale)
{
  __shared__ u16 As[128 * 32];
  __shared__ u16 Bs[128 * 32];
  const int lane = threadIdx.x & 63, wid = threadIdx.x >> 6;
  const int wg = ((blockIdx.x & 7) << 6) | (blockIdx.x >> 3);  // [xcd:3][seq:6]
  const int m0 = (wg >> 3) * 128, n0 = (wg & 7) * 128;

  const int srow = wid * 32 + (lane >> 2);
  const int scol = (lane & 3) * 8;
  const u16* gA = A  + (size_t)(m0 + srow) * DMODEL + scol;
  const u16* gB = Bt + (size_t)(n0 + srow) * DMODEL + scol;
  u16* lA0 = &As[(wid * 32) * 32];
  u16* lA1 = &As[(wid * 32 + 16) * 32];
  u16* lB0 = &Bs[(wid * 32) * 32];
  u16* lB1 = &Bs[(wid * 32 + 16) * 32];

  const int fr = lane & 15, quad = lane >> 4, fk = quad * 8;
  const int wr = (wid >> 1) * 64, wc = (wid & 1) * 64;

  f32x4 acc[4][4] = {};

  for (int kt = 0; kt < DMODEL / 32; ++kt) {
    __syncthreads();
    gload16(gA,               lA0);
    gload16(gA + 16 * DMODEL, lA1);
    gload16(gB,               lB0);
    gload16(gB + 16 * DMODEL, lB1);
    gA += 32; gB += 32;
    __syncthreads();

    bf16x8 af[4], bfr[4];
#pragma unroll
    for (int i = 0; i < 4; ++i) {
      af[i]  = *(const bf16x8*)&As[(wr + i * 16 + fr) * 32 + fk];
      bfr[i] = *(const bf16x8*)&Bs[(wc + i * 16 + fr) * 32 + fk];
    }
#pragma unroll
    for (int i = 0; i < 4; ++i)
#pragma unroll
      for (int j = 0; j < 4; ++j)
        acc[i][j] = MFMA16(af[i], bfr[j], acc[i][j]);
  }

#pragma unroll
  for (int i = 0; i < 4; ++i) {
    int row0 = m0 + wr + i * 16 + quad * 4;
#pragma unroll
    for (int j = 0; j < 4; ++j) {
      int col = n0 + wc + j * 16 + fr;
      float bv = bias[col];
      float v0 = (acc[i][j][0] + bv) * scale, v1 = (acc[i][j][1] + bv) * scale;
      float v2 = (acc[i][j][2] + bv) * scale, v3 = (acc[i][j][3] + bv) * scale;
      if constexpr (EPI == 2) {
        float* C = (float*)Cout;
        C[(size_t)(row0 + 0) * DMODEL + col] = v0;
        C[(size_t)(row0 + 1) * DMODEL + col] = v1;
        C[(size_t)(row0 + 2) * DMODEL + col] = v2;
        C[(size_t)(row0 + 3) * DMODEL + col] = v3;
      } else if constexpr (EPI == 0) {
        u16* C = (u16*)Cout;
        C[(size_t)(row0 + 0) * DMODEL + col] = f2bf(v0);
        C[(size_t)(row0 + 1) * DMODEL + col] = f2bf(v1);
        C[(size_t)(row0 + 2) * DMODEL + col] = f2bf(v2);
        C[(size_t)(row0 + 3) * DMODEL + col] = f2bf(v3);
      } else {
        u16* C = (u16*)Cout;
        int bi = row0 >> 11, s = row0 & 2047;
        // permuted s within 32-group: (b:1|c:2|r:2) -> (c:2|b:1|r:2); r block intact
        int sN = (s & ~31) | (((s >> 2) & 3) << 3) | (((s >> 4) & 1) << 2) | (s & 3);
        size_t vtr = ((size_t)(bi * NHEAD + (col >> 6)) * HDIM + (col & 63)) * SEQ + sN;
        *(uint2*)&C[vtr] = make_uint2((u32)f2bf(v0) | ((u32)f2bf(v1) << 16),
                                      (u32)f2bf(v2) | ((u32)f2bf(v3) << 16));
      }
    }
  }
}

// ---------------- flash attention v8 ----------------
// v7 + (a) b128 V reads via s-permuted Vt (conflict-free, half the V-read count)
//    + (b) reduced register pressure: 2 running prefetch pointers, short kf lives.
// Split-K waves 2x2 (wq x wk), swapped QK^T, zero-shuffle P into K=16 PV,
// unroll-by-2 (compile-time cur), 1024 pair-blocks, XCD-swizzled.

#define ATTN_STEP(CUR, TT)                                                      \
  do {                                                                          \
    const int kb_ = (TT) * 64;                                                  \
    if ((TT) + 1 < nsteps) {                                                    \
      gload16(kpre,              &KV[(CUR) ^ 1][(wid * 16 + 0) * 64]);          \
      gload16(kpre + 8 * DMODEL, &KV[(CUR) ^ 1][(wid * 16 + 8) * 64]);          \
      gload16(vpre,              &KV[2 + ((CUR) ^ 1)][(wid * 16 + 0) * 64]);    \
      gload16(vpre + 8 * SEQ,    &KV[2 + ((CUR) ^ 1)][(wid * 16 + 8) * 64]);    \
      kpre += 64 * DMODEL; vpre += 64;                                          \
    }                                                                           \
    const u16* kr0_ = &KV[(CUR)][(wk * 32 + fr) * 64];                          \
    f32x4 sa[2][2];                                                             \
    __builtin_amdgcn_s_setprio(1);                                              \
    {                                                                           \
      bf16x8 kfa = *(const bf16x8*)&kr0_[xk0];                                  \
      bf16x8 kfb = *(const bf16x8*)&kr0_[xk1];                                  \
      f32x4 s = {};                                                             \
      s = MFMA16(kfa, aq[0][0], s); s = MFMA16(kfb, aq[0][1], s); sa[0][0] = s; \
      s = (f32x4){};                                                            \
      s = MFMA16(kfa, aq[1][0], s); s = MFMA16(kfb, aq[1][1], s); sa[0][1] = s; \
      kfa = *(const bf16x8*)&kr0_[16 * 64 + xk0];                               \
      kfb = *(const bf16x8*)&kr0_[16 * 64 + xk1];                               \
      s = (f32x4){};                                                            \
      s = MFMA16(kfa, aq[0][0], s); s = MFMA16(kfb, aq[0][1], s); sa[1][0] = s; \
      s = (f32x4){};                                                            \
      s = MFMA16(kfa, aq[1][0], s); s = MFMA16(kfb, aq[1][1], s); sa[1][1] = s; \
    }                                                                           \
    __builtin_amdgcn_s_setprio(0);                                              \
    if (causal && kb_ + wk * 32 + 31 > qbase) {                                 \
      _Pragma("unroll")                                                         \
      for (int kblk = 0; kblk < 2; ++kblk)                                      \
        _Pragma("unroll")                                                       \
        for (int nb = 0; nb < 2; ++nb) {                                        \
          int key = kb_ + wk * 32 + kblk * 16 + quad * 4;                       \
          int q   = qbase + nb * 16 + fr;                                       \
          _Pragma("unroll")                                                     \
          for (int r = 0; r < 4; ++r)                                           \
            if (key + r > q) sa[kblk][nb][r] = MASKV;                           \
        }                                                                       \
    }                                                                           \
    float lm[2];                                                                \
    _Pragma("unroll")                                                           \
    for (int nb = 0; nb < 2; ++nb) {                                            \
      f32x4 mx4 = sa[0][nb];                                                    \
      mx4[0] = fmaxf(mx4[0], sa[1][nb][0]); mx4[1] = fmaxf(mx4[1], sa[1][nb][1]);\
      mx4[2] = fmaxf(mx4[2], sa[1][nb][2]); mx4[3] = fmaxf(mx4[3], sa[1][nb][3]);\
      lm[nb] = fmaxf(fmaxf(mx4[0], mx4[1]), fmaxf(mx4[2], mx4[3]));             \
    }                                                                           \
    int ok = (lm[0] <= mrow[0] + 11.f) & (lm[1] <= mrow[1] + 11.f);             \
    if (!__all(ok)) {                                                           \
      _Pragma("unroll")                                                         \
      for (int nb = 0; nb < 2; ++nb) {                                          \
        float mx = lm[nb];                                                      \
        mx = fmaxf(mx, __shfl_xor(mx, 16));                                     \
        mx = fmaxf(mx, __shfl_xor(mx, 32));                                     \
        float mnew = fmaxf(mrow[nb], mx);                                       \
        float a = __builtin_amdgcn_exp2f(mrow[nb] - mnew);                      \
        mrow[nb] = mnew;                                                        \
        lp[nb] *= a;                                                            \
        _Pragma("unroll")                                                       \
        for (int r = 0; r < 4; ++r) {                                           \
          float ar = __shfl(a, (lane & 48) | (quad * 4 + r));                   \
          oacc[nb][0][r] *= ar; oacc[nb][1][r] *= ar;                           \
          oacc[nb][2][r] *= ar; oacc[nb][3][r] *= ar;                           \
        }                                                                       \
      }                                                                         \
    }                                                                           \
    bf16x4 pa[2][2];                                                            \
    _Pragma("unroll")                                                           \
    for (int kblk = 0; kblk < 2; ++kblk)                                        \
      _Pragma("unroll")                                                         \
      for (int nb = 0; nb < 2; ++nb) {                                          \
        float p0 = __builtin_amdgcn_exp2f(sa[kblk][nb][0] - mrow[nb]);          \
        float p1 = __builtin_amdgcn_exp2f(sa[kblk][nb][1] - mrow[nb]);          \
        float p2 = __builtin_amdgcn_exp2f(sa[kblk][nb][2] - mrow[nb]);          \
        float p3 = __builtin_amdgcn_exp2f(sa[kblk][nb][3] - mrow[nb]);          \
        lp[nb] += (p0 + p1) + (p2 + p3);                                        \
        bf16x4 pk;                                                              \
        pk[0] = (short)f2bf(p0); pk[1] = (short)f2bf(p1);                       \
        pk[2] = (short)f2bf(p2); pk[3] = (short)f2bf(p3);                       \
        pa[kblk][nb] = pk;                                                      \
      }                                                                         \
    __builtin_amdgcn_s_setprio(1);                                              \
    _Pragma("unroll")                                                           \
    for (int db = 0; db < 4; ++db) {                                            \
      const u16* vr = &KV[2 + (CUR)][(db * 16 + fr) * 64];                      \
      bf16x8 vv = *(const bf16x8*)&vr[xv];                                      \
      bf16x4 v0 = {vv[0], vv[1], vv[2], vv[3]};                                 \
      bf16x4 v1 = {vv[4], vv[5], vv[6], vv[7]};                                 \
      oacc[0][db] = MFMA16K16(pa[0][0], v0, oacc[0][db]);                       \
      oacc[0][db] = MFMA16K16(pa[1][0], v1, oacc[0][db]);                       \
      oacc[1][db] = MFMA16K16(pa[0][1], v0, oacc[1][db]);                       \
      oacc[1][db] = MFMA16K16(pa[1][1], v1, oacc[1][db]);                       \
    }                                                                           \
    __builtin_amdgcn_s_setprio(0);                                              \
    __syncthreads();                                                            \
  } while (0)

__global__ __launch_bounds__(256, 4)
void attn_kernel(const u16* __restrict__ Q, const u16* __restrict__ K,
                 const u16* __restrict__ Vt, u16* __restrict__ O, int causal)
{
  __shared__ u16 KV[4][64 * 64];   // [0,1]=K dbuf, [2,3]=V dbuf; merge reuses as f32
  const int lane = threadIdx.x & 63, wid = threadIdx.x >> 6;
  const int fr = lane & 15, quad = lane >> 4;
  const int wq = wid >> 1, wk = wid & 1;

  const int flat = blockIdx.x;
  const int bh = ((flat >> 7) << 3) | (flat & 7);
  const int pair = (flat >> 3) & 15;
  const int b = bh >> 4, h = bh & 15;

  // loop-invariant swizzled LDS element offsets
  const int xk0 = ((quad    ) ^ (fr & 7)) * 8;
  const int xk1 = ((quad + 4) ^ (fr & 7)) * 8;
  const int xv  = ((wk * 4 + quad) ^ (fr & 7)) * 8;   // one b128: both kblk halves

  const int srow = wid * 16 + (lane >> 3);
  const int jg = (lane & 7) ^ (srow & 7);   // same for srow and srow+8
  const u16* kg = K + (size_t)b * SEQ * DMODEL + h * HDIM;
  const u16* vg = Vt + (size_t)bh * HDIM * SEQ;
  const u16* ks0 = kg + (size_t)srow * DMODEL + jg * 8;
  const u16* vs0 = vg + (size_t)srow * SEQ + jg * 8;
  float* mbuf = (float*)&KV[0][0];          // merge scratch in K bufs

  for (int tile = 0; tile < 2; ++tile) {
    const int qb = tile == 0 ? (31 - pair) : pair;
    const int q0 = qb * 64;
    const int qbase = q0 + wq * 32;

    bf16x8 aq[2][2];
#pragma unroll
    for (int nb = 0; nb < 2; ++nb) {
      const u16* qp = Q + (size_t)(b * SEQ + qbase + nb * 16 + fr) * DMODEL + h * HDIM + quad * 8;
      aq[nb][0] = *(const bf16x8*)qp;
      aq[nb][1] = *(const bf16x8*)(qp + 32);
    }

    f32x4 oacc[2][4] = {};
    float mrow[2] = {-1e30f, -1e30f};
    float lp[2]   = {0.f, 0.f};

    const int nsteps = (causal ? (q0 + 64) : SEQ) >> 6;

    // prologue: stage tile 0 into bufs {0, 2}
    gload16(ks0,              &KV[0][(wid * 16 + 0) * 64]);
    gload16(ks0 + 8 * DMODEL, &KV[0][(wid * 16 + 8) * 64]);
    gload16(vs0,              &KV[2][(wid * 16 + 0) * 64]);
    gload16(vs0 + 8 * SEQ,    &KV[2][(wid * 16 + 8) * 64]);
    const u16* kpre = ks0 + 64 * DMODEL;
    const u16* vpre = vs0 + 64;
    __syncthreads();

    int t = 0;
    while (t + 2 <= nsteps) {
      ATTN_STEP(0, t);
      ATTN_STEP(1, t + 1);
      t += 2;
    }
    if (t < nsteps) ATTN_STEP(0, t);

    // ---- tile epilogue: finalize within wave, 2-way split-K merge across wk ----
#pragma unroll
    for (int nb = 0; nb < 2; ++nb) {
      lp[nb] += __shfl_xor(lp[nb], 16);
      lp[nb] += __shfl_xor(lp[nb], 32);
    }
    float mr2[2][4], lr2[2][4];
#pragma unroll
    for (int nb = 0; nb < 2; ++nb)
#pragma unroll
      for (int r = 0; r < 4; ++r) {
        int src = (lane & 48) | (quad * 4 + r);
        mr2[nb][r] = __shfl(mrow[nb], src);
        lr2[nb][r] = __shfl(lp[nb],   src);
      }
    float* mp = mbuf + (size_t)(wq * 64 + lane) * 50;
    if (wk) {
#pragma unroll
      for (int nb = 0; nb < 2; ++nb)
#pragma unroll
        for (int db = 0; db < 4; ++db) {
          *(float2*)&mp[(nb * 4 + db) * 4 + 0] = make_float2(oacc[nb][db][0], oacc[nb][db][1]);
          *(float2*)&mp[(nb * 4 + db) * 4 + 2] = make_float2(oacc[nb][db][2], oacc[nb][db][3]);
        }
#pragma unroll
      for (int nb = 0; nb < 2; ++nb) {
        *(float2*)&mp[32 + nb * 4 + 0] = make_float2(mr2[nb][0], mr2[nb][1]);
        *(float2*)&mp[32 + nb * 4 + 2] = make_float2(mr2[nb][2], mr2[nb][3]);
        *(float2*)&mp[40 + nb * 4 + 0] = make_float2(lr2[nb][0], lr2[nb][1]);
        *(float2*)&mp[40 + nb * 4 + 2] = make_float2(lr2[nb][2], lr2[nb][3]);
      }
    }
    __syncthreads();
    if (!wk) {
      float w0[2][4], w1[2][4];
#pragma unroll
      for (int nb = 0; nb < 2; ++nb)
#pragma unroll
        for (int r = 0; r < 4; ++r) {
          float m1 = mp[32 + nb * 4 + r];
          float l1 = mp[40 + nb * 4 + r];
          float M  = fmaxf(mr2[nb][r], m1);
          float c0 = __builtin_amdgcn_exp2f(mr2[nb][r] - M);
          float c1 = __builtin_amdgcn_exp2f(m1 - M);
          float inv = 1.0f / (lr2[nb][r] * c0 + l1 * c1);
          w0[nb][r] = c0 * inv;
          w1[nb][r] = c1 * inv;
        }
#pragma unroll
      for (int nb = 0; nb < 2; ++nb) {
        u16* op = O + (size_t)(b * SEQ + qbase + nb * 16 + quad * 4) * DMODEL + h * HDIM + fr;
#pragma unroll
        for (int db = 0; db < 4; ++db) {
          float2 oa = *(float2*)&mp[(nb * 4 + db) * 4 + 0];
          float2 ob = *(float2*)&mp[(nb * 4 + db) * 4 + 2];
          float o1[4] = {oa.x, oa.y, ob.x, ob.y};
#pragma unroll
          for (int r = 0; r < 4; ++r)
            op[(size_t)r * DMODEL + db * 16] =
                f2bf(oacc[nb][db][r] * w0[nb][r] + o1[r] * w1[nb][r]);
        }
      }
    }
    __syncthreads();   // merge reads done before next tile's staging reuses KV
  }
}

// ---------------- launcher ----------------
extern "C" void kernel_launch(void* const* d_in, const int* in_sizes, int n_in,
                              void* d_out, int out_size, void* d_ws, size_t ws_size,
                              hipStream_t stream)
{
  const float* x   = (const float*)d_in[0];
  const float* ek  = (const float*)d_in[1];
  const float* ev  = (const float*)d_in[2];
  const float* Wq1 = (const float*)d_in[3];
  const float* bq1 = (const float*)d_in[4];
  const float* Wk1 = (const float*)d_in[5];
  const float* bk1 = (const float*)d_in[6];
  const float* Wv1 = (const float*)d_in[7];
  const float* bv1 = (const float*)d_in[8];
  const float* Wo1 = (const float*)d_in[9];
  const float* bo1 = (const float*)d_in[10];
  const float* Wq2 = (const float*)d_in[11];
  const float* bq2 = (const float*)d_in[12];
  const float* Wk2 = (const float*)d_in[13];
  const float* bk2 = (const float*)d_in[14];
  const float* Wv2 = (const float*)d_in[15];
  const float* bv2 = (const float*)d_in[16];
  const float* Wo2 = (const float*)d_in[17];
  const float* bo2 = (const float*)d_in[18];

  char* ws = (char*)d_ws;
  u16* wt  = (u16*)ws;
  u16* xb  = (u16*)(ws + (16u << 20));
  u16* ekb = (u16*)(ws + (32u << 20));
  u16* evb = (u16*)(ws + (48u << 20));
  u16* qb  = (u16*)(ws + (64u << 20));
  u16* kkb = (u16*)(ws + (80u << 20));
  u16* vtb = (u16*)(ws + (96u << 20));
  u16* hb  = (u16*)(ws + (112u << 20));
  u16* ob  = xb;   // x dead after layer-1 projections

  const int NW = DMODEL * DMODEL;
  const int n4 = MTOT * DMODEL / 4;
  const float qscale = 0.125f * 1.4426950408889634f;   // 1/sqrt(HD) * log2(e)

  pack_act<<<n4 / 256, 256, 0, stream>>>(x,  xb,  n4);
  pack_act<<<n4 / 256, 256, 0, stream>>>(ek, ekb, n4);
  pack_act<<<n4 / 256, 256, 0, stream>>>(ev, evb, n4);

  dim3 wg(16, 16);
  pack_w<<<wg, 256, 0, stream>>>(Wq1, wt + 0 * NW, 1);
  pack_w<<<wg, 256, 0, stream>>>(Wk1, wt + 1 * NW, 1);
  pack_w<<<wg, 256, 0, stream>>>(Wv1, wt + 2 * NW, 1);
  pack_w<<<wg, 256, 0, stream>>>(Wo1, wt + 3 * NW, 0);
  pack_w<<<wg, 256, 0, stream>>>(Wq2, wt + 4 * NW, 1);
  pack_w<<<wg, 256, 0, stream>>>(Wk2, wt + 5 * NW, 1);
  pack_w<<<wg, 256, 0, stream>>>(Wv2, wt + 6 * NW, 1);
  pack_w<<<wg, 256, 0, stream>>>(Wo2, wt + 7 * NW, 0);

  const int gblocks = (MTOT / 128) * (DMODEL / 128);   // 512, XCD-swizzled in-kernel
  const int ablocks = (SEQ / 128) * BSZ * NHEAD;       // 1024 pair-blocks

  // layer 1: causal self-attention
  gemm_bt<0><<<gblocks, 256, 0, stream>>>(xb,  wt + 0 * NW, bq1, qb,  qscale);
  gemm_bt<0><<<gblocks, 256, 0, stream>>>(xb,  wt + 1 * NW, bk1, kkb, 1.0f);
  gemm_bt<1><<<gblocks, 256, 0, stream>>>(xb,  wt + 2 * NW, bv1, vtb, 1.0f);
  attn_kernel<<<ablocks, 256, 0, stream>>>(qb, kkb, vtb, ob, 1);
  gemm_bt<0><<<gblocks, 256, 0, stream>>>(ob,  wt + 3 * NW, bo1, hb,  1.0f);

  // layer 2: cross attention
  gemm_bt<0><<<gblocks, 256, 0, stream>>>(hb,  wt + 4 * NW, bq2, qb,  qscale);
  gemm_bt<0><<<gblocks, 256, 0, stream>>>(ekb, wt + 5 * NW, bk2, kkb, 1.0f);
  gemm_bt<1><<<gblocks, 256, 0, stream>>>(evb, wt + 6 * NW, bv2, vtb, 1.0f);
  attn_kernel<<<ablocks, 256, 0, stream>>>(qb, kkb, vtb, ob, 0);
  gemm_bt<2><<<gblocks, 256, 0, stream>>>(ob,  wt + 7 * NW, bo2, d_out, 1.0f);
}

// Round 9
// 409.063 us; speedup vs baseline: 1.4320x; 1.0974x over previous
//
#include <hip/hip_runtime.h>
#include <hip/hip_bf16.h>
#include <cstdint>

typedef unsigned short u16;
typedef unsigned int   u32;
typedef __attribute__((ext_vector_type(8))) short bf16x8;   // 8 bf16 = 4 VGPRs
typedef __attribute__((ext_vector_type(4))) short bf16x4;   // 4 bf16 = 2 VGPRs
typedef __attribute__((ext_vector_type(4))) float f32x4;

#define MFMA16(a,b,c)    __builtin_amdgcn_mfma_f32_16x16x32_bf16((a),(b),(c),0,0,0)
#define MFMA16K16(a,b,c) __builtin_amdgcn_mfma_f32_16x16x16bf16_1k((a),(b),(c),0,0,0)

#define BSZ    4
#define SEQ    2048
#define DMODEL 1024
#define NHEAD  16
#define HDIM   64
#define MTOT   (BSZ*SEQ)   // 8192
#define MASKV  (-3.0e38f)  // finite: exp2(MASKV - m) == 0, no inf-inf NaN

// native conversion: compiler lowers to v_cvt_pk_bf16_f32 when paired (m240)
__device__ __forceinline__ u16 f2bf(float f) {
  __hip_bfloat16 h = __float2bfloat16(f);
  return __builtin_bit_cast(u16, h);
}

typedef __attribute__((address_space(1))) void g1v;
typedef __attribute__((address_space(3))) void l3v;
// async global->LDS, 16B/lane. LDS dest is wave-uniform base (HW adds lane*16B).
__device__ __forceinline__ void gload16(const void* g, void* l) {
  __builtin_amdgcn_global_load_lds((g1v*)(uintptr_t)g, (l3v*)(u32)(uintptr_t)l, 16, 0, 0);
}

// ---------------- pack: fp32 -> bf16 activations ----------------
__global__ void pack_act(const float* __restrict__ in, u16* __restrict__ out, int n4) {
  int i = blockIdx.x * blockDim.x + threadIdx.x;
  if (i >= n4) return;
  float4 v = ((const float4*)in)[i];
  u32 lo = (u32)f2bf(v.x) | ((u32)f2bf(v.y) << 16);
  u32 hi = (u32)f2bf(v.z) | ((u32)f2bf(v.w) << 16);
  ((uint2*)out)[i] = make_uint2(lo, hi);
}

// ---------------- pack: weights -> Bt[n][k] bf16 (transposed) ----------------
__global__ void pack_w(const float* __restrict__ src, u16* __restrict__ dst, int per_head) {
  __shared__ float tile[64][65];
  int kt = blockIdx.x * 64, nt = blockIdx.y * 64;
  int tx = threadIdx.x & 63, ty = threadIdx.x >> 6;
  for (int kk = ty; kk < 64; kk += 4) {
    int k = kt + kk, n = nt + tx;
    float v = per_head ? src[(size_t)(n >> 6) * (DMODEL * HDIM) + (size_t)k * HDIM + (n & 63)]
                       : src[(size_t)k * DMODEL + n];
    tile[kk][tx] = v;
  }
  __syncthreads();
  for (int nn = ty; nn < 64; nn += 4)
    dst[(size_t)(nt + nn) * DMODEL + kt + tx] = f2bf(tile[tx][nn]);
}

// ---------------- GEMM v2: BK=64 single-buffer ----------------
// C[M,N] = (A[M,K] @ Bt[N,K]^T + bias) * scale. 128x128 tile, BK=64, 4 waves,
// 16 K-steps (half the barrier pairs of BK=32), 32 MFMA/wave per barrier pair.
// 128B LDS rows: XOR-chunk swizzle c^=(row&7) => conflict-free b128 fragment
// reads; staging pre-swizzles the global source (LDS dest stays linear).
// XCD-swizzled 1D grid. EPI 1 stores Vt with s-permuted layout (see attn).
template <int EPI>
__global__ __launch_bounds__(256, 2)
void gemm_bt(const u16* __restrict__ A, const u16* __restrict__ Bt,
             const float* __restrict__ bias, void* __restrict__ Cout, float scale)
{
  __shared__ u16 As[128 * 64];
  __shared__ u16 Bs[128 * 64];
  const int lane = threadIdx.x & 63, wid = threadIdx.x >> 6;
  const int wg = ((blockIdx.x & 7) << 6) | (blockIdx.x >> 3);  // [xcd:3][seq:6]
  const int m0 = (wg >> 3) * 128, n0 = (wg & 7) * 128;

  // staging: wave covers rows wid*32..+31; instr i = 8 rows x 8 chunks (16B)
  const int srow = wid * 32 + (lane >> 3);          // +i*8; (row&7) == lane>>3
  const int sc = (lane & 7) ^ ((lane >> 3) & 7);    // pre-swizzled source chunk
  const u16* gA = A  + (size_t)(m0 + srow) * DMODEL + sc * 8;
  const u16* gB = Bt + (size_t)(n0 + srow) * DMODEL + sc * 8;

  const int fr = lane & 15, quad = lane >> 4;
  const int wr = (wid >> 1) * 64, wc = (wid & 1) * 64;

  f32x4 acc[4][4] = {};

  for (int kt = 0; kt < DMODEL / 64; ++kt) {
    __syncthreads();                       // previous step's reads done
#pragma unroll
    for (int i = 0; i < 4; ++i) {
      gload16(gA + (size_t)(i * 8) * DMODEL, &As[(wid * 32 + i * 8) * 64]);
      gload16(gB + (size_t)(i * 8) * DMODEL, &Bs[(wid * 32 + i * 8) * 64]);
    }
    gA += 64; gB += 64;
    __syncthreads();                       // tiles staged (vmcnt drained)

#pragma unroll
    for (int kp = 0; kp < 2; ++kp) {
      bf16x8 af[4], bfr[4];
#pragma unroll
      for (int i = 0; i < 4; ++i) {
        int ra = wr + i * 16 + fr;
        af[i]  = *(const bf16x8*)&As[ra * 64 + (((kp * 4 + quad) ^ (ra & 7)) * 8)];
        int rb = wc + i * 16 + fr;
        bfr[i] = *(const bf16x8*)&Bs[rb * 64 + (((kp * 4 + quad) ^ (rb & 7)) * 8)];
      }
#pragma unroll
      for (int i = 0; i < 4; ++i)
#pragma unroll
        for (int j = 0; j < 4; ++j)
          acc[i][j] = MFMA16(af[i], bfr[j], acc[i][j]);
    }
  }

  // C/D layout: col = lane&15, row = (lane>>4)*4 + reg
#pragma unroll
  for (int i = 0; i < 4; ++i) {
    int row0 = m0 + wr + i * 16 + quad * 4;
#pragma unroll
    for (int j = 0; j < 4; ++j) {
      int col = n0 + wc + j * 16 + fr;
      float bv = bias[col];
      float v0 = (acc[i][j][0] + bv) * scale, v1 = (acc[i][j][1] + bv) * scale;
      float v2 = (acc[i][j][2] + bv) * scale, v3 = (acc[i][j][3] + bv) * scale;
      if constexpr (EPI == 2) {
        float* C = (float*)Cout;
        C[(size_t)(row0 + 0) * DMODEL + col] = v0;
        C[(size_t)(row0 + 1) * DMODEL + col] = v1;
        C[(size_t)(row0 + 2) * DMODEL + col] = v2;
        C[(size_t)(row0 + 3) * DMODEL + col] = v3;
      } else if constexpr (EPI == 0) {
        u16* C = (u16*)Cout;
        C[(size_t)(row0 + 0) * DMODEL + col] = f2bf(v0);
        C[(size_t)(row0 + 1) * DMODEL + col] = f2bf(v1);
        C[(size_t)(row0 + 2) * DMODEL + col] = f2bf(v2);
        C[(size_t)(row0 + 3) * DMODEL + col] = f2bf(v3);
      } else {
        u16* C = (u16*)Cout;
        int bi = row0 >> 11, s = row0 & 2047;
        // permuted s within 32-group: (b:1|c:2|r:2) -> (c:2|b:1|r:2)
        int sN = (s & ~31) | (((s >> 2) & 3) << 3) | (((s >> 4) & 1) << 2) | (s & 3);
        size_t vtr = ((size_t)(bi * NHEAD + (col >> 6)) * HDIM + (col & 63)) * SEQ + sN;
        *(uint2*)&C[vtr] = make_uint2((u32)f2bf(v0) | ((u32)f2bf(v1) << 16),
                                      (u32)f2bf(v2) | ((u32)f2bf(v3) << 16));
      }
    }
  }
}

// ---------------- flash attention v9 ----------------
// v6 loop structure (runtime cur, no unroll -> no spill) + b128 V reads via
// s-permuted Vt (conflict-free) + running prefetch pointers.
// Split-K waves 2x2 (wq x wk), swapped QK^T, zero-shuffle P into K=16 PV,
// 1024 pair-blocks (causal = uniform 33 steps), XCD-swizzled.
__global__ __launch_bounds__(256, 4)
void attn_kernel(const u16* __restrict__ Q, const u16* __restrict__ K,
                 const u16* __restrict__ Vt, u16* __restrict__ O, int causal)
{
  __shared__ u16 KV[4][64 * 64];   // [0,1]=K dbuf, [2,3]=V dbuf; merge reuses as f32
  const int lane = threadIdx.x & 63, wid = threadIdx.x >> 6;
  const int fr = lane & 15, quad = lane >> 4;
  const int wq = wid >> 1, wk = wid & 1;

  const int flat = blockIdx.x;
  const int bh = ((flat >> 7) << 3) | (flat & 7);
  const int pair = (flat >> 3) & 15;
  const int b = bh >> 4, h = bh & 15;

  // loop-invariant swizzled LDS element offsets
  const int xk0 = ((quad    ) ^ (fr & 7)) * 8;
  const int xk1 = ((quad + 4) ^ (fr & 7)) * 8;
  const int xv  = ((wk * 4 + quad) ^ (fr & 7)) * 8;   // one b128: both kblk halves

  const int srow = wid * 16 + (lane >> 3);
  const int jg = (lane & 7) ^ (srow & 7);   // same for srow and srow+8
  const u16* kg = K + (size_t)b * SEQ * DMODEL + h * HDIM;
  const u16* vg = Vt + (size_t)bh * HDIM * SEQ;
  const u16* ks0 = kg + (size_t)srow * DMODEL + jg * 8;
  const u16* vs0 = vg + (size_t)srow * SEQ + jg * 8;
  float* mbuf = (float*)&KV[0][0];          // merge scratch (25.6KB < 32KB)

  for (int tile = 0; tile < 2; ++tile) {
    const int qb = tile == 0 ? (31 - pair) : pair;
    const int q0 = qb * 64;
    const int qbase = q0 + wq * 32;

    bf16x8 aq[2][2];
#pragma unroll
    for (int nb = 0; nb < 2; ++nb) {
      const u16* qp = Q + (size_t)(b * SEQ + qbase + nb * 16 + fr) * DMODEL + h * HDIM + quad * 8;
      aq[nb][0] = *(const bf16x8*)qp;
      aq[nb][1] = *(const bf16x8*)(qp + 32);
    }

    f32x4 oacc[2][4] = {};
    float mrow[2] = {-1e30f, -1e30f};
    float lp[2]   = {0.f, 0.f};

    const int nsteps = (causal ? (q0 + 64) : SEQ) >> 6;

    // prologue: stage tile 0 into bufs {0, 2}
    gload16(ks0,              &KV[0][(wid * 16 + 0) * 64]);
    gload16(ks0 + 8 * DMODEL, &KV[0][(wid * 16 + 8) * 64]);
    gload16(vs0,              &KV[2][(wid * 16 + 0) * 64]);
    gload16(vs0 + 8 * SEQ,    &KV[2][(wid * 16 + 8) * 64]);
    const u16* kpre = ks0 + 64 * DMODEL;
    const u16* vpre = vs0 + 64;
    __syncthreads();

    for (int t = 0; t < nsteps; ++t) {
      const int cur = t & 1;
      const int kb = t * 64;
      if (t + 1 < nsteps) {
        gload16(kpre,              &KV[cur ^ 1][(wid * 16 + 0) * 64]);
        gload16(kpre + 8 * DMODEL, &KV[cur ^ 1][(wid * 16 + 8) * 64]);
        gload16(vpre,              &KV[2 + (cur ^ 1)][(wid * 16 + 0) * 64]);
        gload16(vpre + 8 * SEQ,    &KV[2 + (cur ^ 1)][(wid * 16 + 8) * 64]);
        kpre += 64 * DMODEL; vpre += 64;
      }
      // swapped QK^T: sa[kblk][nb][r] = S[key=kb+wk*32+kblk*16+quad*4+r][q=qbase+nb*16+fr]
      const u16* kr0 = &KV[cur][(wk * 32 + fr) * 64];
      f32x4 sa[2][2];
      __builtin_amdgcn_s_setprio(1);
      {
        bf16x8 kfa = *(const bf16x8*)&kr0[xk0];
        bf16x8 kfb = *(const bf16x8*)&kr0[xk1];
        f32x4 s = {};
        s = MFMA16(kfa, aq[0][0], s); s = MFMA16(kfb, aq[0][1], s); sa[0][0] = s;
        s = (f32x4){};
        s = MFMA16(kfa, aq[1][0], s); s = MFMA16(kfb, aq[1][1], s); sa[0][1] = s;
        kfa = *(const bf16x8*)&kr0[16 * 64 + xk0];
        kfb = *(const bf16x8*)&kr0[16 * 64 + xk1];
        s = (f32x4){};
        s = MFMA16(kfa, aq[0][0], s); s = MFMA16(kfb, aq[0][1], s); sa[1][0] = s;
        s = (f32x4){};
        s = MFMA16(kfa, aq[1][0], s); s = MFMA16(kfb, aq[1][1], s); sa[1][1] = s;
      }
      __builtin_amdgcn_s_setprio(0);

      if (causal && kb + wk * 32 + 31 > qbase) {   // wave-uniform diagonal check
#pragma unroll
        for (int kblk = 0; kblk < 2; ++kblk)
#pragma unroll
          for (int nb = 0; nb < 2; ++nb) {
            int key = kb + wk * 32 + kblk * 16 + quad * 4;
            int q   = qbase + nb * 16 + fr;
#pragma unroll
            for (int r = 0; r < 4; ++r)
              if (key + r > q) sa[kblk][nb][r] = MASKV;
          }
      }

      // ---- defer-max softmax (lane-local partials) ----
      float lm[2];
#pragma unroll
      for (int nb = 0; nb < 2; ++nb) {
        f32x4 mx4 = sa[0][nb];
        mx4[0] = fmaxf(mx4[0], sa[1][nb][0]); mx4[1] = fmaxf(mx4[1], sa[1][nb][1]);
        mx4[2] = fmaxf(mx4[2], sa[1][nb][2]); mx4[3] = fmaxf(mx4[3], sa[1][nb][3]);
        lm[nb] = fmaxf(fmaxf(mx4[0], mx4[1]), fmaxf(mx4[2], mx4[3]));
      }
      int ok = (lm[0] <= mrow[0] + 11.f) & (lm[1] <= mrow[1] + 11.f);
      if (!__all(ok)) {
#pragma unroll
        for (int nb = 0; nb < 2; ++nb) {
          float mx = lm[nb];
          mx = fmaxf(mx, __shfl_xor(mx, 16));
          mx = fmaxf(mx, __shfl_xor(mx, 32));
          float mnew = fmaxf(mrow[nb], mx);
          float a = __builtin_amdgcn_exp2f(mrow[nb] - mnew);
          mrow[nb] = mnew;
          lp[nb] *= a;
#pragma unroll
          for (int r = 0; r < 4; ++r) {
            float ar = __shfl(a, (lane & 48) | (quad * 4 + r));
            oacc[nb][0][r] *= ar; oacc[nb][1][r] *= ar;
            oacc[nb][2][r] *= ar; oacc[nb][3][r] *= ar;
          }
        }
      }

      // exp2 + pack P^T straight into K=16 A-frags (no LDS, no shuffles)
      bf16x4 pa[2][2];
#pragma unroll
      for (int kblk = 0; kblk < 2; ++kblk)
#pragma unroll
        for (int nb = 0; nb < 2; ++nb) {
          float p0 = __builtin_amdgcn_exp2f(sa[kblk][nb][0] - mrow[nb]);
          float p1 = __builtin_amdgcn_exp2f(sa[kblk][nb][1] - mrow[nb]);
          float p2 = __builtin_amdgcn_exp2f(sa[kblk][nb][2] - mrow[nb]);
          float p3 = __builtin_amdgcn_exp2f(sa[kblk][nb][3] - mrow[nb]);
          lp[nb] += (p0 + p1) + (p2 + p3);
          bf16x4 pk;
          pk[0] = (short)f2bf(p0); pk[1] = (short)f2bf(p1);
          pk[2] = (short)f2bf(p2); pk[3] = (short)f2bf(p3);
          pa[kblk][nb] = pk;
        }

      // PV: one b128 per d-block from s-permuted Vt tile (both kblk halves)
      __builtin_amdgcn_s_setprio(1);
#pragma unroll
      for (int db = 0; db < 4; ++db) {
        const u16* vr = &KV[2 + cur][(db * 16 + fr) * 64];
        bf16x8 vv = *(const bf16x8*)&vr[xv];
        bf16x4 v0 = {vv[0], vv[1], vv[2], vv[3]};
        bf16x4 v1 = {vv[4], vv[5], vv[6], vv[7]};
        oacc[0][db] = MFMA16K16(pa[0][0], v0, oacc[0][db]);
        oacc[0][db] = MFMA16K16(pa[1][0], v1, oacc[0][db]);
        oacc[1][db] = MFMA16K16(pa[0][1], v0, oacc[1][db]);
        oacc[1][db] = MFMA16K16(pa[1][1], v1, oacc[1][db]);
      }
      __builtin_amdgcn_s_setprio(0);
      __syncthreads();   // buf[cur] reads done; buf[cur^1] staging drained
    }

    // ---- tile epilogue: finalize within wave, 2-way split-K merge across wk ----
#pragma unroll
    for (int nb = 0; nb < 2; ++nb) {
      lp[nb] += __shfl_xor(lp[nb], 16);
      lp[nb] += __shfl_xor(lp[nb], 32);
    }
    float mr2[2][4], lr2[2][4];
#pragma unroll
    for (int nb = 0; nb < 2; ++nb)
#pragma unroll
      for (int r = 0; r < 4; ++r) {
        int src = (lane & 48) | (quad * 4 + r);
        mr2[nb][r] = __shfl(mrow[nb], src);
        lr2[nb][r] = __shfl(lp[nb],   src);
      }
    float* mp = mbuf + (size_t)(wq * 64 + lane) * 50;
    if (wk) {
#pragma unroll
      for (int nb = 0; nb < 2; ++nb)
#pragma unroll
        for (int db = 0; db < 4; ++db) {
          *(float2*)&mp[(nb * 4 + db) * 4 + 0] = make_float2(oacc[nb][db][0], oacc[nb][db][1]);
          *(float2*)&mp[(nb * 4 + db) * 4 + 2] = make_float2(oacc[nb][db][2], oacc[nb][db][3]);
        }
#pragma unroll
      for (int nb = 0; nb < 2; ++nb) {
        *(float2*)&mp[32 + nb * 4 + 0] = make_float2(mr2[nb][0], mr2[nb][1]);
        *(float2*)&mp[32 + nb * 4 + 2] = make_float2(mr2[nb][2], mr2[nb][3]);
        *(float2*)&mp[40 + nb * 4 + 0] = make_float2(lr2[nb][0], lr2[nb][1]);
        *(float2*)&mp[40 + nb * 4 + 2] = make_float2(lr2[nb][2], lr2[nb][3]);
      }
    }
    __syncthreads();
    if (!wk) {
      float w0[2][4], w1[2][4];
#pragma unroll
      for (int nb = 0; nb < 2; ++nb)
#pragma unroll
        for (int r = 0; r < 4; ++r) {
          float m1 = mp[32 + nb * 4 + r];
          float l1 = mp[40 + nb * 4 + r];
          float M  = fmaxf(mr2[nb][r], m1);
          float c0 = __builtin_amdgcn_exp2f(mr2[nb][r] - M);
          float c1 = __builtin_amdgcn_exp2f(m1 - M);
          float inv = 1.0f / (lr2[nb][r] * c0 + l1 * c1);
          w0[nb][r] = c0 * inv;
          w1[nb][r] = c1 * inv;
        }
#pragma unroll
      for (int nb = 0; nb < 2; ++nb) {
        u16* op = O + (size_t)(b * SEQ + qbase + nb * 16 + quad * 4) * DMODEL + h * HDIM + fr;
#pragma unroll
        for (int db = 0; db < 4; ++db) {
          float2 oa = *(float2*)&mp[(nb * 4 + db) * 4 + 0];
          float2 ob = *(float2*)&mp[(nb * 4 + db) * 4 + 2];
          float o1[4] = {oa.x, oa.y, ob.x, ob.y};
#pragma unroll
          for (int r = 0; r < 4; ++r)
            op[(size_t)r * DMODEL + db * 16] =
                f2bf(oacc[nb][db][r] * w0[nb][r] + o1[r] * w1[nb][r]);
        }
      }
    }
    __syncthreads();   // merge reads done before next tile's staging reuses KV
  }
}

// ---------------- launcher ----------------
extern "C" void kernel_launch(void* const* d_in, const int* in_sizes, int n_in,
                              void* d_out, int out_size, void* d_ws, size_t ws_size,
                              hipStream_t stream)
{
  const float* x   = (const float*)d_in[0];
  const float* ek  = (const float*)d_in[1];
  const float* ev  = (const float*)d_in[2];
  const float* Wq1 = (const float*)d_in[3];
  const float* bq1 = (const float*)d_in[4];
  const float* Wk1 = (const float*)d_in[5];
  const float* bk1 = (const float*)d_in[6];
  const float* Wv1 = (const float*)d_in[7];
  const float* bv1 = (const float*)d_in[8];
  const float* Wo1 = (const float*)d_in[9];
  const float* bo1 = (const float*)d_in[10];
  const float* Wq2 = (const float*)d_in[11];
  const float* bq2 = (const float*)d_in[12];
  const float* Wk2 = (const float*)d_in[13];
  const float* bk2 = (const float*)d_in[14];
  const float* Wv2 = (const float*)d_in[15];
  const float* bv2 = (const float*)d_in[16];
  const float* Wo2 = (const float*)d_in[17];
  const float* bo2 = (const float*)d_in[18];

  char* ws = (char*)d_ws;
  u16* wt  = (u16*)ws;
  u16* xb  = (u16*)(ws + (16u << 20));
  u16* ekb = (u16*)(ws + (32u << 20));
  u16* evb = (u16*)(ws + (48u << 20));
  u16* qb  = (u16*)(ws + (64u << 20));
  u16* kkb = (u16*)(ws + (80u << 20));
  u16* vtb = (u16*)(ws + (96u << 20));
  u16* hb  = (u16*)(ws + (112u << 20));
  u16* ob  = xb;   // x dead after layer-1 projections

  const int NW = DMODEL * DMODEL;
  const int n4 = MTOT * DMODEL / 4;
  const float qscale = 0.125f * 1.4426950408889634f;   // 1/sqrt(HD) * log2(e)

  pack_act<<<n4 / 256, 256, 0, stream>>>(x,  xb,  n4);
  pack_act<<<n4 / 256, 256, 0, stream>>>(ek, ekb, n4);
  pack_act<<<n4 / 256, 256, 0, stream>>>(ev, evb, n4);

  dim3 wg(16, 16);
  pack_w<<<wg, 256, 0, stream>>>(Wq1, wt + 0 * NW, 1);
  pack_w<<<wg, 256, 0, stream>>>(Wk1, wt + 1 * NW, 1);
  pack_w<<<wg, 256, 0, stream>>>(Wv1, wt + 2 * NW, 1);
  pack_w<<<wg, 256, 0, stream>>>(Wo1, wt + 3 * NW, 0);
  pack_w<<<wg, 256, 0, stream>>>(Wq2, wt + 4 * NW, 1);
  pack_w<<<wg, 256, 0, stream>>>(Wk2, wt + 5 * NW, 1);
  pack_w<<<wg, 256, 0, stream>>>(Wv2, wt + 6 * NW, 1);
  pack_w<<<wg, 256, 0, stream>>>(Wo2, wt + 7 * NW, 0);

  const int gblocks = (MTOT / 128) * (DMODEL / 128);   // 512, XCD-swizzled in-kernel
  const int ablocks = (SEQ / 128) * BSZ * NHEAD;       // 1024 pair-blocks

  // layer 1: causal self-attention
  gemm_bt<0><<<gblocks, 256, 0, stream>>>(xb,  wt + 0 * NW, bq1, qb,  qscale);
  gemm_bt<0><<<gblocks, 256, 0, stream>>>(xb,  wt + 1 * NW, bk1, kkb, 1.0f);
  gemm_bt<1><<<gblocks, 256, 0, stream>>>(xb,  wt + 2 * NW, bv1, vtb, 1.0f);
  attn_kernel<<<ablocks, 256, 0, stream>>>(qb, kkb, vtb, ob, 1);
  gemm_bt<0><<<gblocks, 256, 0, stream>>>(ob,  wt + 3 * NW, bo1, hb,  1.0f);

  // layer 2: cross attention
  gemm_bt<0><<<gblocks, 256, 0, stream>>>(hb,  wt + 4 * NW, bq2, qb,  qscale);
  gemm_bt<0><<<gblocks, 256, 0, stream>>>(ekb, wt + 5 * NW, bk2, kkb, 1.0f);
  gemm_bt<1><<<gblocks, 256, 0, stream>>>(evb, wt + 6 * NW, bv2, vtb, 1.0f);
  attn_kernel<<<ablocks, 256, 0, stream>>>(qb, kkb, vtb, ob, 0);
  gemm_bt<2><<<gblocks, 256, 0, stream>>>(ob,  wt + 7 * NW, bo2, d_out, 1.0f);
}

// Round 10
// 378.626 us; speedup vs baseline: 1.5471x; 1.0804x over previous
//
#include <hip/hip_runtime.h>
#include <hip/hip_bf16.h>
#include <cstdint>

typedef unsigned short u16;
typedef unsigned int   u32;
typedef __attribute__((ext_vector_type(8))) short bf16x8;   // 8 bf16 = 4 VGPRs
typedef __attribute__((ext_vector_type(4))) float f32x4;

#define MFMA16(a,b,c)    __builtin_amdgcn_mfma_f32_16x16x32_bf16((a),(b),(c),0,0,0)

#define BSZ    4
#define SEQ    2048
#define DMODEL 1024
#define NHEAD  16
#define HDIM   64
#define MTOT   (BSZ*SEQ)   // 8192
#define MASKV  (-3.0e38f)  // finite: exp2(MASKV - m) == 0, no inf-inf NaN

// native conversion: compiler lowers to v_cvt_pk_bf16_f32 when paired (m240)
__device__ __forceinline__ u16 f2bf(float f) {
  __hip_bfloat16 h = __float2bfloat16(f);
  return __builtin_bit_cast(u16, h);
}

typedef __attribute__((address_space(1))) void g1v;
typedef __attribute__((address_space(3))) void l3v;
// async global->LDS, 16B/lane. LDS dest is wave-uniform base (HW adds lane*16B).
__device__ __forceinline__ void gload16(const void* g, void* l) {
  __builtin_amdgcn_global_load_lds((g1v*)(uintptr_t)g, (l3v*)(u32)(uintptr_t)l, 16, 0, 0);
}

// ---------------- pack: fp32 -> bf16 activations ----------------
__global__ void pack_act(const float* __restrict__ in, u16* __restrict__ out, int n4) {
  int i = blockIdx.x * blockDim.x + threadIdx.x;
  if (i >= n4) return;
  float4 v = ((const float4*)in)[i];
  u32 lo = (u32)f2bf(v.x) | ((u32)f2bf(v.y) << 16);
  u32 hi = (u32)f2bf(v.z) | ((u32)f2bf(v.w) << 16);
  ((uint2*)out)[i] = make_uint2(lo, hi);
}

// ---------------- pack: weights -> Bt[n][k] bf16 (transposed) ----------------
__global__ void pack_w(const float* __restrict__ src, u16* __restrict__ dst, int per_head) {
  __shared__ float tile[64][65];
  int kt = blockIdx.x * 64, nt = blockIdx.y * 64;
  int tx = threadIdx.x & 63, ty = threadIdx.x >> 6;
  for (int kk = ty; kk < 64; kk += 4) {
    int k = kt + kk, n = nt + tx;
    float v = per_head ? src[(size_t)(n >> 6) * (DMODEL * HDIM) + (size_t)k * HDIM + (n & 63)]
                       : src[(size_t)k * DMODEL + n];
    tile[kk][tx] = v;
  }
  __syncthreads();
  for (int nn = ty; nn < 64; nn += 4)
    dst[(size_t)(nt + nn) * DMODEL + kt + tx] = f2bf(tile[tx][nn]);
}

// ---------------- GEMM v3: BK=64, double-buffered 2-phase prefetch ----------------
// C[M,N] = (A[M,K] @ Bt[N,K]^T + bias) * scale. 128x128 tile, 4 waves, 16 K-steps,
// one barrier per step: issue next-tile global_load_lds BEFORE computing current
// (attn-style prefetch; staging latency hides under 32 MFMA + ds_reads).
// 128B LDS rows with XOR-chunk swizzle c^=(row&7); staging pre-swizzles the source.
// XCD-swizzled 1D grid. EPI 1 stores Vt with s-permuted layout (see attn).
template <int EPI>
__global__ __launch_bounds__(256, 2)
void gemm_bt(const u16* __restrict__ A, const u16* __restrict__ Bt,
             const float* __restrict__ bias, void* __restrict__ Cout, float scale)
{
  __shared__ u16 As[2][128 * 64];
  __shared__ u16 Bs[2][128 * 64];
  const int lane = threadIdx.x & 63, wid = threadIdx.x >> 6;
  const int wg = ((blockIdx.x & 7) << 6) | (blockIdx.x >> 3);  // [xcd:3][seq:6]
  const int m0 = (wg >> 3) * 128, n0 = (wg & 7) * 128;

  // staging: wave covers rows wid*32..+31; instr i = 8 rows x 8 chunks (16B)
  const int srow = wid * 32 + (lane >> 3);          // +i*8; (row&7) == lane>>3
  const int sc = (lane & 7) ^ ((lane >> 3) & 7);    // pre-swizzled source chunk
  const u16* gA = A  + (size_t)(m0 + srow) * DMODEL + sc * 8;
  const u16* gB = Bt + (size_t)(n0 + srow) * DMODEL + sc * 8;

  const int fr = lane & 15, quad = lane >> 4;
  const int wr = (wid >> 1) * 64, wc = (wid & 1) * 64;

  f32x4 acc[4][4] = {};
  const int NT = DMODEL / 64;   // 16

  // prologue: stage tile 0 into buf 0
#pragma unroll
  for (int i = 0; i < 4; ++i) {
    gload16(gA + (size_t)(i * 8) * DMODEL, &As[0][(wid * 32 + i * 8) * 64]);
    gload16(gB + (size_t)(i * 8) * DMODEL, &Bs[0][(wid * 32 + i * 8) * 64]);
  }
  gA += 64; gB += 64;
  __syncthreads();

  for (int kt = 0; kt < NT; ++kt) {
    const int cur = kt & 1;
    if (kt + 1 < NT) {
#pragma unroll
      for (int i = 0; i < 4; ++i) {
        gload16(gA + (size_t)(i * 8) * DMODEL, &As[cur ^ 1][(wid * 32 + i * 8) * 64]);
        gload16(gB + (size_t)(i * 8) * DMODEL, &Bs[cur ^ 1][(wid * 32 + i * 8) * 64]);
      }
      gA += 64; gB += 64;
    }
#pragma unroll
    for (int kp = 0; kp < 2; ++kp) {
      bf16x8 af[4], bfr[4];
#pragma unroll
      for (int i = 0; i < 4; ++i) {
        int ra = wr + i * 16 + fr;
        af[i]  = *(const bf16x8*)&As[cur][ra * 64 + (((kp * 4 + quad) ^ (ra & 7)) * 8)];
        int rb = wc + i * 16 + fr;
        bfr[i] = *(const bf16x8*)&Bs[cur][rb * 64 + (((kp * 4 + quad) ^ (rb & 7)) * 8)];
      }
#pragma unroll
      for (int i = 0; i < 4; ++i)
#pragma unroll
        for (int j = 0; j < 4; ++j)
          acc[i][j] = MFMA16(af[i], bfr[j], acc[i][j]);
    }
    __syncthreads();   // buf[cur] reads done; buf[cur^1] staging drained (vmcnt 0)
  }

  // C/D layout: col = lane&15, row = (lane>>4)*4 + reg
#pragma unroll
  for (int i = 0; i < 4; ++i) {
    int row0 = m0 + wr + i * 16 + quad * 4;
#pragma unroll
    for (int j = 0; j < 4; ++j) {
      int col = n0 + wc + j * 16 + fr;
      float bv = bias[col];
      float v0 = (acc[i][j][0] + bv) * scale, v1 = (acc[i][j][1] + bv) * scale;
      float v2 = (acc[i][j][2] + bv) * scale, v3 = (acc[i][j][3] + bv) * scale;
      if constexpr (EPI == 2) {
        float* C = (float*)Cout;
        C[(size_t)(row0 + 0) * DMODEL + col] = v0;
        C[(size_t)(row0 + 1) * DMODEL + col] = v1;
        C[(size_t)(row0 + 2) * DMODEL + col] = v2;
        C[(size_t)(row0 + 3) * DMODEL + col] = v3;
      } else if constexpr (EPI == 0) {
        u16* C = (u16*)Cout;
        C[(size_t)(row0 + 0) * DMODEL + col] = f2bf(v0);
        C[(size_t)(row0 + 1) * DMODEL + col] = f2bf(v1);
        C[(size_t)(row0 + 2) * DMODEL + col] = f2bf(v2);
        C[(size_t)(row0 + 3) * DMODEL + col] = f2bf(v3);
      } else {
        u16* C = (u16*)Cout;
        int bi = row0 >> 11, s = row0 & 2047;
        // permuted s within 32-group: (b:1|c:2|r:2) -> (c:2|b:1|r:2)
        int sN = (s & ~31) | (((s >> 2) & 3) << 3) | (((s >> 4) & 1) << 2) | (s & 3);
        size_t vtr = ((size_t)(bi * NHEAD + (col >> 6)) * HDIM + (col & 63)) * SEQ + sN;
        *(uint2*)&C[vtr] = make_uint2((u32)f2bf(v0) | ((u32)f2bf(v1) << 16),
                                      (u32)f2bf(v2) | ((u32)f2bf(v3) << 16));
      }
    }
  }
}

// ---------------- flash attention v10 ----------------
// v9 + K=32 PV: key-axis relabeling (slot quad*8+kblk*4+r <-> key kblk*16+quad*4+r)
// lets the 8 lane-local P values form a full 16x16x32 A-frag, and the s-permuted
// Vt b128 read already delivers V rows in matching order => 8 MFMA16 instead of
// 16 K16 MFMAs per step. Split-K waves 2x2, swapped QK^T, zero-shuffle P,
// 1024 pair-blocks (causal = uniform 33 steps), XCD-swizzled.
__global__ __launch_bounds__(256, 4)
void attn_kernel(const u16* __restrict__ Q, const u16* __restrict__ K,
                 const u16* __restrict__ Vt, u16* __restrict__ O, int causal)
{
  __shared__ u16 KV[4][64 * 64];   // [0,1]=K dbuf, [2,3]=V dbuf; merge reuses as f32
  const int lane = threadIdx.x & 63, wid = threadIdx.x >> 6;
  const int fr = lane & 15, quad = lane >> 4;
  const int wq = wid >> 1, wk = wid & 1;

  const int flat = blockIdx.x;
  const int bh = ((flat >> 7) << 3) | (flat & 7);
  const int pair = (flat >> 3) & 15;
  const int b = bh >> 4, h = bh & 15;

  // loop-invariant swizzled LDS element offsets
  const int xk0 = ((quad    ) ^ (fr & 7)) * 8;
  const int xk1 = ((quad + 4) ^ (fr & 7)) * 8;
  const int xv  = ((wk * 4 + quad) ^ (fr & 7)) * 8;   // one b128: full K=32 B-frag

  const int srow = wid * 16 + (lane >> 3);
  const int jg = (lane & 7) ^ (srow & 7);   // same for srow and srow+8
  const u16* kg = K + (size_t)b * SEQ * DMODEL + h * HDIM;
  const u16* vg = Vt + (size_t)bh * HDIM * SEQ;
  const u16* ks0 = kg + (size_t)srow * DMODEL + jg * 8;
  const u16* vs0 = vg + (size_t)srow * SEQ + jg * 8;
  float* mbuf = (float*)&KV[0][0];          // merge scratch (25.6KB < 32KB)

  for (int tile = 0; tile < 2; ++tile) {
    const int qb = tile == 0 ? (31 - pair) : pair;
    const int q0 = qb * 64;
    const int qbase = q0 + wq * 32;

    bf16x8 aq[2][2];
#pragma unroll
    for (int nb = 0; nb < 2; ++nb) {
      const u16* qp = Q + (size_t)(b * SEQ + qbase + nb * 16 + fr) * DMODEL + h * HDIM + quad * 8;
      aq[nb][0] = *(const bf16x8*)qp;
      aq[nb][1] = *(const bf16x8*)(qp + 32);
    }

    f32x4 oacc[2][4] = {};
    float mrow[2] = {-1e30f, -1e30f};
    float lp[2]   = {0.f, 0.f};

    const int nsteps = (causal ? (q0 + 64) : SEQ) >> 6;

    // prologue: stage tile 0 into bufs {0, 2}
    gload16(ks0,              &KV[0][(wid * 16 + 0) * 64]);
    gload16(ks0 + 8 * DMODEL, &KV[0][(wid * 16 + 8) * 64]);
    gload16(vs0,              &KV[2][(wid * 16 + 0) * 64]);
    gload16(vs0 + 8 * SEQ,    &KV[2][(wid * 16 + 8) * 64]);
    const u16* kpre = ks0 + 64 * DMODEL;
    const u16* vpre = vs0 + 64;
    __syncthreads();

    for (int t = 0; t < nsteps; ++t) {
      const int cur = t & 1;
      const int kb = t * 64;
      if (t + 1 < nsteps) {
        gload16(kpre,              &KV[cur ^ 1][(wid * 16 + 0) * 64]);
        gload16(kpre + 8 * DMODEL, &KV[cur ^ 1][(wid * 16 + 8) * 64]);
        gload16(vpre,              &KV[2 + (cur ^ 1)][(wid * 16 + 0) * 64]);
        gload16(vpre + 8 * SEQ,    &KV[2 + (cur ^ 1)][(wid * 16 + 8) * 64]);
        kpre += 64 * DMODEL; vpre += 64;
      }
      // swapped QK^T: sa[kblk][nb][r] = S[key=kb+wk*32+kblk*16+quad*4+r][q=qbase+nb*16+fr]
      const u16* kr0 = &KV[cur][(wk * 32 + fr) * 64];
      f32x4 sa[2][2];
      __builtin_amdgcn_s_setprio(1);
      {
        bf16x8 kfa = *(const bf16x8*)&kr0[xk0];
        bf16x8 kfb = *(const bf16x8*)&kr0[xk1];
        f32x4 s = {};
        s = MFMA16(kfa, aq[0][0], s); s = MFMA16(kfb, aq[0][1], s); sa[0][0] = s;
        s = (f32x4){};
        s = MFMA16(kfa, aq[1][0], s); s = MFMA16(kfb, aq[1][1], s); sa[0][1] = s;
        kfa = *(const bf16x8*)&kr0[16 * 64 + xk0];
        kfb = *(const bf16x8*)&kr0[16 * 64 + xk1];
        s = (f32x4){};
        s = MFMA16(kfa, aq[0][0], s); s = MFMA16(kfb, aq[0][1], s); sa[1][0] = s;
        s = (f32x4){};
        s = MFMA16(kfa, aq[1][0], s); s = MFMA16(kfb, aq[1][1], s); sa[1][1] = s;
      }
      __builtin_amdgcn_s_setprio(0);

      if (causal && kb + wk * 32 + 31 > qbase) {   // wave-uniform diagonal check
#pragma unroll
        for (int kblk = 0; kblk < 2; ++kblk)
#pragma unroll
          for (int nb = 0; nb < 2; ++nb) {
            int key = kb + wk * 32 + kblk * 16 + quad * 4;
            int q   = qbase + nb * 16 + fr;
#pragma unroll
            for (int r = 0; r < 4; ++r)
              if (key + r > q) sa[kblk][nb][r] = MASKV;
          }
      }

      // ---- defer-max softmax (lane-local partials) ----
      float lm[2];
#pragma unroll
      for (int nb = 0; nb < 2; ++nb) {
        f32x4 mx4 = sa[0][nb];
        mx4[0] = fmaxf(mx4[0], sa[1][nb][0]); mx4[1] = fmaxf(mx4[1], sa[1][nb][1]);
        mx4[2] = fmaxf(mx4[2], sa[1][nb][2]); mx4[3] = fmaxf(mx4[3], sa[1][nb][3]);
        lm[nb] = fmaxf(fmaxf(mx4[0], mx4[1]), fmaxf(mx4[2], mx4[3]));
      }
      int ok = (lm[0] <= mrow[0] + 11.f) & (lm[1] <= mrow[1] + 11.f);
      if (!__all(ok)) {
#pragma unroll
        for (int nb = 0; nb < 2; ++nb) {
          float mx = lm[nb];
          mx = fmaxf(mx, __shfl_xor(mx, 16));
          mx = fmaxf(mx, __shfl_xor(mx, 32));
          float mnew = fmaxf(mrow[nb], mx);
          float a = __builtin_amdgcn_exp2f(mrow[nb] - mnew);
          mrow[nb] = mnew;
          lp[nb] *= a;
#pragma unroll
          for (int r = 0; r < 4; ++r) {
            float ar = __shfl(a, (lane & 48) | (quad * 4 + r));
            oacc[nb][0][r] *= ar; oacc[nb][1][r] *= ar;
            oacc[nb][2][r] *= ar; oacc[nb][3][r] *= ar;
          }
        }
      }

      // exp2 + pack P^T into one K=32 A-frag per nb (slot = quad*8 + kblk*4 + r)
      bf16x8 pa32[2];
#pragma unroll
      for (int nb = 0; nb < 2; ++nb) {
        bf16x8 pk;
#pragma unroll
        for (int kblk = 0; kblk < 2; ++kblk) {
          float p0 = __builtin_amdgcn_exp2f(sa[kblk][nb][0] - mrow[nb]);
          float p1 = __builtin_amdgcn_exp2f(sa[kblk][nb][1] - mrow[nb]);
          float p2 = __builtin_amdgcn_exp2f(sa[kblk][nb][2] - mrow[nb]);
          float p3 = __builtin_amdgcn_exp2f(sa[kblk][nb][3] - mrow[nb]);
          lp[nb] += (p0 + p1) + (p2 + p3);
          pk[kblk * 4 + 0] = (short)f2bf(p0); pk[kblk * 4 + 1] = (short)f2bf(p1);
          pk[kblk * 4 + 2] = (short)f2bf(p2); pk[kblk * 4 + 3] = (short)f2bf(p3);
        }
        pa32[nb] = pk;
      }

      // PV K=32: one b128 per d-block (s-permuted Vt rows match pa32's key order)
      __builtin_amdgcn_s_setprio(1);
#pragma unroll
      for (int db = 0; db < 4; ++db) {
        const u16* vr = &KV[2 + cur][(db * 16 + fr) * 64];
        bf16x8 vv = *(const bf16x8*)&vr[xv];
        oacc[0][db] = MFMA16(pa32[0], vv, oacc[0][db]);
        oacc[1][db] = MFMA16(pa32[1], vv, oacc[1][db]);
      }
      __builtin_amdgcn_s_setprio(0);
      __syncthreads();   // buf[cur] reads done; buf[cur^1] staging drained
    }

    // ---- tile epilogue: finalize within wave, 2-way split-K merge across wk ----
#pragma unroll
    for (int nb = 0; nb < 2; ++nb) {
      lp[nb] += __shfl_xor(lp[nb], 16);
      lp[nb] += __shfl_xor(lp[nb], 32);
    }
    float mr2[2][4], lr2[2][4];
#pragma unroll
    for (int nb = 0; nb < 2; ++nb)
#pragma unroll
      for (int r = 0; r < 4; ++r) {
        int src = (lane & 48) | (quad * 4 + r);
        mr2[nb][r] = __shfl(mrow[nb], src);
        lr2[nb][r] = __shfl(lp[nb],   src);
      }
    float* mp = mbuf + (size_t)(wq * 64 + lane) * 50;
    if (wk) {
#pragma unroll
      for (int nb = 0; nb < 2; ++nb)
#pragma unroll
        for (int db = 0; db < 4; ++db) {
          *(float2*)&mp[(nb * 4 + db) * 4 + 0] = make_float2(oacc[nb][db][0], oacc[nb][db][1]);
          *(float2*)&mp[(nb * 4 + db) * 4 + 2] = make_float2(oacc[nb][db][2], oacc[nb][db][3]);
        }
#pragma unroll
      for (int nb = 0; nb < 2; ++nb) {
        *(float2*)&mp[32 + nb * 4 + 0] = make_float2(mr2[nb][0], mr2[nb][1]);
        *(float2*)&mp[32 + nb * 4 + 2] = make_float2(mr2[nb][2], mr2[nb][3]);
        *(float2*)&mp[40 + nb * 4 + 0] = make_float2(lr2[nb][0], lr2[nb][1]);
        *(float2*)&mp[40 + nb * 4 + 2] = make_float2(lr2[nb][2], lr2[nb][3]);
      }
    }
    __syncthreads();
    if (!wk) {
      float w0[2][4], w1[2][4];
#pragma unroll
      for (int nb = 0; nb < 2; ++nb)
#pragma unroll
        for (int r = 0; r < 4; ++r) {
          float m1 = mp[32 + nb * 4 + r];
          float l1 = mp[40 + nb * 4 + r];
          float M  = fmaxf(mr2[nb][r], m1);
          float c0 = __builtin_amdgcn_exp2f(mr2[nb][r] - M);
          float c1 = __builtin_amdgcn_exp2f(m1 - M);
          float inv = 1.0f / (lr2[nb][r] * c0 + l1 * c1);
          w0[nb][r] = c0 * inv;
          w1[nb][r] = c1 * inv;
        }
#pragma unroll
      for (int nb = 0; nb < 2; ++nb) {
        u16* op = O + (size_t)(b * SEQ + qbase + nb * 16 + quad * 4) * DMODEL + h * HDIM + fr;
#pragma unroll
        for (int db = 0; db < 4; ++db) {
          float2 oa = *(float2*)&mp[(nb * 4 + db) * 4 + 0];
          float2 ob = *(float2*)&mp[(nb * 4 + db) * 4 + 2];
          float o1[4] = {oa.x, oa.y, ob.x, ob.y};
#pragma unroll
          for (int r = 0; r < 4; ++r)
            op[(size_t)r * DMODEL + db * 16] =
                f2bf(oacc[nb][db][r] * w0[nb][r] + o1[r] * w1[nb][r]);
        }
      }
    }
    __syncthreads();   // merge reads done before next tile's staging reuses KV
  }
}

// ---------------- launcher ----------------
extern "C" void kernel_launch(void* const* d_in, const int* in_sizes, int n_in,
                              void* d_out, int out_size, void* d_ws, size_t ws_size,
                              hipStream_t stream)
{
  const float* x   = (const float*)d_in[0];
  const float* ek  = (const float*)d_in[1];
  const float* ev  = (const float*)d_in[2];
  const float* Wq1 = (const float*)d_in[3];
  const float* bq1 = (const float*)d_in[4];
  const float* Wk1 = (const float*)d_in[5];
  const float* bk1 = (const float*)d_in[6];
  const float* Wv1 = (const float*)d_in[7];
  const float* bv1 = (const float*)d_in[8];
  const float* Wo1 = (const float*)d_in[9];
  const float* bo1 = (const float*)d_in[10];
  const float* Wq2 = (const float*)d_in[11];
  const float* bq2 = (const float*)d_in[12];
  const float* Wk2 = (const float*)d_in[13];
  const float* bk2 = (const float*)d_in[14];
  const float* Wv2 = (const float*)d_in[15];
  const float* bv2 = (const float*)d_in[16];
  const float* Wo2 = (const float*)d_in[17];
  const float* bo2 = (const float*)d_in[18];

  char* ws = (char*)d_ws;
  u16* wt  = (u16*)ws;
  u16* xb  = (u16*)(ws + (16u << 20));
  u16* ekb = (u16*)(ws + (32u << 20));
  u16* evb = (u16*)(ws + (48u << 20));
  u16* qb  = (u16*)(ws + (64u << 20));
  u16* kkb = (u16*)(ws + (80u << 20));
  u16* vtb = (u16*)(ws + (96u << 20));
  u16* hb  = (u16*)(ws + (112u << 20));
  u16* ob  = xb;   // x dead after layer-1 projections

  const int NW = DMODEL * DMODEL;
  const int n4 = MTOT * DMODEL / 4;
  const float qscale = 0.125f * 1.4426950408889634f;   // 1/sqrt(HD) * log2(e)

  pack_act<<<n4 / 256, 256, 0, stream>>>(x,  xb,  n4);
  pack_act<<<n4 / 256, 256, 0, stream>>>(ek, ekb, n4);
  pack_act<<<n4 / 256, 256, 0, stream>>>(ev, evb, n4);

  dim3 wg(16, 16);
  pack_w<<<wg, 256, 0, stream>>>(Wq1, wt + 0 * NW, 1);
  pack_w<<<wg, 256, 0, stream>>>(Wk1, wt + 1 * NW, 1);
  pack_w<<<wg, 256, 0, stream>>>(Wv1, wt + 2 * NW, 1);
  pack_w<<<wg, 256, 0, stream>>>(Wo1, wt + 3 * NW, 0);
  pack_w<<<wg, 256, 0, stream>>>(Wq2, wt + 4 * NW, 1);
  pack_w<<<wg, 256, 0, stream>>>(Wk2, wt + 5 * NW, 1);
  pack_w<<<wg, 256, 0, stream>>>(Wv2, wt + 6 * NW, 1);
  pack_w<<<wg, 256, 0, stream>>>(Wo2, wt + 7 * NW, 0);

  const int gblocks = (MTOT / 128) * (DMODEL / 128);   // 512, XCD-swizzled in-kernel
  const int ablocks = (SEQ / 128) * BSZ * NHEAD;       // 1024 pair-blocks

  // layer 1: causal self-attention
  gemm_bt<0><<<gblocks, 256, 0, stream>>>(xb,  wt + 0 * NW, bq1, qb,  qscale);
  gemm_bt<0><<<gblocks, 256, 0, stream>>>(xb,  wt + 1 * NW, bk1, kkb, 1.0f);
  gemm_bt<1><<<gblocks, 256, 0, stream>>>(xb,  wt + 2 * NW, bv1, vtb, 1.0f);
  attn_kernel<<<ablocks, 256, 0, stream>>>(qb, kkb, vtb, ob, 1);
  gemm_bt<0><<<gblocks, 256, 0, stream>>>(ob,  wt + 3 * NW, bo1, hb,  1.0f);

  // layer 2: cross attention
  gemm_bt<0><<<gblocks, 256, 0, stream>>>(hb,  wt + 4 * NW, bq2, qb,  qscale);
  gemm_bt<0><<<gblocks, 256, 0, stream>>>(ekb, wt + 5 * NW, bk2, kkb, 1.0f);
  gemm_bt<1><<<gblocks, 256, 0, stream>>>(evb, wt + 6 * NW, bv2, vtb, 1.0f);
  attn_kernel<<<ablocks, 256, 0, stream>>>(qb, kkb, vtb, ob, 0);
  gemm_bt<2><<<gblocks, 256, 0, stream>>>(ob,  wt + 7 * NW, bo2, d_out, 1.0f);
}

// Round 11
// 377.426 us; speedup vs baseline: 1.5521x; 1.0032x over previous
//
#include <hip/hip_runtime.h>
#include <hip/hip_bf16.h>
#include <cstdint>

typedef unsigned short u16;
typedef unsigned int   u32;
typedef __attribute__((ext_vector_type(8))) short bf16x8;   // 8 bf16 = 4 VGPRs
typedef __attribute__((ext_vector_type(4))) float f32x4;

#define MFMA16(a,b,c)    __builtin_amdgcn_mfma_f32_16x16x32_bf16((a),(b),(c),0,0,0)

#define BSZ    4
#define SEQ    2048
#define DMODEL 1024
#define NHEAD  16
#define HDIM   64
#define MTOT   (BSZ*SEQ)   // 8192
#define MASKV  (-3.0e38f)  // finite: exp2(MASKV - m) == 0, no inf-inf NaN

// native conversion: compiler lowers to v_cvt_pk_bf16_f32 when paired (m240)
__device__ __forceinline__ u16 f2bf(float f) {
  __hip_bfloat16 h = __float2bfloat16(f);
  return __builtin_bit_cast(u16, h);
}

typedef __attribute__((address_space(1))) void g1v;
typedef __attribute__((address_space(3))) void l3v;
// async global->LDS, 16B/lane. LDS dest is wave-uniform base (HW adds lane*16B).
__device__ __forceinline__ void gload16(const void* g, void* l) {
  __builtin_amdgcn_global_load_lds((g1v*)(uintptr_t)g, (l3v*)(u32)(uintptr_t)l, 16, 0, 0);
}

// ---------------- pack: fp32 -> bf16 activations ----------------
__global__ void pack_act(const float* __restrict__ in, u16* __restrict__ out, int n4) {
  int i = blockIdx.x * blockDim.x + threadIdx.x;
  if (i >= n4) return;
  float4 v = ((const float4*)in)[i];
  u32 lo = (u32)f2bf(v.x) | ((u32)f2bf(v.y) << 16);
  u32 hi = (u32)f2bf(v.z) | ((u32)f2bf(v.w) << 16);
  ((uint2*)out)[i] = make_uint2(lo, hi);
}

// ---------------- pack: weights -> Bt[n][k] bf16 (transposed) ----------------
__global__ void pack_w(const float* __restrict__ src, u16* __restrict__ dst, int per_head) {
  __shared__ float tile[64][65];
  int kt = blockIdx.x * 64, nt = blockIdx.y * 64;
  int tx = threadIdx.x & 63, ty = threadIdx.x >> 6;
  for (int kk = ty; kk < 64; kk += 4) {
    int k = kt + kk, n = nt + tx;
    float v = per_head ? src[(size_t)(n >> 6) * (DMODEL * HDIM) + (size_t)k * HDIM + (n & 63)]
                       : src[(size_t)k * DMODEL + n];
    tile[kk][tx] = v;
  }
  __syncthreads();
  for (int nn = ty; nn < 64; nn += 4)
    dst[(size_t)(nt + nn) * DMODEL + kt + tx] = f2bf(tile[tx][nn]);
}

// ---------------- GEMM v3: BK=64, double-buffered 2-phase prefetch ----------------
// C[M,N] = (A[M,K] @ Bt[N,K]^T + bias) * scale. 128x128 tile, 4 waves, 16 K-steps,
// one barrier per step: issue next-tile global_load_lds BEFORE computing current
// (attn-style prefetch; staging latency hides under 32 MFMA + ds_reads).
// 128B LDS rows with XOR-chunk swizzle c^=(row&7); staging pre-swizzles the source.
// XCD-swizzled 1D grid. EPI 1 stores Vt with s-permuted layout (see attn).
template <int EPI>
__global__ __launch_bounds__(256, 2)
void gemm_bt(const u16* __restrict__ A, const u16* __restrict__ Bt,
             const float* __restrict__ bias, void* __restrict__ Cout, float scale)
{
  __shared__ u16 As[2][128 * 64];
  __shared__ u16 Bs[2][128 * 64];
  const int lane = threadIdx.x & 63, wid = threadIdx.x >> 6;
  const int wg = ((blockIdx.x & 7) << 6) | (blockIdx.x >> 3);  // [xcd:3][seq:6]
  const int m0 = (wg >> 3) * 128, n0 = (wg & 7) * 128;

  // staging: wave covers rows wid*32..+31; instr i = 8 rows x 8 chunks (16B)
  const int srow = wid * 32 + (lane >> 3);          // +i*8; (row&7) == lane>>3
  const int sc = (lane & 7) ^ ((lane >> 3) & 7);    // pre-swizzled source chunk
  const u16* gA = A  + (size_t)(m0 + srow) * DMODEL + sc * 8;
  const u16* gB = Bt + (size_t)(n0 + srow) * DMODEL + sc * 8;

  const int fr = lane & 15, quad = lane >> 4;
  const int wr = (wid >> 1) * 64, wc = (wid & 1) * 64;

  f32x4 acc[4][4] = {};
  const int NT = DMODEL / 64;   // 16

  // prologue: stage tile 0 into buf 0
#pragma unroll
  for (int i = 0; i < 4; ++i) {
    gload16(gA + (size_t)(i * 8) * DMODEL, &As[0][(wid * 32 + i * 8) * 64]);
    gload16(gB + (size_t)(i * 8) * DMODEL, &Bs[0][(wid * 32 + i * 8) * 64]);
  }
  gA += 64; gB += 64;
  __syncthreads();

  for (int kt = 0; kt < NT; ++kt) {
    const int cur = kt & 1;
    if (kt + 1 < NT) {
#pragma unroll
      for (int i = 0; i < 4; ++i) {
        gload16(gA + (size_t)(i * 8) * DMODEL, &As[cur ^ 1][(wid * 32 + i * 8) * 64]);
        gload16(gB + (size_t)(i * 8) * DMODEL, &Bs[cur ^ 1][(wid * 32 + i * 8) * 64]);
      }
      gA += 64; gB += 64;
    }
#pragma unroll
    for (int kp = 0; kp < 2; ++kp) {
      bf16x8 af[4], bfr[4];
#pragma unroll
      for (int i = 0; i < 4; ++i) {
        int ra = wr + i * 16 + fr;
        af[i]  = *(const bf16x8*)&As[cur][ra * 64 + (((kp * 4 + quad) ^ (ra & 7)) * 8)];
        int rb = wc + i * 16 + fr;
        bfr[i] = *(const bf16x8*)&Bs[cur][rb * 64 + (((kp * 4 + quad) ^ (rb & 7)) * 8)];
      }
#pragma unroll
      for (int i = 0; i < 4; ++i)
#pragma unroll
        for (int j = 0; j < 4; ++j)
          acc[i][j] = MFMA16(af[i], bfr[j], acc[i][j]);
    }
    __syncthreads();   // buf[cur] reads done; buf[cur^1] staging drained (vmcnt 0)
  }

  // C/D layout: col = lane&15, row = (lane>>4)*4 + reg
#pragma unroll
  for (int i = 0; i < 4; ++i) {
    int row0 = m0 + wr + i * 16 + quad * 4;
#pragma unroll
    for (int j = 0; j < 4; ++j) {
      int col = n0 + wc + j * 16 + fr;
      float bv = bias[col];
      float v0 = (acc[i][j][0] + bv) * scale, v1 = (acc[i][j][1] + bv) * scale;
      float v2 = (acc[i][j][2] + bv) * scale, v3 = (acc[i][j][3] + bv) * scale;
      if constexpr (EPI == 2) {
        float* C = (float*)Cout;
        C[(size_t)(row0 + 0) * DMODEL + col] = v0;
        C[(size_t)(row0 + 1) * DMODEL + col] = v1;
        C[(size_t)(row0 + 2) * DMODEL + col] = v2;
        C[(size_t)(row0 + 3) * DMODEL + col] = v3;
      } else if constexpr (EPI == 0) {
        u16* C = (u16*)Cout;
        C[(size_t)(row0 + 0) * DMODEL + col] = f2bf(v0);
        C[(size_t)(row0 + 1) * DMODEL + col] = f2bf(v1);
        C[(size_t)(row0 + 2) * DMODEL + col] = f2bf(v2);
        C[(size_t)(row0 + 3) * DMODEL + col] = f2bf(v3);
      } else {
        u16* C = (u16*)Cout;
        int bi = row0 >> 11, s = row0 & 2047;
        // permuted s within 32-group: (b:1|c:2|r:2) -> (c:2|b:1|r:2)
        int sN = (s & ~31) | (((s >> 2) & 3) << 3) | (((s >> 4) & 1) << 2) | (s & 3);
        size_t vtr = ((size_t)(bi * NHEAD + (col >> 6)) * HDIM + (col & 63)) * SEQ + sN;
        *(uint2*)&C[vtr] = make_uint2((u32)f2bf(v0) | ((u32)f2bf(v1) << 16),
                                      (u32)f2bf(v2) | ((u32)f2bf(v3) << 16));
      }
    }
  }
}

// ---------------- flash attention v10 ----------------
// v9 + K=32 PV: key-axis relabeling (slot quad*8+kblk*4+r <-> key kblk*16+quad*4+r)
// lets the 8 lane-local P values form a full 16x16x32 A-frag, and the s-permuted
// Vt b128 read already delivers V rows in matching order => 8 MFMA16 instead of
// 16 K16 MFMAs per step. Split-K waves 2x2, swapped QK^T, zero-shuffle P,
// 1024 pair-blocks (causal = uniform 33 steps), XCD-swizzled.
__global__ __launch_bounds__(256, 4)
void attn_kernel(const u16* __restrict__ Q, const u16* __restrict__ K,
                 const u16* __restrict__ Vt, u16* __restrict__ O, int causal)
{
  __shared__ u16 KV[4][64 * 64];   // [0,1]=K dbuf, [2,3]=V dbuf; merge reuses as f32
  const int lane = threadIdx.x & 63, wid = threadIdx.x >> 6;
  const int fr = lane & 15, quad = lane >> 4;
  const int wq = wid >> 1, wk = wid & 1;

  const int flat = blockIdx.x;
  const int bh = ((flat >> 7) << 3) | (flat & 7);
  const int pair = (flat >> 3) & 15;
  const int b = bh >> 4, h = bh & 15;

  // loop-invariant swizzled LDS element offsets
  const int xk0 = ((quad    ) ^ (fr & 7)) * 8;
  const int xk1 = ((quad + 4) ^ (fr & 7)) * 8;
  const int xv  = ((wk * 4 + quad) ^ (fr & 7)) * 8;   // one b128: full K=32 B-frag

  const int srow = wid * 16 + (lane >> 3);
  const int jg = (lane & 7) ^ (srow & 7);   // same for srow and srow+8
  const u16* kg = K + (size_t)b * SEQ * DMODEL + h * HDIM;
  const u16* vg = Vt + (size_t)bh * HDIM * SEQ;
  const u16* ks0 = kg + (size_t)srow * DMODEL + jg * 8;
  const u16* vs0 = vg + (size_t)srow * SEQ + jg * 8;
  float* mbuf = (float*)&KV[0][0];          // merge scratch (25.6KB < 32KB)

  for (int tile = 0; tile < 2; ++tile) {
    const int qb = tile == 0 ? (31 - pair) : pair;
    const int q0 = qb * 64;
    const int qbase = q0 + wq * 32;

    bf16x8 aq[2][2];
#pragma unroll
    for (int nb = 0; nb < 2; ++nb) {
      const u16* qp = Q + (size_t)(b * SEQ + qbase + nb * 16 + fr) * DMODEL + h * HDIM + quad * 8;
      aq[nb][0] = *(const bf16x8*)qp;
      aq[nb][1] = *(const bf16x8*)(qp + 32);
    }

    f32x4 oacc[2][4] = {};
    float mrow[2] = {-1e30f, -1e30f};
    float lp[2]   = {0.f, 0.f};

    const int nsteps = (causal ? (q0 + 64) : SEQ) >> 6;

    // prologue: stage tile 0 into bufs {0, 2}
    gload16(ks0,              &KV[0][(wid * 16 + 0) * 64]);
    gload16(ks0 + 8 * DMODEL, &KV[0][(wid * 16 + 8) * 64]);
    gload16(vs0,              &KV[2][(wid * 16 + 0) * 64]);
    gload16(vs0 + 8 * SEQ,    &KV[2][(wid * 16 + 8) * 64]);
    const u16* kpre = ks0 + 64 * DMODEL;
    const u16* vpre = vs0 + 64;
    __syncthreads();

    for (int t = 0; t < nsteps; ++t) {
      const int cur = t & 1;
      const int kb = t * 64;
      if (t + 1 < nsteps) {
        gload16(kpre,              &KV[cur ^ 1][(wid * 16 + 0) * 64]);
        gload16(kpre + 8 * DMODEL, &KV[cur ^ 1][(wid * 16 + 8) * 64]);
        gload16(vpre,              &KV[2 + (cur ^ 1)][(wid * 16 + 0) * 64]);
        gload16(vpre + 8 * SEQ,    &KV[2 + (cur ^ 1)][(wid * 16 + 8) * 64]);
        kpre += 64 * DMODEL; vpre += 64;
      }
      // swapped QK^T: sa[kblk][nb][r] = S[key=kb+wk*32+kblk*16+quad*4+r][q=qbase+nb*16+fr]
      const u16* kr0 = &KV[cur][(wk * 32 + fr) * 64];
      f32x4 sa[2][2];
      __builtin_amdgcn_s_setprio(1);
      {
        bf16x8 kfa = *(const bf16x8*)&kr0[xk0];
        bf16x8 kfb = *(const bf16x8*)&kr0[xk1];
        f32x4 s = {};
        s = MFMA16(kfa, aq[0][0], s); s = MFMA16(kfb, aq[0][1], s); sa[0][0] = s;
        s = (f32x4){};
        s = MFMA16(kfa, aq[1][0], s); s = MFMA16(kfb, aq[1][1], s); sa[0][1] = s;
        kfa = *(const bf16x8*)&kr0[16 * 64 + xk0];
        kfb = *(const bf16x8*)&kr0[16 * 64 + xk1];
        s = (f32x4){};
        s = MFMA16(kfa, aq[0][0], s); s = MFMA16(kfb, aq[0][1], s); sa[1][0] = s;
        s = (f32x4){};
        s = MFMA16(kfa, aq[1][0], s); s = MFMA16(kfb, aq[1][1], s); sa[1][1] = s;
      }
      __builtin_amdgcn_s_setprio(0);

      if (causal && kb + wk * 32 + 31 > qbase) {   // wave-uniform diagonal check
#pragma unroll
        for (int kblk = 0; kblk < 2; ++kblk)
#pragma unroll
          for (int nb = 0; nb < 2; ++nb) {
            int key = kb + wk * 32 + kblk * 16 + quad * 4;
            int q   = qbase + nb * 16 + fr;
#pragma unroll
            for (int r = 0; r < 4; ++r)
              if (key + r > q) sa[kblk][nb][r] = MASKV;
          }
      }

      // ---- defer-max softmax (lane-local partials) ----
      float lm[2];
#pragma unroll
      for (int nb = 0; nb < 2; ++nb) {
        f32x4 mx4 = sa[0][nb];
        mx4[0] = fmaxf(mx4[0], sa[1][nb][0]); mx4[1] = fmaxf(mx4[1], sa[1][nb][1]);
        mx4[2] = fmaxf(mx4[2], sa[1][nb][2]); mx4[3] = fmaxf(mx4[3], sa[1][nb][3]);
        lm[nb] = fmaxf(fmaxf(mx4[0], mx4[1]), fmaxf(mx4[2], mx4[3]));
      }
      int ok = (lm[0] <= mrow[0] + 11.f) & (lm[1] <= mrow[1] + 11.f);
      if (!__all(ok)) {
#pragma unroll
        for (int nb = 0; nb < 2; ++nb) {
          float mx = lm[nb];
          mx = fmaxf(mx, __shfl_xor(mx, 16));
          mx = fmaxf(mx, __shfl_xor(mx, 32));
          float mnew = fmaxf(mrow[nb], mx);
          float a = __builtin_amdgcn_exp2f(mrow[nb] - mnew);
          mrow[nb] = mnew;
          lp[nb] *= a;
#pragma unroll
          for (int r = 0; r < 4; ++r) {
            float ar = __shfl(a, (lane & 48) | (quad * 4 + r));
            oacc[nb][0][r] *= ar; oacc[nb][1][r] *= ar;
            oacc[nb][2][r] *= ar; oacc[nb][3][r] *= ar;
          }
        }
      }

      // exp2 + pack P^T into one K=32 A-frag per nb (slot = quad*8 + kblk*4 + r)
      bf16x8 pa32[2];
#pragma unroll
      for (int nb = 0; nb < 2; ++nb) {
        bf16x8 pk;
#pragma unroll
        for (int kblk = 0; kblk < 2; ++kblk) {
          float p0 = __builtin_amdgcn_exp2f(sa[kblk][nb][0] - mrow[nb]);
          float p1 = __builtin_amdgcn_exp2f(sa[kblk][nb][1] - mrow[nb]);
          float p2 = __builtin_amdgcn_exp2f(sa[kblk][nb][2] - mrow[nb]);
          float p3 = __builtin_amdgcn_exp2f(sa[kblk][nb][3] - mrow[nb]);
          lp[nb] += (p0 + p1) + (p2 + p3);
          pk[kblk * 4 + 0] = (short)f2bf(p0); pk[kblk * 4 + 1] = (short)f2bf(p1);
          pk[kblk * 4 + 2] = (short)f2bf(p2); pk[kblk * 4 + 3] = (short)f2bf(p3);
        }
        pa32[nb] = pk;
      }

      // PV K=32: one b128 per d-block (s-permuted Vt rows match pa32's key order)
      __builtin_amdgcn_s_setprio(1);
#pragma unroll
      for (int db = 0; db < 4; ++db) {
        const u16* vr = &KV[2 + cur][(db * 16 + fr) * 64];
        bf16x8 vv = *(const bf16x8*)&vr[xv];
        oacc[0][db] = MFMA16(pa32[0], vv, oacc[0][db]);
        oacc[1][db] = MFMA16(pa32[1], vv, oacc[1][db]);
      }
      __builtin_amdgcn_s_setprio(0);
      __syncthreads();   // buf[cur] reads done; buf[cur^1] staging drained
    }

    // ---- tile epilogue: finalize within wave, 2-way split-K merge across wk ----
#pragma unroll
    for (int nb = 0; nb < 2; ++nb) {
      lp[nb] += __shfl_xor(lp[nb], 16);
      lp[nb] += __shfl_xor(lp[nb], 32);
    }
    float mr2[2][4], lr2[2][4];
#pragma unroll
    for (int nb = 0; nb < 2; ++nb)
#pragma unroll
      for (int r = 0; r < 4; ++r) {
        int src = (lane & 48) | (quad * 4 + r);
        mr2[nb][r] = __shfl(mrow[nb], src);
        lr2[nb][r] = __shfl(lp[nb],   src);
      }
    float* mp = mbuf + (size_t)(wq * 64 + lane) * 50;
    if (wk) {
#pragma unroll
      for (int nb = 0; nb < 2; ++nb)
#pragma unroll
        for (int db = 0; db < 4; ++db) {
          *(float2*)&mp[(nb * 4 + db) * 4 + 0] = make_float2(oacc[nb][db][0], oacc[nb][db][1]);
          *(float2*)&mp[(nb * 4 + db) * 4 + 2] = make_float2(oacc[nb][db][2], oacc[nb][db][3]);
        }
#pragma unroll
      for (int nb = 0; nb < 2; ++nb) {
        *(float2*)&mp[32 + nb * 4 + 0] = make_float2(mr2[nb][0], mr2[nb][1]);
        *(float2*)&mp[32 + nb * 4 + 2] = make_float2(mr2[nb][2], mr2[nb][3]);
        *(float2*)&mp[40 + nb * 4 + 0] = make_float2(lr2[nb][0], lr2[nb][1]);
        *(float2*)&mp[40 + nb * 4 + 2] = make_float2(lr2[nb][2], lr2[nb][3]);
      }
    }
    __syncthreads();
    if (!wk) {
      float w0[2][4], w1[2][4];
#pragma unroll
      for (int nb = 0; nb < 2; ++nb)
#pragma unroll
        for (int r = 0; r < 4; ++r) {
          float m1 = mp[32 + nb * 4 + r];
          float l1 = mp[40 + nb * 4 + r];
          float M  = fmaxf(mr2[nb][r], m1);
          float c0 = __builtin_amdgcn_exp2f(mr2[nb][r] - M);
          float c1 = __builtin_amdgcn_exp2f(m1 - M);
          float inv = 1.0f / (lr2[nb][r] * c0 + l1 * c1);
          w0[nb][r] = c0 * inv;
          w1[nb][r] = c1 * inv;
        }
#pragma unroll
      for (int nb = 0; nb < 2; ++nb) {
        u16* op = O + (size_t)(b * SEQ + qbase + nb * 16 + quad * 4) * DMODEL + h * HDIM + fr;
#pragma unroll
        for (int db = 0; db < 4; ++db) {
          float2 oa = *(float2*)&mp[(nb * 4 + db) * 4 + 0];
          float2 ob = *(float2*)&mp[(nb * 4 + db) * 4 + 2];
          float o1[4] = {oa.x, oa.y, ob.x, ob.y};
#pragma unroll
          for (int r = 0; r < 4; ++r)
            op[(size_t)r * DMODEL + db * 16] =
                f2bf(oacc[nb][db][r] * w0[nb][r] + o1[r] * w1[nb][r]);
        }
      }
    }
    __syncthreads();   // merge reads done before next tile's staging reuses KV
  }
}

// ---------------- launcher ----------------
extern "C" void kernel_launch(void* const* d_in, const int* in_sizes, int n_in,
                              void* d_out, int out_size, void* d_ws, size_t ws_size,
                              hipStream_t stream)
{
  const float* x   = (const float*)d_in[0];
  const float* ek  = (const float*)d_in[1];
  const float* ev  = (const float*)d_in[2];
  const float* Wq1 = (const float*)d_in[3];
  const float* bq1 = (const float*)d_in[4];
  const float* Wk1 = (const float*)d_in[5];
  const float* bk1 = (const float*)d_in[6];
  const float* Wv1 = (const float*)d_in[7];
  const float* bv1 = (const float*)d_in[8];
  const float* Wo1 = (const float*)d_in[9];
  const float* bo1 = (const float*)d_in[10];
  const float* Wq2 = (const float*)d_in[11];
  const float* bq2 = (const float*)d_in[12];
  const float* Wk2 = (const float*)d_in[13];
  const float* bk2 = (const float*)d_in[14];
  const float* Wv2 = (const float*)d_in[15];
  const float* bv2 = (const float*)d_in[16];
  const float* Wo2 = (const float*)d_in[17];
  const float* bo2 = (const float*)d_in[18];

  char* ws = (char*)d_ws;
  u16* wt  = (u16*)ws;
  u16* xb  = (u16*)(ws + (16u << 20));
  u16* ekb = (u16*)(ws + (32u << 20));
  u16* evb = (u16*)(ws + (48u << 20));
  u16* qb  = (u16*)(ws + (64u << 20));
  u16* kkb = (u16*)(ws + (80u << 20));
  u16* vtb = (u16*)(ws + (96u << 20));
  u16* hb  = (u16*)(ws + (112u << 20));
  u16* ob  = xb;   // x dead after layer-1 projections

  const int NW = DMODEL * DMODEL;
  const int n4 = MTOT * DMODEL / 4;
  const float qscale = 0.125f * 1.4426950408889634f;   // 1/sqrt(HD) * log2(e)

  pack_act<<<n4 / 256, 256, 0, stream>>>(x,  xb,  n4);
  pack_act<<<n4 / 256, 256, 0, stream>>>(ek, ekb, n4);
  pack_act<<<n4 / 256, 256, 0, stream>>>(ev, evb, n4);

  dim3 wg(16, 16);
  pack_w<<<wg, 256, 0, stream>>>(Wq1, wt + 0 * NW, 1);
  pack_w<<<wg, 256, 0, stream>>>(Wk1, wt + 1 * NW, 1);
  pack_w<<<wg, 256, 0, stream>>>(Wv1, wt + 2 * NW, 1);
  pack_w<<<wg, 256, 0, stream>>>(Wo1, wt + 3 * NW, 0);
  pack_w<<<wg, 256, 0, stream>>>(Wq2, wt + 4 * NW, 1);
  pack_w<<<wg, 256, 0, stream>>>(Wk2, wt + 5 * NW, 1);
  pack_w<<<wg, 256, 0, stream>>>(Wv2, wt + 6 * NW, 1);
  pack_w<<<wg, 256, 0, stream>>>(Wo2, wt + 7 * NW, 0);

  const int gblocks = (MTOT / 128) * (DMODEL / 128);   // 512, XCD-swizzled in-kernel
  const int ablocks = (SEQ / 128) * BSZ * NHEAD;       // 1024 pair-blocks

  // layer 1: causal self-attention
  gemm_bt<0><<<gblocks, 256, 0, stream>>>(xb,  wt + 0 * NW, bq1, qb,  qscale);
  gemm_bt<0><<<gblocks, 256, 0, stream>>>(xb,  wt + 1 * NW, bk1, kkb, 1.0f);
  gemm_bt<1><<<gblocks, 256, 0, stream>>>(xb,  wt + 2 * NW, bv1, vtb, 1.0f);
  attn_kernel<<<ablocks, 256, 0, stream>>>(qb, kkb, vtb, ob, 1);
  gemm_bt<0><<<gblocks, 256, 0, stream>>>(ob,  wt + 3 * NW, bo1, hb,  1.0f);

  // layer 2: cross attention
  gemm_bt<0><<<gblocks, 256, 0, stream>>>(hb,  wt + 4 * NW, bq2, qb,  qscale);
  gemm_bt<0><<<gblocks, 256, 0, stream>>>(ekb, wt + 5 * NW, bk2, kkb, 1.0f);
  gemm_bt<1><<<gblocks, 256, 0, stream>>>(evb, wt + 6 * NW, bv2, vtb, 1.0f);
  attn_kernel<<<ablocks, 256, 0, stream>>>(qb, kkb, vtb, ob, 0);
  gemm_bt<2><<<gblocks, 256, 0, stream>>>(ob,  wt + 7 * NW, bo2, d_out, 1.0f);
}

// Round 13
// 368.420 us; speedup vs baseline: 1.5900x; 1.0244x over previous
//
#include <hip/hip_runtime.h>
#include <hip/hip_bf16.h>
#include <cstdint>

typedef unsigned short u16;
typedef unsigned int   u32;
typedef __attribute__((ext_vector_type(8))) short bf16x8;   // 8 bf16 = 4 VGPRs
typedef __attribute__((ext_vector_type(4))) u32  u32x4;
typedef __attribute__((ext_vector_type(4))) float f32x4;

#define MFMA16(a,b,c)    __builtin_amdgcn_mfma_f32_16x16x32_bf16((a),(b),(c),0,0,0)

#define BSZ    4
#define SEQ    2048
#define DMODEL 1024
#define NHEAD  16
#define HDIM   64
#define MTOT   (BSZ*SEQ)   // 8192
#define MASKV  (-3.0e38f)  // finite: exp2(MASKV - m) == 0, no inf-inf NaN
#define NW     (DMODEL*DMODEL)

// native conversion (RNE)
__device__ __forceinline__ u16 f2bf(float f) {
  __hip_bfloat16 h = __float2bfloat16(f);
  return __builtin_bit_cast(u16, h);
}
// paired conversion: two scalar RNE casts packed to one u32 (compiler fuses to cvt_pk)
__device__ __forceinline__ u32 f2bf2(float a, float b) {
  return (u32)f2bf(a) | ((u32)f2bf(b) << 16);
}

typedef __attribute__((address_space(1))) void g1v;
typedef __attribute__((address_space(3))) void l3v;
// async global->LDS, 16B/lane. LDS dest is wave-uniform base (HW adds lane*16B).
__device__ __forceinline__ void gload16(const void* g, void* l) {
  __builtin_amdgcn_global_load_lds((g1v*)(uintptr_t)g, (l3v*)(u32)(uintptr_t)l, 16, 0, 0);
}

// ---------------- pack: fp32 -> bf16 activations (x, ek, ev in one launch) ----------
__global__ void pack_act3(const float* __restrict__ x, const float* __restrict__ ek,
                          const float* __restrict__ ev, u16* __restrict__ xb,
                          u16* __restrict__ ekb, u16* __restrict__ evb, int n4) {
  int i = blockIdx.x * blockDim.x + threadIdx.x;
  if (i >= n4) return;
  const float* in; u16* out;
  if (blockIdx.y == 0)      { in = x;  out = xb;  }
  else if (blockIdx.y == 1) { in = ek; out = ekb; }
  else                      { in = ev; out = evb; }
  float4 v = ((const float4*)in)[i];
  ((uint2*)out)[i] = make_uint2(f2bf2(v.x, v.y), f2bf2(v.z, v.w));
}

// ---------------- pack: all 8 weights -> Bt[n][k] bf16 in one launch ----------------
__global__ void pack_w8(const float* __restrict__ w0, const float* __restrict__ w1,
                        const float* __restrict__ w2, const float* __restrict__ w3,
                        const float* __restrict__ w4, const float* __restrict__ w5,
                        const float* __restrict__ w6, const float* __restrict__ w7,
                        u16* __restrict__ wt) {
  __shared__ float tile[64][65];
  const int w = blockIdx.z;
  const float* src;
  switch (w) {
    case 0: src = w0; break; case 1: src = w1; break;
    case 2: src = w2; break; case 3: src = w3; break;
    case 4: src = w4; break; case 5: src = w5; break;
    case 6: src = w6; break; default: src = w7; break;
  }
  const int per_head = (w == 3 || w == 7) ? 0 : 1;
  u16* dst = wt + (size_t)w * NW;
  int kt = blockIdx.x * 64, nt = blockIdx.y * 64;
  int tx = threadIdx.x & 63, ty = threadIdx.x >> 6;
  for (int kk = ty; kk < 64; kk += 4) {
    int k = kt + kk, n = nt + tx;
    float v = per_head ? src[(size_t)(n >> 6) * (DMODEL * HDIM) + (size_t)k * HDIM + (n & 63)]
                       : src[(size_t)k * DMODEL + n];
    tile[kk][tx] = v;
  }
  __syncthreads();
  for (int nn = ty; nn < 64; nn += 4)
    dst[(size_t)(nt + nn) * DMODEL + kt + tx] = f2bf(tile[tx][nn]);
}

// ---------------- GEMM core (BK=64 double-buffered 2-phase prefetch) ----------------
// epi: 0 = bf16 [M][N]; 1 = bf16 Vt s-permuted; 2 = f32 [M][N]
template <bool TMPL>
__device__ __forceinline__ void gemm_body(const u16* __restrict__ A, const u16* __restrict__ Bt,
                                          const float* __restrict__ bias, void* __restrict__ Cout,
                                          float scale, int epi, int inner)
{
  __shared__ u16 As[2][128 * 64];
  __shared__ u16 Bs[2][128 * 64];
  const int lane = threadIdx.x & 63, wid = threadIdx.x >> 6;
  const int wg = ((inner & 7) << 6) | (inner >> 3);  // [xcd:3][seq:6]
  const int m0 = (wg >> 3) * 128, n0 = (wg & 7) * 128;

  const int srow = wid * 32 + (lane >> 3);          // +i*8; (row&7) == lane>>3
  const int sc = (lane & 7) ^ ((lane >> 3) & 7);    // pre-swizzled source chunk
  const u16* gA = A  + (size_t)(m0 + srow) * DMODEL + sc * 8;
  const u16* gB = Bt + (size_t)(n0 + srow) * DMODEL + sc * 8;

  const int fr = lane & 15, quad = lane >> 4;
  const int wr = (wid >> 1) * 64, wc = (wid & 1) * 64;

  f32x4 acc[4][4] = {};
  const int NT = DMODEL / 64;   // 16

#pragma unroll
  for (int i = 0; i < 4; ++i) {
    gload16(gA + (size_t)(i * 8) * DMODEL, &As[0][(wid * 32 + i * 8) * 64]);
    gload16(gB + (size_t)(i * 8) * DMODEL, &Bs[0][(wid * 32 + i * 8) * 64]);
  }
  gA += 64; gB += 64;
  __syncthreads();

  for (int kt = 0; kt < NT; ++kt) {
    const int cur = kt & 1;
    if (kt + 1 < NT) {
#pragma unroll
      for (int i = 0; i < 4; ++i) {
        gload16(gA + (size_t)(i * 8) * DMODEL, &As[cur ^ 1][(wid * 32 + i * 8) * 64]);
        gload16(gB + (size_t)(i * 8) * DMODEL, &Bs[cur ^ 1][(wid * 32 + i * 8) * 64]);
      }
      gA += 64; gB += 64;
    }
#pragma unroll
    for (int kp = 0; kp < 2; ++kp) {
      bf16x8 af[4], bfr[4];
#pragma unroll
      for (int i = 0; i < 4; ++i) {
        int ra = wr + i * 16 + fr;
        af[i]  = *(const bf16x8*)&As[cur][ra * 64 + (((kp * 4 + quad) ^ (ra & 7)) * 8)];
        int rb = wc + i * 16 + fr;
        bfr[i] = *(const bf16x8*)&Bs[cur][rb * 64 + (((kp * 4 + quad) ^ (rb & 7)) * 8)];
      }
#pragma unroll
      for (int i = 0; i < 4; ++i)
#pragma unroll
        for (int j = 0; j < 4; ++j)
          acc[i][j] = MFMA16(af[i], bfr[j], acc[i][j]);
    }
    __syncthreads();   // buf[cur] reads done; buf[cur^1] staging drained
  }

  // C/D layout: col = lane&15, row = (lane>>4)*4 + reg
#pragma unroll
  for (int i = 0; i < 4; ++i) {
    int row0 = m0 + wr + i * 16 + quad * 4;
#pragma unroll
    for (int j = 0; j < 4; ++j) {
      int col = n0 + wc + j * 16 + fr;
      float bv = bias[col];
      float v0 = (acc[i][j][0] + bv) * scale, v1 = (acc[i][j][1] + bv) * scale;
      float v2 = (acc[i][j][2] + bv) * scale, v3 = (acc[i][j][3] + bv) * scale;
      if (epi == 2) {
        float* C = (float*)Cout;
        C[(size_t)(row0 + 0) * DMODEL + col] = v0;
        C[(size_t)(row0 + 1) * DMODEL + col] = v1;
        C[(size_t)(row0 + 2) * DMODEL + col] = v2;
        C[(size_t)(row0 + 3) * DMODEL + col] = v3;
      } else if (epi == 0) {
        u16* C = (u16*)Cout;
        C[(size_t)(row0 + 0) * DMODEL + col] = f2bf(v0);
        C[(size_t)(row0 + 1) * DMODEL + col] = f2bf(v1);
        C[(size_t)(row0 + 2) * DMODEL + col] = f2bf(v2);
        C[(size_t)(row0 + 3) * DMODEL + col] = f2bf(v3);
      } else {
        u16* C = (u16*)Cout;
        int bi = row0 >> 11, s = row0 & 2047;
        // permuted s within 32-group: (b:1|c:2|r:2) -> (c:2|b:1|r:2)
        int sN = (s & ~31) | (((s >> 2) & 3) << 3) | (((s >> 4) & 1) << 2) | (s & 3);
        size_t vtr = ((size_t)(bi * NHEAD + (col >> 6)) * HDIM + (col & 63)) * SEQ + sN;
        *(uint2*)&C[vtr] = make_uint2(f2bf2(v0, v1), f2bf2(v2, v3));
      }
    }
  }
}

// single GEMM (Wo projections, final output)
__global__ __launch_bounds__(256, 2)
void gemm_bt(const u16* __restrict__ A, const u16* __restrict__ Bt,
             const float* __restrict__ bias, void* __restrict__ Cout,
             float scale, int epi)
{
  gemm_body<true>(A, Bt, bias, Cout, scale, epi, blockIdx.x);
}

// fused Q/K/V projections: 3 x 512 blocks; seg = bid>>9 picks operands (uniform)
__global__ __launch_bounds__(256, 2)
void gemm_qkv(const u16* __restrict__ Aq, const u16* __restrict__ Ak,
              const u16* __restrict__ Av, const u16* __restrict__ Btb,
              const float* __restrict__ bq, const float* __restrict__ bk,
              const float* __restrict__ bv, void* __restrict__ oq,
              void* __restrict__ ok, void* __restrict__ ov, float qscale)
{
  const int seg = blockIdx.x >> 9, inner = blockIdx.x & 511;
  const u16* A; const float* bias; void* Cout; float scale; int epi;
  if (seg == 0)      { A = Aq; bias = bq; Cout = oq; scale = qscale; epi = 0; }
  else if (seg == 1) { A = Ak; bias = bk; Cout = ok; scale = 1.0f;   epi = 0; }
  else               { A = Av; bias = bv; Cout = ov; scale = 1.0f;   epi = 1; }
  gemm_body<true>(A, Btb + (size_t)seg * NW, bias, Cout, scale, epi, inner);
}

// ---------------- flash attention v11 ----------------
// v10 + paired P-pack. Split-K waves 2x2 (wq x wk), swapped QK^T, zero-shuffle P,
// K=32 PV via s-permuted Vt, 1024 pair-blocks (causal = uniform 33 steps), XCD-swizzled.
__global__ __launch_bounds__(256, 4)
void attn_kernel(const u16* __restrict__ Q, const u16* __restrict__ K,
                 const u16* __restrict__ Vt, u16* __restrict__ O, int causal)
{
  __shared__ u16 KV[4][64 * 64];   // [0,1]=K dbuf, [2,3]=V dbuf; merge reuses as f32
  const int lane = threadIdx.x & 63, wid = threadIdx.x >> 6;
  const int fr = lane & 15, quad = lane >> 4;
  const int wq = wid >> 1, wk = wid & 1;

  const int flat = blockIdx.x;
  const int bh = ((flat >> 7) << 3) | (flat & 7);
  const int pair = (flat >> 3) & 15;
  const int b = bh >> 4, h = bh & 15;

  // loop-invariant swizzled LDS element offsets
  const int xk0 = ((quad    ) ^ (fr & 7)) * 8;
  const int xk1 = ((quad + 4) ^ (fr & 7)) * 8;
  const int xv  = ((wk * 4 + quad) ^ (fr & 7)) * 8;   // one b128: full K=32 B-frag

  const int srow = wid * 16 + (lane >> 3);
  const int jg = (lane & 7) ^ (srow & 7);   // same for srow and srow+8
  const u16* kg = K + (size_t)b * SEQ * DMODEL + h * HDIM;
  const u16* vg = Vt + (size_t)bh * HDIM * SEQ;
  const u16* ks0 = kg + (size_t)srow * DMODEL + jg * 8;
  const u16* vs0 = vg + (size_t)srow * SEQ + jg * 8;
  float* mbuf = (float*)&KV[0][0];          // merge scratch (25.6KB < 32KB)

  for (int tile = 0; tile < 2; ++tile) {
    const int qb = tile == 0 ? (31 - pair) : pair;
    const int q0 = qb * 64;
    const int qbase = q0 + wq * 32;

    bf16x8 aq[2][2];
#pragma unroll
    for (int nb = 0; nb < 2; ++nb) {
      const u16* qp = Q + (size_t)(b * SEQ + qbase + nb * 16 + fr) * DMODEL + h * HDIM + quad * 8;
      aq[nb][0] = *(const bf16x8*)qp;
      aq[nb][1] = *(const bf16x8*)(qp + 32);
    }

    f32x4 oacc[2][4] = {};
    float mrow[2] = {-1e30f, -1e30f};
    float lp[2]   = {0.f, 0.f};

    const int nsteps = (causal ? (q0 + 64) : SEQ) >> 6;

    // prologue: stage tile 0 into bufs {0, 2}
    gload16(ks0,              &KV[0][(wid * 16 + 0) * 64]);
    gload16(ks0 + 8 * DMODEL, &KV[0][(wid * 16 + 8) * 64]);
    gload16(vs0,              &KV[2][(wid * 16 + 0) * 64]);
    gload16(vs0 + 8 * SEQ,    &KV[2][(wid * 16 + 8) * 64]);
    const u16* kpre = ks0 + 64 * DMODEL;
    const u16* vpre = vs0 + 64;
    __syncthreads();

    for (int t = 0; t < nsteps; ++t) {
      const int cur = t & 1;
      const int kb = t * 64;
      if (t + 1 < nsteps) {
        gload16(kpre,              &KV[cur ^ 1][(wid * 16 + 0) * 64]);
        gload16(kpre + 8 * DMODEL, &KV[cur ^ 1][(wid * 16 + 8) * 64]);
        gload16(vpre,              &KV[2 + (cur ^ 1)][(wid * 16 + 0) * 64]);
        gload16(vpre + 8 * SEQ,    &KV[2 + (cur ^ 1)][(wid * 16 + 8) * 64]);
        kpre += 64 * DMODEL; vpre += 64;
      }
      // swapped QK^T: sa[kblk][nb][r] = S[key=kb+wk*32+kblk*16+quad*4+r][q=qbase+nb*16+fr]
      const u16* kr0 = &KV[cur][(wk * 32 + fr) * 64];
      f32x4 sa[2][2];
      __builtin_amdgcn_s_setprio(1);
      {
        bf16x8 kfa = *(const bf16x8*)&kr0[xk0];
        bf16x8 kfb = *(const bf16x8*)&kr0[xk1];
        f32x4 s = {};
        s = MFMA16(kfa, aq[0][0], s); s = MFMA16(kfb, aq[0][1], s); sa[0][0] = s;
        s = (f32x4){};
        s = MFMA16(kfa, aq[1][0], s); s = MFMA16(kfb, aq[1][1], s); sa[0][1] = s;
        kfa = *(const bf16x8*)&kr0[16 * 64 + xk0];
        kfb = *(const bf16x8*)&kr0[16 * 64 + xk1];
        s = (f32x4){};
        s = MFMA16(kfa, aq[0][0], s); s = MFMA16(kfb, aq[0][1], s); sa[1][0] = s;
        s = (f32x4){};
        s = MFMA16(kfa, aq[1][0], s); s = MFMA16(kfb, aq[1][1], s); sa[1][1] = s;
      }
      __builtin_amdgcn_s_setprio(0);

      if (causal && kb + wk * 32 + 31 > qbase) {   // wave-uniform diagonal check
#pragma unroll
        for (int kblk = 0; kblk < 2; ++kblk)
#pragma unroll
          for (int nb = 0; nb < 2; ++nb) {
            int key = kb + wk * 32 + kblk * 16 + quad * 4;
            int q   = qbase + nb * 16 + fr;
#pragma unroll
            for (int r = 0; r < 4; ++r)
              if (key + r > q) sa[kblk][nb][r] = MASKV;
          }
      }

      // ---- defer-max softmax (lane-local partials) ----
      float lm[2];
#pragma unroll
      for (int nb = 0; nb < 2; ++nb) {
        f32x4 mx4 = sa[0][nb];
        mx4[0] = fmaxf(mx4[0], sa[1][nb][0]); mx4[1] = fmaxf(mx4[1], sa[1][nb][1]);
        mx4[2] = fmaxf(mx4[2], sa[1][nb][2]); mx4[3] = fmaxf(mx4[3], sa[1][nb][3]);
        lm[nb] = fmaxf(fmaxf(mx4[0], mx4[1]), fmaxf(mx4[2], mx4[3]));
      }
      int ok = (lm[0] <= mrow[0] + 11.f) & (lm[1] <= mrow[1] + 11.f);
      if (!__all(ok)) {
#pragma unroll
        for (int nb = 0; nb < 2; ++nb) {
          float mx = lm[nb];
          mx = fmaxf(mx, __shfl_xor(mx, 16));
          mx = fmaxf(mx, __shfl_xor(mx, 32));
          float mnew = fmaxf(mrow[nb], mx);
          float a = __builtin_amdgcn_exp2f(mrow[nb] - mnew);
          mrow[nb] = mnew;
          lp[nb] *= a;
#pragma unroll
          for (int r = 0; r < 4; ++r) {
            float ar = __shfl(a, (lane & 48) | (quad * 4 + r));
            oacc[nb][0][r] *= ar; oacc[nb][1][r] *= ar;
            oacc[nb][2][r] *= ar; oacc[nb][3][r] *= ar;
          }
        }
      }

      // exp2 + paired-pack P^T into one K=32 A-frag per nb (slot = quad*8 + kblk*4 + r)
      bf16x8 pa32[2];
#pragma unroll
      for (int nb = 0; nb < 2; ++nb) {
        u32x4 pw;
#pragma unroll
        for (int kblk = 0; kblk < 2; ++kblk) {
          float p0 = __builtin_amdgcn_exp2f(sa[kblk][nb][0] - mrow[nb]);
          float p1 = __builtin_amdgcn_exp2f(sa[kblk][nb][1] - mrow[nb]);
          float p2 = __builtin_amdgcn_exp2f(sa[kblk][nb][2] - mrow[nb]);
          float p3 = __builtin_amdgcn_exp2f(sa[kblk][nb][3] - mrow[nb]);
          lp[nb] += (p0 + p1) + (p2 + p3);
          pw[kblk * 2 + 0] = f2bf2(p0, p1);
          pw[kblk * 2 + 1] = f2bf2(p2, p3);
        }
        pa32[nb] = __builtin_bit_cast(bf16x8, pw);
      }

      // PV K=32: one b128 per d-block (s-permuted Vt rows match pa32's key order)
      __builtin_amdgcn_s_setprio(1);
#pragma unroll
      for (int db = 0; db < 4; ++db) {
        const u16* vr = &KV[2 + cur][(db * 16 + fr) * 64];
        bf16x8 vv = *(const bf16x8*)&vr[xv];
        oacc[0][db] = MFMA16(pa32[0], vv, oacc[0][db]);
        oacc[1][db] = MFMA16(pa32[1], vv, oacc[1][db]);
      }
      __builtin_amdgcn_s_setprio(0);
      __syncthreads();   // buf[cur] reads done; buf[cur^1] staging drained
    }

    // ---- tile epilogue: finalize within wave, 2-way split-K merge across wk ----
#pragma unroll
    for (int nb = 0; nb < 2; ++nb) {
      lp[nb] += __shfl_xor(lp[nb], 16);
      lp[nb] += __shfl_xor(lp[nb], 32);
    }
    float mr2[2][4], lr2[2][4];
#pragma unroll
    for (int nb = 0; nb < 2; ++nb)
#pragma unroll
      for (int r = 0; r < 4; ++r) {
        int src = (lane & 48) | (quad * 4 + r);
        mr2[nb][r] = __shfl(mrow[nb], src);
        lr2[nb][r] = __shfl(lp[nb],   src);
      }
    float* mp = mbuf + (size_t)(wq * 64 + lane) * 50;
    if (wk) {
#pragma unroll
      for (int nb = 0; nb < 2; ++nb)
#pragma unroll
        for (int db = 0; db < 4; ++db) {
          *(float2*)&mp[(nb * 4 + db) * 4 + 0] = make_float2(oacc[nb][db][0], oacc[nb][db][1]);
          *(float2*)&mp[(nb * 4 + db) * 4 + 2] = make_float2(oacc[nb][db][2], oacc[nb][db][3]);
        }
#pragma unroll
      for (int nb = 0; nb < 2; ++nb) {
        *(float2*)&mp[32 + nb * 4 + 0] = make_float2(mr2[nb][0], mr2[nb][1]);
        *(float2*)&mp[32 + nb * 4 + 2] = make_float2(mr2[nb][2], mr2[nb][3]);
        *(float2*)&mp[40 + nb * 4 + 0] = make_float2(lr2[nb][0], lr2[nb][1]);
        *(float2*)&mp[40 + nb * 4 + 2] = make_float2(lr2[nb][2], lr2[nb][3]);
      }
    }
    __syncthreads();
    if (!wk) {
      float w0[2][4], w1[2][4];
#pragma unroll
      for (int nb = 0; nb < 2; ++nb)
#pragma unroll
        for (int r = 0; r < 4; ++r) {
          float m1 = mp[32 + nb * 4 + r];
          float l1 = mp[40 + nb * 4 + r];
          float M  = fmaxf(mr2[nb][r], m1);
          float c0 = __builtin_amdgcn_exp2f(mr2[nb][r] - M);
          float c1 = __builtin_amdgcn_exp2f(m1 - M);
          float inv = 1.0f / (lr2[nb][r] * c0 + l1 * c1);
          w0[nb][r] = c0 * inv;
          w1[nb][r] = c1 * inv;
        }
#pragma unroll
      for (int nb = 0; nb < 2; ++nb) {
        u16* op = O + (size_t)(b * SEQ + qbase + nb * 16 + quad * 4) * DMODEL + h * HDIM + fr;
#pragma unroll
        for (int db = 0; db < 4; ++db) {
          float2 oa = *(float2*)&mp[(nb * 4 + db) * 4 + 0];
          float2 ob = *(float2*)&mp[(nb * 4 + db) * 4 + 2];
          float o1[4] = {oa.x, oa.y, ob.x, ob.y};
#pragma unroll
          for (int r = 0; r < 4; ++r)
            op[(size_t)r * DMODEL + db * 16] =
                f2bf(oacc[nb][db][r] * w0[nb][r] + o1[r] * w1[nb][r]);
        }
      }
    }
    __syncthreads();   // merge reads done before next tile's staging reuses KV
  }
}

// ---------------- launcher ----------------
extern "C" void kernel_launch(void* const* d_in, const int* in_sizes, int n_in,
                              void* d_out, int out_size, void* d_ws, size_t ws_size,
                              hipStream_t stream)
{
  const float* x   = (const float*)d_in[0];
  const float* ek  = (const float*)d_in[1];
  const float* ev  = (const float*)d_in[2];
  const float* Wq1 = (const float*)d_in[3];
  const float* bq1 = (const float*)d_in[4];
  const float* Wk1 = (const float*)d_in[5];
  const float* bk1 = (const float*)d_in[6];
  const float* Wv1 = (const float*)d_in[7];
  const float* bv1 = (const float*)d_in[8];
  const float* Wo1 = (const float*)d_in[9];
  const float* bo1 = (const float*)d_in[10];
  const float* Wq2 = (const float*)d_in[11];
  const float* bq2 = (const float*)d_in[12];
  const float* Wk2 = (const float*)d_in[13];
  const float* bk2 = (const float*)d_in[14];
  const float* Wv2 = (const float*)d_in[15];
  const float* bv2 = (const float*)d_in[16];
  const float* Wo2 = (const float*)d_in[17];
  const float* bo2 = (const float*)d_in[18];

  char* ws = (char*)d_ws;
  u16* wt  = (u16*)ws;
  u16* xb  = (u16*)(ws + (16u << 20));
  u16* ekb = (u16*)(ws + (32u << 20));
  u16* evb = (u16*)(ws + (48u << 20));
  u16* qb  = (u16*)(ws + (64u << 20));
  u16* kkb = (u16*)(ws + (80u << 20));
  u16* vtb = (u16*)(ws + (96u << 20));
  u16* hb  = (u16*)(ws + (112u << 20));
  u16* ob  = xb;   // x dead after layer-1 projections

  const int n4 = MTOT * DMODEL / 4;
  const float qscale = 0.125f * 1.4426950408889634f;   // 1/sqrt(HD) * log2(e)

  pack_act3<<<dim3(n4 / 256, 3), 256, 0, stream>>>(x, ek, ev, xb, ekb, evb, n4);
  pack_w8<<<dim3(16, 16, 8), 256, 0, stream>>>(Wq1, Wk1, Wv1, Wo1, Wq2, Wk2, Wv2, Wo2, wt);

  const int gblocks = (MTOT / 128) * (DMODEL / 128);   // 512, XCD-swizzled in-kernel
  const int ablocks = (SEQ / 128) * BSZ * NHEAD;       // 1024 pair-blocks

  // layer 1: causal self-attention
  gemm_qkv<<<3 * gblocks, 256, 0, stream>>>(xb, xb, xb, wt, bq1, bk1, bv1,
                                            qb, kkb, vtb, qscale);
  attn_kernel<<<ablocks, 256, 0, stream>>>(qb, kkb, vtb, ob, 1);
  gemm_bt<<<gblocks, 256, 0, stream>>>(ob, wt + 3 * NW, bo1, hb, 1.0f, 0);

  // layer 2: cross attention
  gemm_qkv<<<3 * gblocks, 256, 0, stream>>>(hb, ekb, evb, wt + 4 * NW, bq2, bk2, bv2,
                                            qb, kkb, vtb, qscale);
  attn_kernel<<<ablocks, 256, 0, stream>>>(qb, kkb, vtb, ob, 0);
  gemm_bt<<<gblocks, 256, 0, stream>>>(ob, wt + 7 * NW, bo2, d_out, 1.0f, 2);
}

// Round 14
// 358.914 us; speedup vs baseline: 1.6321x; 1.0265x over previous
//
#include <hip/hip_runtime.h>
#include <hip/hip_bf16.h>
#include <cstdint>

typedef unsigned short u16;
typedef unsigned int   u32;
typedef __attribute__((ext_vector_type(8))) short bf16x8;   // 8 bf16 = 4 VGPRs
typedef __attribute__((ext_vector_type(4))) u32  u32x4;
typedef __attribute__((ext_vector_type(4))) float f32x4;

#define MFMA16(a,b,c)    __builtin_amdgcn_mfma_f32_16x16x32_bf16((a),(b),(c),0,0,0)

#define BSZ    4
#define SEQ    2048
#define DMODEL 1024
#define NHEAD  16
#define HDIM   64
#define MTOT   (BSZ*SEQ)   // 8192
#define MASKV  (-3.0e38f)  // finite: exp2(MASKV - m) == 0, no inf-inf NaN
#define NW     (DMODEL*DMODEL)

// native conversion (RNE)
__device__ __forceinline__ u16 f2bf(float f) {
  __hip_bfloat16 h = __float2bfloat16(f);
  return __builtin_bit_cast(u16, h);
}
// paired conversion -> single v_cvt_pk_bf16_f32 (RNE; byte-copy since bf162 isn't
// trivially copyable for bit_cast)
__device__ __forceinline__ u32 f2bf2(float a, float b) {
  __hip_bfloat162 h = __float22bfloat162_rn(make_float2(a, b));
  u32 u; __builtin_memcpy(&u, &h, sizeof(u));
  return u;
}
// fmax-of-3 -> v_max3_f32
__device__ __forceinline__ float max3f(float a, float b, float c) {
  return fmaxf(fmaxf(a, b), c);
}

typedef __attribute__((address_space(1))) void g1v;
typedef __attribute__((address_space(3))) void l3v;
// async global->LDS, 16B/lane. LDS dest is wave-uniform base (HW adds lane*16B).
__device__ __forceinline__ void gload16(const void* g, void* l) {
  __builtin_amdgcn_global_load_lds((g1v*)(uintptr_t)g, (l3v*)(u32)(uintptr_t)l, 16, 0, 0);
}

// ---------------- pack: fp32 -> bf16 activations (x, ek, ev in one launch) ----------
__global__ void pack_act3(const float* __restrict__ x, const float* __restrict__ ek,
                          const float* __restrict__ ev, u16* __restrict__ xb,
                          u16* __restrict__ ekb, u16* __restrict__ evb, int n4) {
  int i = blockIdx.x * blockDim.x + threadIdx.x;
  if (i >= n4) return;
  const float* in; u16* out;
  if (blockIdx.y == 0)      { in = x;  out = xb;  }
  else if (blockIdx.y == 1) { in = ek; out = ekb; }
  else                      { in = ev; out = evb; }
  float4 v = ((const float4*)in)[i];
  ((uint2*)out)[i] = make_uint2(f2bf2(v.x, v.y), f2bf2(v.z, v.w));
}

// ---------------- pack: all 8 weights -> Bt[n][k] bf16 in one launch ----------------
__global__ void pack_w8(const float* __restrict__ w0, const float* __restrict__ w1,
                        const float* __restrict__ w2, const float* __restrict__ w3,
                        const float* __restrict__ w4, const float* __restrict__ w5,
                        const float* __restrict__ w6, const float* __restrict__ w7,
                        u16* __restrict__ wt) {
  __shared__ float tile[64][65];
  const int w = blockIdx.z;
  const float* src;
  switch (w) {
    case 0: src = w0; break; case 1: src = w1; break;
    case 2: src = w2; break; case 3: src = w3; break;
    case 4: src = w4; break; case 5: src = w5; break;
    case 6: src = w6; break; default: src = w7; break;
  }
  const int per_head = (w == 3 || w == 7) ? 0 : 1;
  u16* dst = wt + (size_t)w * NW;
  int kt = blockIdx.x * 64, nt = blockIdx.y * 64;
  int tx = threadIdx.x & 63, ty = threadIdx.x >> 6;
  for (int kk = ty; kk < 64; kk += 4) {
    int k = kt + kk, n = nt + tx;
    float v = per_head ? src[(size_t)(n >> 6) * (DMODEL * HDIM) + (size_t)k * HDIM + (n & 63)]
                       : src[(size_t)k * DMODEL + n];
    tile[kk][tx] = v;
  }
  __syncthreads();
  for (int nn = ty; nn < 64; nn += 4)
    dst[(size_t)(nt + nn) * DMODEL + kt + tx] = f2bf(tile[tx][nn]);
}

// ---------------- GEMM core (BK=64 double-buffered 2-phase prefetch) ----------------
// epi: 0 = bf16 [M][N]; 1 = bf16 Vt s-permuted; 2 = f32 [M][N]
template <bool TMPL>
__device__ __forceinline__ void gemm_body(const u16* __restrict__ A, const u16* __restrict__ Bt,
                                          const float* __restrict__ bias, void* __restrict__ Cout,
                                          float scale, int epi, int inner)
{
  __shared__ u16 As[2][128 * 64];
  __shared__ u16 Bs[2][128 * 64];
  const int lane = threadIdx.x & 63, wid = threadIdx.x >> 6;
  const int wg = ((inner & 7) << 6) | (inner >> 3);  // [xcd:3][seq:6]
  const int m0 = (wg >> 3) * 128, n0 = (wg & 7) * 128;

  const int srow = wid * 32 + (lane >> 3);          // +i*8; (row&7) == lane>>3
  const int sc = (lane & 7) ^ ((lane >> 3) & 7);    // pre-swizzled source chunk
  const u16* gA = A  + (size_t)(m0 + srow) * DMODEL + sc * 8;
  const u16* gB = Bt + (size_t)(n0 + srow) * DMODEL + sc * 8;

  const int fr = lane & 15, quad = lane >> 4;
  const int wr = (wid >> 1) * 64, wc = (wid & 1) * 64;

  f32x4 acc[4][4] = {};
  const int NT = DMODEL / 64;   // 16

#pragma unroll
  for (int i = 0; i < 4; ++i) {
    gload16(gA + (size_t)(i * 8) * DMODEL, &As[0][(wid * 32 + i * 8) * 64]);
    gload16(gB + (size_t)(i * 8) * DMODEL, &Bs[0][(wid * 32 + i * 8) * 64]);
  }
  gA += 64; gB += 64;
  __syncthreads();

  for (int kt = 0; kt < NT; ++kt) {
    const int cur = kt & 1;
    if (kt + 1 < NT) {
#pragma unroll
      for (int i = 0; i < 4; ++i) {
        gload16(gA + (size_t)(i * 8) * DMODEL, &As[cur ^ 1][(wid * 32 + i * 8) * 64]);
        gload16(gB + (size_t)(i * 8) * DMODEL, &Bs[cur ^ 1][(wid * 32 + i * 8) * 64]);
      }
      gA += 64; gB += 64;
    }
#pragma unroll
    for (int kp = 0; kp < 2; ++kp) {
      bf16x8 af[4], bfr[4];
#pragma unroll
      for (int i = 0; i < 4; ++i) {
        int ra = wr + i * 16 + fr;
        af[i]  = *(const bf16x8*)&As[cur][ra * 64 + (((kp * 4 + quad) ^ (ra & 7)) * 8)];
        int rb = wc + i * 16 + fr;
        bfr[i] = *(const bf16x8*)&Bs[cur][rb * 64 + (((kp * 4 + quad) ^ (rb & 7)) * 8)];
      }
#pragma unroll
      for (int i = 0; i < 4; ++i)
#pragma unroll
        for (int j = 0; j < 4; ++j)
          acc[i][j] = MFMA16(af[i], bfr[j], acc[i][j]);
    }
    __syncthreads();   // buf[cur] reads done; buf[cur^1] staging drained
  }

  // C/D layout: col = lane&15, row = (lane>>4)*4 + reg
#pragma unroll
  for (int i = 0; i < 4; ++i) {
    int row0 = m0 + wr + i * 16 + quad * 4;
#pragma unroll
    for (int j = 0; j < 4; ++j) {
      int col = n0 + wc + j * 16 + fr;
      float bv = bias[col];
      float v0 = (acc[i][j][0] + bv) * scale, v1 = (acc[i][j][1] + bv) * scale;
      float v2 = (acc[i][j][2] + bv) * scale, v3 = (acc[i][j][3] + bv) * scale;
      if (epi == 2) {
        float* C = (float*)Cout;
        C[(size_t)(row0 + 0) * DMODEL + col] = v0;
        C[(size_t)(row0 + 1) * DMODEL + col] = v1;
        C[(size_t)(row0 + 2) * DMODEL + col] = v2;
        C[(size_t)(row0 + 3) * DMODEL + col] = v3;
      } else if (epi == 0) {
        u16* C = (u16*)Cout;
        C[(size_t)(row0 + 0) * DMODEL + col] = f2bf(v0);
        C[(size_t)(row0 + 1) * DMODEL + col] = f2bf(v1);
        C[(size_t)(row0 + 2) * DMODEL + col] = f2bf(v2);
        C[(size_t)(row0 + 3) * DMODEL + col] = f2bf(v3);
      } else {
        u16* C = (u16*)Cout;
        int bi = row0 >> 11, s = row0 & 2047;
        // permuted s within 32-group: (b:1|c:2|r:2) -> (c:2|b:1|r:2)
        int sN = (s & ~31) | (((s >> 2) & 3) << 3) | (((s >> 4) & 1) << 2) | (s & 3);
        size_t vtr = ((size_t)(bi * NHEAD + (col >> 6)) * HDIM + (col & 63)) * SEQ + sN;
        *(uint2*)&C[vtr] = make_uint2(f2bf2(v0, v1), f2bf2(v2, v3));
      }
    }
  }
}

// single GEMM (Wo projections, final output)
__global__ __launch_bounds__(256, 2)
void gemm_bt(const u16* __restrict__ A, const u16* __restrict__ Bt,
             const float* __restrict__ bias, void* __restrict__ Cout,
             float scale, int epi)
{
  gemm_body<true>(A, Bt, bias, Cout, scale, epi, blockIdx.x);
}

// fused Q/K/V projections: 3 x 512 blocks; seg = bid>>9 picks operands (uniform)
__global__ __launch_bounds__(256, 2)
void gemm_qkv(const u16* __restrict__ Aq, const u16* __restrict__ Ak,
              const u16* __restrict__ Av, const u16* __restrict__ Btb,
              const float* __restrict__ bq, const float* __restrict__ bk,
              const float* __restrict__ bv, void* __restrict__ oq,
              void* __restrict__ ok, void* __restrict__ ov, float qscale)
{
  const int seg = blockIdx.x >> 9, inner = blockIdx.x & 511;
  const u16* A; const float* bias; void* Cout; float scale; int epi;
  if (seg == 0)      { A = Aq; bias = bq; Cout = oq; scale = qscale; epi = 0; }
  else if (seg == 1) { A = Ak; bias = bk; Cout = ok; scale = 1.0f;   epi = 0; }
  else               { A = Av; bias = bv; Cout = ov; scale = 1.0f;   epi = 1; }
  gemm_body<true>(A, Btb + (size_t)seg * NW, bias, Cout, scale, epi, inner);
}

// ---------------- flash attention v12 ----------------
// Split-K waves 2x2 (wq x wk), swapped QK^T, zero-shuffle P, K=32 PV via s-permuted Vt.
// Causal: 1024 paired blocks (qb {31-pair, pair} => uniform 33 steps), 4 blocks/CU.
// Cross:  2048 single-tile blocks (uniform 32 steps), 5 blocks/CU (32KB LDS x 5 = 160KB).
// Real v_cvt_pk P-pack; v_max3 tile-max chains.
__global__ __launch_bounds__(256, 4)
void attn_kernel(const u16* __restrict__ Q, const u16* __restrict__ K,
                 const u16* __restrict__ Vt, u16* __restrict__ O, int causal)
{
  __shared__ u16 KV[4][64 * 64];   // [0,1]=K dbuf, [2,3]=V dbuf; merge reuses as f32
  const int lane = threadIdx.x & 63, wid = threadIdx.x >> 6;
  const int fr = lane & 15, quad = lane >> 4;
  const int wq = wid >> 1, wk = wid & 1;

  const int flat = blockIdx.x;
  int bh, qb0, qb1, ntiles;
  if (causal) {                     // [bh_hi:3][pair:4][xcd:3]
    bh = ((flat >> 7) << 3) | (flat & 7);
    const int pair = (flat >> 3) & 15;
    qb0 = 31 - pair; qb1 = pair; ntiles = 2;
  } else {                          // [bh_hi:3][qb:5][xcd:3]
    bh = ((flat >> 8) << 3) | (flat & 7);
    qb0 = (flat >> 3) & 31; qb1 = 0; ntiles = 1;
  }
  const int b = bh >> 4, h = bh & 15;

  // loop-invariant swizzled LDS element offsets
  const int xk0 = ((quad    ) ^ (fr & 7)) * 8;
  const int xk1 = ((quad + 4) ^ (fr & 7)) * 8;
  const int xv  = ((wk * 4 + quad) ^ (fr & 7)) * 8;   // one b128: full K=32 B-frag

  const int srow = wid * 16 + (lane >> 3);
  const int jg = (lane & 7) ^ (srow & 7);   // same for srow and srow+8
  const u16* kg = K + (size_t)b * SEQ * DMODEL + h * HDIM;
  const u16* vg = Vt + (size_t)bh * HDIM * SEQ;
  const u16* ks0 = kg + (size_t)srow * DMODEL + jg * 8;
  const u16* vs0 = vg + (size_t)srow * SEQ + jg * 8;
  float* mbuf = (float*)&KV[0][0];          // merge scratch (25.6KB < 32KB)

  for (int tile = 0; tile < ntiles; ++tile) {
    const int qb = tile == 0 ? qb0 : qb1;
    const int q0 = qb * 64;
    const int qbase = q0 + wq * 32;

    bf16x8 aq[2][2];
#pragma unroll
    for (int nb = 0; nb < 2; ++nb) {
      const u16* qp = Q + (size_t)(b * SEQ + qbase + nb * 16 + fr) * DMODEL + h * HDIM + quad * 8;
      aq[nb][0] = *(const bf16x8*)qp;
      aq[nb][1] = *(const bf16x8*)(qp + 32);
    }

    f32x4 oacc[2][4] = {};
    float mrow[2] = {-1e30f, -1e30f};
    float lp[2]   = {0.f, 0.f};

    const int nsteps = (causal ? (q0 + 64) : SEQ) >> 6;

    // prologue: stage tile 0 into bufs {0, 2}
    gload16(ks0,              &KV[0][(wid * 16 + 0) * 64]);
    gload16(ks0 + 8 * DMODEL, &KV[0][(wid * 16 + 8) * 64]);
    gload16(vs0,              &KV[2][(wid * 16 + 0) * 64]);
    gload16(vs0 + 8 * SEQ,    &KV[2][(wid * 16 + 8) * 64]);
    const u16* kpre = ks0 + 64 * DMODEL;
    const u16* vpre = vs0 + 64;
    __syncthreads();

    for (int t = 0; t < nsteps; ++t) {
      const int cur = t & 1;
      const int kb = t * 64;
      if (t + 1 < nsteps) {
        gload16(kpre,              &KV[cur ^ 1][(wid * 16 + 0) * 64]);
        gload16(kpre + 8 * DMODEL, &KV[cur ^ 1][(wid * 16 + 8) * 64]);
        gload16(vpre,              &KV[2 + (cur ^ 1)][(wid * 16 + 0) * 64]);
        gload16(vpre + 8 * SEQ,    &KV[2 + (cur ^ 1)][(wid * 16 + 8) * 64]);
        kpre += 64 * DMODEL; vpre += 64;
      }
      // swapped QK^T: sa[kblk][nb][r] = S[key=kb+wk*32+kblk*16+quad*4+r][q=qbase+nb*16+fr]
      const u16* kr0 = &KV[cur][(wk * 32 + fr) * 64];
      f32x4 sa[2][2];
      __builtin_amdgcn_s_setprio(1);
      {
        bf16x8 kfa = *(const bf16x8*)&kr0[xk0];
        bf16x8 kfb = *(const bf16x8*)&kr0[xk1];
        f32x4 s = {};
        s = MFMA16(kfa, aq[0][0], s); s = MFMA16(kfb, aq[0][1], s); sa[0][0] = s;
        s = (f32x4){};
        s = MFMA16(kfa, aq[1][0], s); s = MFMA16(kfb, aq[1][1], s); sa[0][1] = s;
        kfa = *(const bf16x8*)&kr0[16 * 64 + xk0];
        kfb = *(const bf16x8*)&kr0[16 * 64 + xk1];
        s = (f32x4){};
        s = MFMA16(kfa, aq[0][0], s); s = MFMA16(kfb, aq[0][1], s); sa[1][0] = s;
        s = (f32x4){};
        s = MFMA16(kfa, aq[1][0], s); s = MFMA16(kfb, aq[1][1], s); sa[1][1] = s;
      }
      __builtin_amdgcn_s_setprio(0);

      if (causal && kb + wk * 32 + 31 > qbase) {   // wave-uniform diagonal check
#pragma unroll
        for (int kblk = 0; kblk < 2; ++kblk)
#pragma unroll
          for (int nb = 0; nb < 2; ++nb) {
            int key = kb + wk * 32 + kblk * 16 + quad * 4;
            int q   = qbase + nb * 16 + fr;
#pragma unroll
            for (int r = 0; r < 4; ++r)
              if (key + r > q) sa[kblk][nb][r] = MASKV;
          }
      }

      // ---- defer-max softmax (lane-local partials; v_max3 tile-max) ----
      float lm[2];
#pragma unroll
      for (int nb = 0; nb < 2; ++nb) {
        float m1 = max3f(sa[0][nb][0], sa[0][nb][1], sa[0][nb][2]);
        float m2 = max3f(sa[0][nb][3], sa[1][nb][0], sa[1][nb][1]);
        float m3 = max3f(sa[1][nb][2], sa[1][nb][3], m1);
        lm[nb] = fmaxf(m2, m3);
      }
      int ok = (lm[0] <= mrow[0] + 11.f) & (lm[1] <= mrow[1] + 11.f);
      if (!__all(ok)) {
#pragma unroll
        for (int nb = 0; nb < 2; ++nb) {
          float mx = lm[nb];
          mx = fmaxf(mx, __shfl_xor(mx, 16));
          mx = fmaxf(mx, __shfl_xor(mx, 32));
          float mnew = fmaxf(mrow[nb], mx);
          float a = __builtin_amdgcn_exp2f(mrow[nb] - mnew);
          mrow[nb] = mnew;
          lp[nb] *= a;
#pragma unroll
          for (int r = 0; r < 4; ++r) {
            float ar = __shfl(a, (lane & 48) | (quad * 4 + r));
            oacc[nb][0][r] *= ar; oacc[nb][1][r] *= ar;
            oacc[nb][2][r] *= ar; oacc[nb][3][r] *= ar;
          }
        }
      }

      // exp2 + cvt_pk P^T into one K=32 A-frag per nb (slot = quad*8 + kblk*4 + r)
      bf16x8 pa32[2];
#pragma unroll
      for (int nb = 0; nb < 2; ++nb) {
        u32x4 pw;
#pragma unroll
        for (int kblk = 0; kblk < 2; ++kblk) {
          float p0 = __builtin_amdgcn_exp2f(sa[kblk][nb][0] - mrow[nb]);
          float p1 = __builtin_amdgcn_exp2f(sa[kblk][nb][1] - mrow[nb]);
          float p2 = __builtin_amdgcn_exp2f(sa[kblk][nb][2] - mrow[nb]);
          float p3 = __builtin_amdgcn_exp2f(sa[kblk][nb][3] - mrow[nb]);
          lp[nb] += (p0 + p1) + (p2 + p3);
          pw[kblk * 2 + 0] = f2bf2(p0, p1);
          pw[kblk * 2 + 1] = f2bf2(p2, p3);
        }
        pa32[nb] = __builtin_bit_cast(bf16x8, pw);
      }

      // PV K=32: one b128 per d-block (s-permuted Vt rows match pa32's key order)
      __builtin_amdgcn_s_setprio(1);
#pragma unroll
      for (int db = 0; db < 4; ++db) {
        const u16* vr = &KV[2 + cur][(db * 16 + fr) * 64];
        bf16x8 vv = *(const bf16x8*)&vr[xv];
        oacc[0][db] = MFMA16(pa32[0], vv, oacc[0][db]);
        oacc[1][db] = MFMA16(pa32[1], vv, oacc[1][db]);
      }
      __builtin_amdgcn_s_setprio(0);
      __syncthreads();   // buf[cur] reads done; buf[cur^1] staging drained
    }

    // ---- tile epilogue: finalize within wave, 2-way split-K merge across wk ----
#pragma unroll
    for (int nb = 0; nb < 2; ++nb) {
      lp[nb] += __shfl_xor(lp[nb], 16);
      lp[nb] += __shfl_xor(lp[nb], 32);
    }
    float mr2[2][4], lr2[2][4];
#pragma unroll
    for (int nb = 0; nb < 2; ++nb)
#pragma unroll
      for (int r = 0; r < 4; ++r) {
        int src = (lane & 48) | (quad * 4 + r);
        mr2[nb][r] = __shfl(mrow[nb], src);
        lr2[nb][r] = __shfl(lp[nb],   src);
      }
    float* mp = mbuf + (size_t)(wq * 64 + lane) * 50;
    if (wk) {
#pragma unroll
      for (int nb = 0; nb < 2; ++nb)
#pragma unroll
        for (int db = 0; db < 4; ++db) {
          *(float2*)&mp[(nb * 4 + db) * 4 + 0] = make_float2(oacc[nb][db][0], oacc[nb][db][1]);
          *(float2*)&mp[(nb * 4 + db) * 4 + 2] = make_float2(oacc[nb][db][2], oacc[nb][db][3]);
        }
#pragma unroll
      for (int nb = 0; nb < 2; ++nb) {
        *(float2*)&mp[32 + nb * 4 + 0] = make_float2(mr2[nb][0], mr2[nb][1]);
        *(float2*)&mp[32 + nb * 4 + 2] = make_float2(mr2[nb][2], mr2[nb][3]);
        *(float2*)&mp[40 + nb * 4 + 0] = make_float2(lr2[nb][0], lr2[nb][1]);
        *(float2*)&mp[40 + nb * 4 + 2] = make_float2(lr2[nb][2], lr2[nb][3]);
      }
    }
    __syncthreads();
    if (!wk) {
      float w0[2][4], w1[2][4];
#pragma unroll
      for (int nb = 0; nb < 2; ++nb)
#pragma unroll
        for (int r = 0; r < 4; ++r) {
          float m1 = mp[32 + nb * 4 + r];
          float l1 = mp[40 + nb * 4 + r];
          float M  = fmaxf(mr2[nb][r], m1);
          float c0 = __builtin_amdgcn_exp2f(mr2[nb][r] - M);
          float c1 = __builtin_amdgcn_exp2f(m1 - M);
          float inv = 1.0f / (lr2[nb][r] * c0 + l1 * c1);
          w0[nb][r] = c0 * inv;
          w1[nb][r] = c1 * inv;
        }
#pragma unroll
      for (int nb = 0; nb < 2; ++nb) {
        u16* op = O + (size_t)(b * SEQ + qbase + nb * 16 + quad * 4) * DMODEL + h * HDIM + fr;
#pragma unroll
        for (int db = 0; db < 4; ++db) {
          float2 oa = *(float2*)&mp[(nb * 4 + db) * 4 + 0];
          float2 ob = *(float2*)&mp[(nb * 4 + db) * 4 + 2];
          float o1[4] = {oa.x, oa.y, ob.x, ob.y};
#pragma unroll
          for (int r = 0; r < 4; ++r)
            op[(size_t)r * DMODEL + db * 16] =
                f2bf(oacc[nb][db][r] * w0[nb][r] + o1[r] * w1[nb][r]);
        }
      }
    }
    __syncthreads();   // merge reads done before next tile's staging reuses KV
  }
}

// ---------------- launcher ----------------
extern "C" void kernel_launch(void* const* d_in, const int* in_sizes, int n_in,
                              void* d_out, int out_size, void* d_ws, size_t ws_size,
                              hipStream_t stream)
{
  const float* x   = (const float*)d_in[0];
  const float* ek  = (const float*)d_in[1];
  const float* ev  = (const float*)d_in[2];
  const float* Wq1 = (const float*)d_in[3];
  const float* bq1 = (const float*)d_in[4];
  const float* Wk1 = (const float*)d_in[5];
  const float* bk1 = (const float*)d_in[6];
  const float* Wv1 = (const float*)d_in[7];
  const float* bv1 = (const float*)d_in[8];
  const float* Wo1 = (const float*)d_in[9];
  const float* bo1 = (const float*)d_in[10];
  const float* Wq2 = (const float*)d_in[11];
  const float* bq2 = (const float*)d_in[12];
  const float* Wk2 = (const float*)d_in[13];
  const float* bk2 = (const float*)d_in[14];
  const float* Wv2 = (const float*)d_in[15];
  const float* bv2 = (const float*)d_in[16];
  const float* Wo2 = (const float*)d_in[17];
  const float* bo2 = (const float*)d_in[18];

  char* ws = (char*)d_ws;
  u16* wt  = (u16*)ws;
  u16* xb  = (u16*)(ws + (16u << 20));
  u16* ekb = (u16*)(ws + (32u << 20));
  u16* evb = (u16*)(ws + (48u << 20));
  u16* qb  = (u16*)(ws + (64u << 20));
  u16* kkb = (u16*)(ws + (80u << 20));
  u16* vtb = (u16*)(ws + (96u << 20));
  u16* hb  = (u16*)(ws + (112u << 20));
  u16* ob  = xb;   // x dead after layer-1 projections

  const int n4 = MTOT * DMODEL / 4;
  const float qscale = 0.125f * 1.4426950408889634f;   // 1/sqrt(HD) * log2(e)

  pack_act3<<<dim3(n4 / 256, 3), 256, 0, stream>>>(x, ek, ev, xb, ekb, evb, n4);
  pack_w8<<<dim3(16, 16, 8), 256, 0, stream>>>(Wq1, Wk1, Wv1, Wo1, Wq2, Wk2, Wv2, Wo2, wt);

  const int gblocks = (MTOT / 128) * (DMODEL / 128);   // 512, XCD-swizzled in-kernel
  const int ablocks_causal = (SEQ / 128) * BSZ * NHEAD; // 1024 pair-blocks
  const int ablocks_cross  = (SEQ / 64) * BSZ * NHEAD;  // 2048 single-tile blocks

  // layer 1: causal self-attention
  gemm_qkv<<<3 * gblocks, 256, 0, stream>>>(xb, xb, xb, wt, bq1, bk1, bv1,
                                            qb, kkb, vtb, qscale);
  attn_kernel<<<ablocks_causal, 256, 0, stream>>>(qb, kkb, vtb, ob, 1);
  gemm_bt<<<gblocks, 256, 0, stream>>>(ob, wt + 3 * NW, bo1, hb, 1.0f, 0);

  // layer 2: cross attention
  gemm_qkv<<<3 * gblocks, 256, 0, stream>>>(hb, ekb, evb, wt + 4 * NW, bq2, bk2, bv2,
                                            qb, kkb, vtb, qscale);
  attn_kernel<<<ablocks_cross, 256, 0, stream>>>(qb, kkb, vtb, ob, 0);
  gemm_bt<<<gblocks, 256, 0, stream>>>(ob, wt + 7 * NW, bo2, d_out, 1.0f, 2);
}

// Round 15
// 355.985 us; speedup vs baseline: 1.6455x; 1.0082x over previous
//
#include <hip/hip_runtime.h>
#include <hip/hip_bf16.h>
#include <cstdint>

typedef unsigned short u16;
typedef unsigned int   u32;
typedef __attribute__((ext_vector_type(8))) short bf16x8;   // 8 bf16 = 4 VGPRs
typedef __attribute__((ext_vector_type(4))) u32  u32x4;
typedef __attribute__((ext_vector_type(4))) float f32x4;

#define MFMA16(a,b,c)    __builtin_amdgcn_mfma_f32_16x16x32_bf16((a),(b),(c),0,0,0)

#define BSZ    4
#define SEQ    2048
#define DMODEL 1024
#define NHEAD  16
#define HDIM   64
#define MTOT   (BSZ*SEQ)   // 8192
#define MASKV  (-3.0e38f)  // finite: exp2(MASKV - m) == 0, no inf-inf NaN
#define NW     (DMODEL*DMODEL)

// native conversion (RNE)
__device__ __forceinline__ u16 f2bf(float f) {
  __hip_bfloat16 h = __float2bfloat16(f);
  return __builtin_bit_cast(u16, h);
}
// paired conversion -> single v_cvt_pk_bf16_f32 (RNE; byte-copy since bf162 isn't
// trivially copyable for bit_cast)
__device__ __forceinline__ u32 f2bf2(float a, float b) {
  __hip_bfloat162 h = __float22bfloat162_rn(make_float2(a, b));
  u32 u; __builtin_memcpy(&u, &h, sizeof(u));
  return u;
}
// fmax-of-3 -> v_max3_f32
__device__ __forceinline__ float max3f(float a, float b, float c) {
  return fmaxf(fmaxf(a, b), c);
}

typedef __attribute__((address_space(1))) void g1v;
typedef __attribute__((address_space(3))) void l3v;
// async global->LDS, 16B/lane. LDS dest is wave-uniform base (HW adds lane*16B).
__device__ __forceinline__ void gload16(const void* g, void* l) {
  __builtin_amdgcn_global_load_lds((g1v*)(uintptr_t)g, (l3v*)(u32)(uintptr_t)l, 16, 0, 0);
}

// ---------------- pack: fp32 -> bf16 activations (x, ek, ev in one launch) ----------
__global__ void pack_act3(const float* __restrict__ x, const float* __restrict__ ek,
                          const float* __restrict__ ev, u16* __restrict__ xb,
                          u16* __restrict__ ekb, u16* __restrict__ evb, int n4) {
  int i = blockIdx.x * blockDim.x + threadIdx.x;
  if (i >= n4) return;
  const float* in; u16* out;
  if (blockIdx.y == 0)      { in = x;  out = xb;  }
  else if (blockIdx.y == 1) { in = ek; out = ekb; }
  else                      { in = ev; out = evb; }
  float4 v = ((const float4*)in)[i];
  ((uint2*)out)[i] = make_uint2(f2bf2(v.x, v.y), f2bf2(v.z, v.w));
}

// ---------------- pack: all 8 weights -> Bt[n][k] bf16 in one launch ----------------
__global__ void pack_w8(const float* __restrict__ w0, const float* __restrict__ w1,
                        const float* __restrict__ w2, const float* __restrict__ w3,
                        const float* __restrict__ w4, const float* __restrict__ w5,
                        const float* __restrict__ w6, const float* __restrict__ w7,
                        u16* __restrict__ wt) {
  __shared__ float tile[64][65];
  const int w = blockIdx.z;
  const float* src;
  switch (w) {
    case 0: src = w0; break; case 1: src = w1; break;
    case 2: src = w2; break; case 3: src = w3; break;
    case 4: src = w4; break; case 5: src = w5; break;
    case 6: src = w6; break; default: src = w7; break;
  }
  const int per_head = (w == 3 || w == 7) ? 0 : 1;
  u16* dst = wt + (size_t)w * NW;
  int kt = blockIdx.x * 64, nt = blockIdx.y * 64;
  int tx = threadIdx.x & 63, ty = threadIdx.x >> 6;
  for (int kk = ty; kk < 64; kk += 4) {
    int k = kt + kk, n = nt + tx;
    float v = per_head ? src[(size_t)(n >> 6) * (DMODEL * HDIM) + (size_t)k * HDIM + (n & 63)]
                       : src[(size_t)k * DMODEL + n];
    tile[kk][tx] = v;
  }
  __syncthreads();
  for (int nn = ty; nn < 64; nn += 4)
    dst[(size_t)(nt + nn) * DMODEL + kt + tx] = f2bf(tile[tx][nn]);
}

// ---------------- GEMM core (BK=64 double-buffered 2-phase prefetch) ----------------
// epi: 0 = bf16 [M][N]; 1 = bf16 Vt s-permuted; 2 = f32 [M][N]
template <bool TMPL>
__device__ __forceinline__ void gemm_body(const u16* __restrict__ A, const u16* __restrict__ Bt,
                                          const float* __restrict__ bias, void* __restrict__ Cout,
                                          float scale, int epi, int inner)
{
  __shared__ u16 As[2][128 * 64];
  __shared__ u16 Bs[2][128 * 64];
  const int lane = threadIdx.x & 63, wid = threadIdx.x >> 6;
  const int wg = ((inner & 7) << 6) | (inner >> 3);  // [xcd:3][seq:6]
  const int m0 = (wg >> 3) * 128, n0 = (wg & 7) * 128;

  const int srow = wid * 32 + (lane >> 3);          // +i*8; (row&7) == lane>>3
  const int sc = (lane & 7) ^ ((lane >> 3) & 7);    // pre-swizzled source chunk
  const u16* gA = A  + (size_t)(m0 + srow) * DMODEL + sc * 8;
  const u16* gB = Bt + (size_t)(n0 + srow) * DMODEL + sc * 8;

  const int fr = lane & 15, quad = lane >> 4;
  const int wr = (wid >> 1) * 64, wc = (wid & 1) * 64;

  f32x4 acc[4][4] = {};
  const int NT = DMODEL / 64;   // 16

#pragma unroll
  for (int i = 0; i < 4; ++i) {
    gload16(gA + (size_t)(i * 8) * DMODEL, &As[0][(wid * 32 + i * 8) * 64]);
    gload16(gB + (size_t)(i * 8) * DMODEL, &Bs[0][(wid * 32 + i * 8) * 64]);
  }
  gA += 64; gB += 64;
  __syncthreads();

  for (int kt = 0; kt < NT; ++kt) {
    const int cur = kt & 1;
    if (kt + 1 < NT) {
#pragma unroll
      for (int i = 0; i < 4; ++i) {
        gload16(gA + (size_t)(i * 8) * DMODEL, &As[cur ^ 1][(wid * 32 + i * 8) * 64]);
        gload16(gB + (size_t)(i * 8) * DMODEL, &Bs[cur ^ 1][(wid * 32 + i * 8) * 64]);
      }
      gA += 64; gB += 64;
    }
#pragma unroll
    for (int kp = 0; kp < 2; ++kp) {
      bf16x8 af[4], bfr[4];
#pragma unroll
      for (int i = 0; i < 4; ++i) {
        int ra = wr + i * 16 + fr;
        af[i]  = *(const bf16x8*)&As[cur][ra * 64 + (((kp * 4 + quad) ^ (ra & 7)) * 8)];
        int rb = wc + i * 16 + fr;
        bfr[i] = *(const bf16x8*)&Bs[cur][rb * 64 + (((kp * 4 + quad) ^ (rb & 7)) * 8)];
      }
#pragma unroll
      for (int i = 0; i < 4; ++i)
#pragma unroll
        for (int j = 0; j < 4; ++j)
          acc[i][j] = MFMA16(af[i], bfr[j], acc[i][j]);
    }
    __syncthreads();   // buf[cur] reads done; buf[cur^1] staging drained
  }

  // C/D layout: col = lane&15, row = (lane>>4)*4 + reg
#pragma unroll
  for (int i = 0; i < 4; ++i) {
    int row0 = m0 + wr + i * 16 + quad * 4;
#pragma unroll
    for (int j = 0; j < 4; ++j) {
      int col = n0 + wc + j * 16 + fr;
      float bv = bias[col];
      float v0 = (acc[i][j][0] + bv) * scale, v1 = (acc[i][j][1] + bv) * scale;
      float v2 = (acc[i][j][2] + bv) * scale, v3 = (acc[i][j][3] + bv) * scale;
      if (epi == 2) {
        float* C = (float*)Cout;
        C[(size_t)(row0 + 0) * DMODEL + col] = v0;
        C[(size_t)(row0 + 1) * DMODEL + col] = v1;
        C[(size_t)(row0 + 2) * DMODEL + col] = v2;
        C[(size_t)(row0 + 3) * DMODEL + col] = v3;
      } else if (epi == 0) {
        u16* C = (u16*)Cout;
        C[(size_t)(row0 + 0) * DMODEL + col] = f2bf(v0);
        C[(size_t)(row0 + 1) * DMODEL + col] = f2bf(v1);
        C[(size_t)(row0 + 2) * DMODEL + col] = f2bf(v2);
        C[(size_t)(row0 + 3) * DMODEL + col] = f2bf(v3);
      } else {
        u16* C = (u16*)Cout;
        int bi = row0 >> 11, s = row0 & 2047;
        // permuted s within 32-group: (b:1|c:2|r:2) -> (c:2|b:1|r:2)
        int sN = (s & ~31) | (((s >> 2) & 3) << 3) | (((s >> 4) & 1) << 2) | (s & 3);
        size_t vtr = ((size_t)(bi * NHEAD + (col >> 6)) * HDIM + (col & 63)) * SEQ + sN;
        *(uint2*)&C[vtr] = make_uint2(f2bf2(v0, v1), f2bf2(v2, v3));
      }
    }
  }
}

// single GEMM (Wo projections, final output)
__global__ __launch_bounds__(256, 2)
void gemm_bt(const u16* __restrict__ A, const u16* __restrict__ Bt,
             const float* __restrict__ bias, void* __restrict__ Cout,
             float scale, int epi)
{
  gemm_body<true>(A, Bt, bias, Cout, scale, epi, blockIdx.x);
}

// fused Q/K/V projections: 3 x 512 blocks; seg = bid>>9 picks operands (uniform)
__global__ __launch_bounds__(256, 2)
void gemm_qkv(const u16* __restrict__ Aq, const u16* __restrict__ Ak,
              const u16* __restrict__ Av, const u16* __restrict__ Btb,
              const float* __restrict__ bq, const float* __restrict__ bk,
              const float* __restrict__ bv, void* __restrict__ oq,
              void* __restrict__ ok, void* __restrict__ ov, float qscale)
{
  const int seg = blockIdx.x >> 9, inner = blockIdx.x & 511;
  const u16* A; const float* bias; void* Cout; float scale; int epi;
  if (seg == 0)      { A = Aq; bias = bq; Cout = oq; scale = qscale; epi = 0; }
  else if (seg == 1) { A = Ak; bias = bk; Cout = ok; scale = 1.0f;   epi = 0; }
  else               { A = Av; bias = bv; Cout = ov; scale = 1.0f;   epi = 1; }
  gemm_body<true>(A, Btb + (size_t)seg * NW, bias, Cout, scale, epi, inner);
}

// ---------------- flash attention v13 ----------------
// v12 + MFMA row-sum: l = P*ones via one extra MFMA per nb (constant ones B-frag,
// all 16 cols identical => oaccl[nb][r] holds l for row quad*4+r, same row space
// as oacc). Removes 16 lp-adds/step + all epilogue lp shuffles.
// Split-K waves 2x2, swapped QK^T, zero-shuffle P, K=32 PV via s-permuted Vt.
// Causal: 1024 paired blocks (uniform 33 steps). Cross: 2048 single-tile blocks.
__global__ __launch_bounds__(256, 4)
void attn_kernel(const u16* __restrict__ Q, const u16* __restrict__ K,
                 const u16* __restrict__ Vt, u16* __restrict__ O, int causal)
{
  __shared__ u16 KV[4][64 * 64];   // [0,1]=K dbuf, [2,3]=V dbuf; merge reuses as f32
  const int lane = threadIdx.x & 63, wid = threadIdx.x >> 6;
  const int fr = lane & 15, quad = lane >> 4;
  const int wq = wid >> 1, wk = wid & 1;

  const int flat = blockIdx.x;
  int bh, qb0, qb1, ntiles;
  if (causal) {                     // [bh_hi:3][pair:4][xcd:3]
    bh = ((flat >> 7) << 3) | (flat & 7);
    const int pair = (flat >> 3) & 15;
    qb0 = 31 - pair; qb1 = pair; ntiles = 2;
  } else {                          // [bh_hi:3][qb:5][xcd:3]
    bh = ((flat >> 8) << 3) | (flat & 7);
    qb0 = (flat >> 3) & 31; qb1 = 0; ntiles = 1;
  }
  const int b = bh >> 4, h = bh & 15;

  // constant all-ones B-frag (bf16 1.0 = 0x3F80)
  const short one = (short)0x3F80;
  const bf16x8 vones = {one, one, one, one, one, one, one, one};

  // loop-invariant swizzled LDS element offsets
  const int xk0 = ((quad    ) ^ (fr & 7)) * 8;
  const int xk1 = ((quad + 4) ^ (fr & 7)) * 8;
  const int xv  = ((wk * 4 + quad) ^ (fr & 7)) * 8;   // one b128: full K=32 B-frag

  const int srow = wid * 16 + (lane >> 3);
  const int jg = (lane & 7) ^ (srow & 7);   // same for srow and srow+8
  const u16* kg = K + (size_t)b * SEQ * DMODEL + h * HDIM;
  const u16* vg = Vt + (size_t)bh * HDIM * SEQ;
  const u16* ks0 = kg + (size_t)srow * DMODEL + jg * 8;
  const u16* vs0 = vg + (size_t)srow * SEQ + jg * 8;
  float* mbuf = (float*)&KV[0][0];          // merge scratch (25.6KB < 32KB)

  for (int tile = 0; tile < ntiles; ++tile) {
    const int qb = tile == 0 ? qb0 : qb1;
    const int q0 = qb * 64;
    const int qbase = q0 + wq * 32;

    bf16x8 aq[2][2];
#pragma unroll
    for (int nb = 0; nb < 2; ++nb) {
      const u16* qp = Q + (size_t)(b * SEQ + qbase + nb * 16 + fr) * DMODEL + h * HDIM + quad * 8;
      aq[nb][0] = *(const bf16x8*)qp;
      aq[nb][1] = *(const bf16x8*)(qp + 32);
    }

    f32x4 oacc[2][4] = {};
    f32x4 oaccl[2] = {};              // MFMA-accumulated row sums (replicated cols)
    float mrow[2] = {-1e30f, -1e30f};

    const int nsteps = (causal ? (q0 + 64) : SEQ) >> 6;

    // prologue: stage tile 0 into bufs {0, 2}
    gload16(ks0,              &KV[0][(wid * 16 + 0) * 64]);
    gload16(ks0 + 8 * DMODEL, &KV[0][(wid * 16 + 8) * 64]);
    gload16(vs0,              &KV[2][(wid * 16 + 0) * 64]);
    gload16(vs0 + 8 * SEQ,    &KV[2][(wid * 16 + 8) * 64]);
    const u16* kpre = ks0 + 64 * DMODEL;
    const u16* vpre = vs0 + 64;
    __syncthreads();

    for (int t = 0; t < nsteps; ++t) {
      const int cur = t & 1;
      const int kb = t * 64;
      if (t + 1 < nsteps) {
        gload16(kpre,              &KV[cur ^ 1][(wid * 16 + 0) * 64]);
        gload16(kpre + 8 * DMODEL, &KV[cur ^ 1][(wid * 16 + 8) * 64]);
        gload16(vpre,              &KV[2 + (cur ^ 1)][(wid * 16 + 0) * 64]);
        gload16(vpre + 8 * SEQ,    &KV[2 + (cur ^ 1)][(wid * 16 + 8) * 64]);
        kpre += 64 * DMODEL; vpre += 64;
      }
      // swapped QK^T: sa[kblk][nb][r] = S[key=kb+wk*32+kblk*16+quad*4+r][q=qbase+nb*16+fr]
      const u16* kr0 = &KV[cur][(wk * 32 + fr) * 64];
      f32x4 sa[2][2];
      __builtin_amdgcn_s_setprio(1);
      {
        bf16x8 kfa = *(const bf16x8*)&kr0[xk0];
        bf16x8 kfb = *(const bf16x8*)&kr0[xk1];
        f32x4 s = {};
        s = MFMA16(kfa, aq[0][0], s); s = MFMA16(kfb, aq[0][1], s); sa[0][0] = s;
        s = (f32x4){};
        s = MFMA16(kfa, aq[1][0], s); s = MFMA16(kfb, aq[1][1], s); sa[0][1] = s;
        kfa = *(const bf16x8*)&kr0[16 * 64 + xk0];
        kfb = *(const bf16x8*)&kr0[16 * 64 + xk1];
        s = (f32x4){};
        s = MFMA16(kfa, aq[0][0], s); s = MFMA16(kfb, aq[0][1], s); sa[1][0] = s;
        s = (f32x4){};
        s = MFMA16(kfa, aq[1][0], s); s = MFMA16(kfb, aq[1][1], s); sa[1][1] = s;
      }
      __builtin_amdgcn_s_setprio(0);

      if (causal && kb + wk * 32 + 31 > qbase) {   // wave-uniform diagonal check
#pragma unroll
        for (int kblk = 0; kblk < 2; ++kblk)
#pragma unroll
          for (int nb = 0; nb < 2; ++nb) {
            int key = kb + wk * 32 + kblk * 16 + quad * 4;
            int q   = qbase + nb * 16 + fr;
#pragma unroll
            for (int r = 0; r < 4; ++r)
              if (key + r > q) sa[kblk][nb][r] = MASKV;
          }
      }

      // ---- defer-max softmax (lane-local partials; v_max3 tile-max) ----
      float lm[2];
#pragma unroll
      for (int nb = 0; nb < 2; ++nb) {
        float m1 = max3f(sa[0][nb][0], sa[0][nb][1], sa[0][nb][2]);
        float m2 = max3f(sa[0][nb][3], sa[1][nb][0], sa[1][nb][1]);
        float m3 = max3f(sa[1][nb][2], sa[1][nb][3], m1);
        lm[nb] = fmaxf(m2, m3);
      }
      int ok = (lm[0] <= mrow[0] + 11.f) & (lm[1] <= mrow[1] + 11.f);
      if (!__all(ok)) {
#pragma unroll
        for (int nb = 0; nb < 2; ++nb) {
          float mx = lm[nb];
          mx = fmaxf(mx, __shfl_xor(mx, 16));
          mx = fmaxf(mx, __shfl_xor(mx, 32));
          float mnew = fmaxf(mrow[nb], mx);
          float a = __builtin_amdgcn_exp2f(mrow[nb] - mnew);
          mrow[nb] = mnew;
#pragma unroll
          for (int r = 0; r < 4; ++r) {
            float ar = __shfl(a, (lane & 48) | (quad * 4 + r));
            oacc[nb][0][r] *= ar; oacc[nb][1][r] *= ar;
            oacc[nb][2][r] *= ar; oacc[nb][3][r] *= ar;
            oaccl[nb][r]   *= ar;
          }
        }
      }

      // exp2 + cvt_pk P^T into one K=32 A-frag per nb (slot = quad*8 + kblk*4 + r)
      bf16x8 pa32[2];
#pragma unroll
      for (int nb = 0; nb < 2; ++nb) {
        u32x4 pw;
#pragma unroll
        for (int kblk = 0; kblk < 2; ++kblk) {
          float p0 = __builtin_amdgcn_exp2f(sa[kblk][nb][0] - mrow[nb]);
          float p1 = __builtin_amdgcn_exp2f(sa[kblk][nb][1] - mrow[nb]);
          float p2 = __builtin_amdgcn_exp2f(sa[kblk][nb][2] - mrow[nb]);
          float p3 = __builtin_amdgcn_exp2f(sa[kblk][nb][3] - mrow[nb]);
          pw[kblk * 2 + 0] = f2bf2(p0, p1);
          pw[kblk * 2 + 1] = f2bf2(p2, p3);
        }
        pa32[nb] = __builtin_bit_cast(bf16x8, pw);
      }

      // PV K=32 + MFMA row-sum (l = P * ones, every col identical)
      __builtin_amdgcn_s_setprio(1);
      oaccl[0] = MFMA16(pa32[0], vones, oaccl[0]);
      oaccl[1] = MFMA16(pa32[1], vones, oaccl[1]);
#pragma unroll
      for (int db = 0; db < 4; ++db) {
        const u16* vr = &KV[2 + cur][(db * 16 + fr) * 64];
        bf16x8 vv = *(const bf16x8*)&vr[xv];
        oacc[0][db] = MFMA16(pa32[0], vv, oacc[0][db]);
        oacc[1][db] = MFMA16(pa32[1], vv, oacc[1][db]);
      }
      __builtin_amdgcn_s_setprio(0);
      __syncthreads();   // buf[cur] reads done; buf[cur^1] staging drained
    }

    // ---- tile epilogue: 2-way split-K merge across wk (l comes free from oaccl) ----
    float mr2[2][4];
#pragma unroll
    for (int nb = 0; nb < 2; ++nb)
#pragma unroll
      for (int r = 0; r < 4; ++r) {
        int src = (lane & 48) | (quad * 4 + r);
        mr2[nb][r] = __shfl(mrow[nb], src);
      }
    float* mp = mbuf + (size_t)(wq * 64 + lane) * 50;
    if (wk) {
#pragma unroll
      for (int nb = 0; nb < 2; ++nb)
#pragma unroll
        for (int db = 0; db < 4; ++db) {
          *(float2*)&mp[(nb * 4 + db) * 4 + 0] = make_float2(oacc[nb][db][0], oacc[nb][db][1]);
          *(float2*)&mp[(nb * 4 + db) * 4 + 2] = make_float2(oacc[nb][db][2], oacc[nb][db][3]);
        }
#pragma unroll
      for (int nb = 0; nb < 2; ++nb) {
        *(float2*)&mp[32 + nb * 4 + 0] = make_float2(mr2[nb][0], mr2[nb][1]);
        *(float2*)&mp[32 + nb * 4 + 2] = make_float2(mr2[nb][2], mr2[nb][3]);
        *(float2*)&mp[40 + nb * 4 + 0] = make_float2(oaccl[nb][0], oaccl[nb][1]);
        *(float2*)&mp[40 + nb * 4 + 2] = make_float2(oaccl[nb][2], oaccl[nb][3]);
      }
    }
    __syncthreads();
    if (!wk) {
      float w0[2][4], w1[2][4];
#pragma unroll
      for (int nb = 0; nb < 2; ++nb)
#pragma unroll
        for (int r = 0; r < 4; ++r) {
          float m1 = mp[32 + nb * 4 + r];
          float l1 = mp[40 + nb * 4 + r];
          float M  = fmaxf(mr2[nb][r], m1);
          float c0 = __builtin_amdgcn_exp2f(mr2[nb][r] - M);
          float c1 = __builtin_amdgcn_exp2f(m1 - M);
          float inv = 1.0f / (oaccl[nb][r] * c0 + l1 * c1);
          w0[nb][r] = c0 * inv;
          w1[nb][r] = c1 * inv;
        }
#pragma unroll
      for (int nb = 0; nb < 2; ++nb) {
        u16* op = O + (size_t)(b * SEQ + qbase + nb * 16 + quad * 4) * DMODEL + h * HDIM + fr;
#pragma unroll
        for (int db = 0; db < 4; ++db) {
          float2 oa = *(float2*)&mp[(nb * 4 + db) * 4 + 0];
          float2 ob = *(float2*)&mp[(nb * 4 + db) * 4 + 2];
          float o1[4] = {oa.x, oa.y, ob.x, ob.y};
#pragma unroll
          for (int r = 0; r < 4; ++r)
            op[(size_t)r * DMODEL + db * 16] =
                f2bf(oacc[nb][db][r] * w0[nb][r] + o1[r] * w1[nb][r]);
        }
      }
    }
    __syncthreads();   // merge reads done before next tile's staging reuses KV
  }
}

// ---------------- launcher ----------------
extern "C" void kernel_launch(void* const* d_in, const int* in_sizes, int n_in,
                              void* d_out, int out_size, void* d_ws, size_t ws_size,
                              hipStream_t stream)
{
  const float* x   = (const float*)d_in[0];
  const float* ek  = (const float*)d_in[1];
  const float* ev  = (const float*)d_in[2];
  const float* Wq1 = (const float*)d_in[3];
  const float* bq1 = (const float*)d_in[4];
  const float* Wk1 = (const float*)d_in[5];
  const float* bk1 = (const float*)d_in[6];
  const float* Wv1 = (const float*)d_in[7];
  const float* bv1 = (const float*)d_in[8];
  const float* Wo1 = (const float*)d_in[9];
  const float* bo1 = (const float*)d_in[10];
  const float* Wq2 = (const float*)d_in[11];
  const float* bq2 = (const float*)d_in[12];
  const float* Wk2 = (const float*)d_in[13];
  const float* bk2 = (const float*)d_in[14];
  const float* Wv2 = (const float*)d_in[15];
  const float* bv2 = (const float*)d_in[16];
  const float* Wo2 = (const float*)d_in[17];
  const float* bo2 = (const float*)d_in[18];

  char* ws = (char*)d_ws;
  u16* wt  = (u16*)ws;
  u16* xb  = (u16*)(ws + (16u << 20));
  u16* ekb = (u16*)(ws + (32u << 20));
  u16* evb = (u16*)(ws + (48u << 20));
  u16* qb  = (u16*)(ws + (64u << 20));
  u16* kkb = (u16*)(ws + (80u << 20));
  u16* vtb = (u16*)(ws + (96u << 20));
  u16* hb  = (u16*)(ws + (112u << 20));
  u16* ob  = xb;   // x dead after layer-1 projections

  const int n4 = MTOT * DMODEL / 4;
  const float qscale = 0.125f * 1.4426950408889634f;   // 1/sqrt(HD) * log2(e)

  pack_act3<<<dim3(n4 / 256, 3), 256, 0, stream>>>(x, ek, ev, xb, ekb, evb, n4);
  pack_w8<<<dim3(16, 16, 8), 256, 0, stream>>>(Wq1, Wk1, Wv1, Wo1, Wq2, Wk2, Wv2, Wo2, wt);

  const int gblocks = (MTOT / 128) * (DMODEL / 128);   // 512, XCD-swizzled in-kernel
  const int ablocks_causal = (SEQ / 128) * BSZ * NHEAD; // 1024 pair-blocks
  const int ablocks_cross  = (SEQ / 64) * BSZ * NHEAD;  // 2048 single-tile blocks

  // layer 1: causal self-attention
  gemm_qkv<<<3 * gblocks, 256, 0, stream>>>(xb, xb, xb, wt, bq1, bk1, bv1,
                                            qb, kkb, vtb, qscale);
  attn_kernel<<<ablocks_causal, 256, 0, stream>>>(qb, kkb, vtb, ob, 1);
  gemm_bt<<<gblocks, 256, 0, stream>>>(ob, wt + 3 * NW, bo1, hb, 1.0f, 0);

  // layer 2: cross attention
  gemm_qkv<<<3 * gblocks, 256, 0, stream>>>(hb, ekb, evb, wt + 4 * NW, bq2, bk2, bv2,
                                            qb, kkb, vtb, qscale);
  attn_kernel<<<ablocks_cross, 256, 0, stream>>>(qb, kkb, vtb, ob, 0);
  gemm_bt<<<gblocks, 256, 0, stream>>>(ob, wt + 7 * NW, bo2, d_out, 1.0f, 2);
}

// Round 16
// 353.818 us; speedup vs baseline: 1.6556x; 1.0061x over previous
//
#include <hip/hip_runtime.h>
#include <hip/hip_bf16.h>
#include <cstdint>

typedef unsigned short u16;
typedef unsigned int   u32;
typedef __attribute__((ext_vector_type(8))) short bf16x8;   // 8 bf16 = 4 VGPRs
typedef __attribute__((ext_vector_type(4))) u32  u32x4;
typedef __attribute__((ext_vector_type(4))) float f32x4;

#define MFMA16(a,b,c)    __builtin_amdgcn_mfma_f32_16x16x32_bf16((a),(b),(c),0,0,0)

#define BSZ    4
#define SEQ    2048
#define DMODEL 1024
#define NHEAD  16
#define HDIM   64
#define MTOT   (BSZ*SEQ)   // 8192
#define MASKV  (-3.0e38f)  // finite: exp2(MASKV - m) == 0, no inf-inf NaN
#define NW     (DMODEL*DMODEL)

// native conversion (RNE)
__device__ __forceinline__ u16 f2bf(float f) {
  __hip_bfloat16 h = __float2bfloat16(f);
  return __builtin_bit_cast(u16, h);
}
// paired conversion -> v_cvt_pk_bf16_f32 (RNE)
__device__ __forceinline__ u32 f2bf2(float a, float b) {
  __hip_bfloat162 h = __float22bfloat162_rn(make_float2(a, b));
  u32 u; __builtin_memcpy(&u, &h, sizeof(u));
  return u;
}
// fmax-of-3 -> v_max3_f32
__device__ __forceinline__ float max3f(float a, float b, float c) {
  return fmaxf(fmaxf(a, b), c);
}

typedef __attribute__((address_space(1))) void g1v;
typedef __attribute__((address_space(3))) void l3v;
// async global->LDS, 16B/lane. LDS dest is wave-uniform base (HW adds lane*16B).
__device__ __forceinline__ void gload16(const void* g, void* l) {
  __builtin_amdgcn_global_load_lds((g1v*)(uintptr_t)g, (l3v*)(u32)(uintptr_t)l, 16, 0, 0);
}

// ---------------- pack: fp32 -> bf16 activations (x, ek, ev in one launch) ----------
__global__ void pack_act3(const float* __restrict__ x, const float* __restrict__ ek,
                          const float* __restrict__ ev, u16* __restrict__ xb,
                          u16* __restrict__ ekb, u16* __restrict__ evb, int n4) {
  int i = blockIdx.x * blockDim.x + threadIdx.x;
  if (i >= n4) return;
  const float* in; u16* out;
  if (blockIdx.y == 0)      { in = x;  out = xb;  }
  else if (blockIdx.y == 1) { in = ek; out = ekb; }
  else                      { in = ev; out = evb; }
  float4 v = ((const float4*)in)[i];
  ((uint2*)out)[i] = make_uint2(f2bf2(v.x, v.y), f2bf2(v.z, v.w));
}

// ---------------- pack: all 8 weights -> Bt[n][k] bf16 in one launch ----------------
__global__ void pack_w8(const float* __restrict__ w0, const float* __restrict__ w1,
                        const float* __restrict__ w2, const float* __restrict__ w3,
                        const float* __restrict__ w4, const float* __restrict__ w5,
                        const float* __restrict__ w6, const float* __restrict__ w7,
                        u16* __restrict__ wt) {
  __shared__ float tile[64][65];
  const int w = blockIdx.z;
  const float* src;
  switch (w) {
    case 0: src = w0; break; case 1: src = w1; break;
    case 2: src = w2; break; case 3: src = w3; break;
    case 4: src = w4; break; case 5: src = w5; break;
    case 6: src = w6; break; default: src = w7; break;
  }
  const int per_head = (w == 3 || w == 7) ? 0 : 1;
  u16* dst = wt + (size_t)w * NW;
  int kt = blockIdx.x * 64, nt = blockIdx.y * 64;
  int tx = threadIdx.x & 63, ty = threadIdx.x >> 6;
  for (int kk = ty; kk < 64; kk += 4) {
    int k = kt + kk, n = nt + tx;
    float v = per_head ? src[(size_t)(n >> 6) * (DMODEL * HDIM) + (size_t)k * HDIM + (n & 63)]
                       : src[(size_t)k * DMODEL + n];
    tile[kk][tx] = v;
  }
  __syncthreads();
  for (int nn = ty; nn < 64; nn += 4)
    dst[(size_t)(nt + nn) * DMODEL + kt + tx] = f2bf(tile[tx][nn]);
}

// ---------------- GEMM core (BK=64 double-buffered 2-phase prefetch) ----------------
// epi: 0 = bf16 [M][N]; 1 = bf16 Vt s-permuted; 2 = f32 [M][N]
template <bool TMPL>
__device__ __forceinline__ void gemm_body(const u16* __restrict__ A, const u16* __restrict__ Bt,
                                          const float* __restrict__ bias, void* __restrict__ Cout,
                                          float scale, int epi, int inner)
{
  __shared__ u16 As[2][128 * 64];
  __shared__ u16 Bs[2][128 * 64];
  const int lane = threadIdx.x & 63, wid = threadIdx.x >> 6;
  const int wg = ((inner & 7) << 6) | (inner >> 3);  // [xcd:3][seq:6]
  const int m0 = (wg >> 3) * 128, n0 = (wg & 7) * 128;

  const int srow = wid * 32 + (lane >> 3);          // +i*8; (row&7) == lane>>3
  const int sc = (lane & 7) ^ ((lane >> 3) & 7);    // pre-swizzled source chunk
  const u16* gA = A  + (size_t)(m0 + srow) * DMODEL + sc * 8;
  const u16* gB = Bt + (size_t)(n0 + srow) * DMODEL + sc * 8;

  const int fr = lane & 15, quad = lane >> 4;
  const int wr = (wid >> 1) * 64, wc = (wid & 1) * 64;

  f32x4 acc[4][4] = {};
  const int NT = DMODEL / 64;   // 16

#pragma unroll
  for (int i = 0; i < 4; ++i) {
    gload16(gA + (size_t)(i * 8) * DMODEL, &As[0][(wid * 32 + i * 8) * 64]);
    gload16(gB + (size_t)(i * 8) * DMODEL, &Bs[0][(wid * 32 + i * 8) * 64]);
  }
  gA += 64; gB += 64;
  __syncthreads();

  for (int kt = 0; kt < NT; ++kt) {
    const int cur = kt & 1;
    if (kt + 1 < NT) {
#pragma unroll
      for (int i = 0; i < 4; ++i) {
        gload16(gA + (size_t)(i * 8) * DMODEL, &As[cur ^ 1][(wid * 32 + i * 8) * 64]);
        gload16(gB + (size_t)(i * 8) * DMODEL, &Bs[cur ^ 1][(wid * 32 + i * 8) * 64]);
      }
      gA += 64; gB += 64;
    }
#pragma unroll
    for (int kp = 0; kp < 2; ++kp) {
      bf16x8 af[4], bfr[4];
#pragma unroll
      for (int i = 0; i < 4; ++i) {
        int ra = wr + i * 16 + fr;
        af[i]  = *(const bf16x8*)&As[cur][ra * 64 + (((kp * 4 + quad) ^ (ra & 7)) * 8)];
        int rb = wc + i * 16 + fr;
        bfr[i] = *(const bf16x8*)&Bs[cur][rb * 64 + (((kp * 4 + quad) ^ (rb & 7)) * 8)];
      }
#pragma unroll
      for (int i = 0; i < 4; ++i)
#pragma unroll
        for (int j = 0; j < 4; ++j)
          acc[i][j] = MFMA16(af[i], bfr[j], acc[i][j]);
    }
    __syncthreads();   // buf[cur] reads done; buf[cur^1] staging drained
  }

  // C/D layout: col = lane&15, row = (lane>>4)*4 + reg
#pragma unroll
  for (int i = 0; i < 4; ++i) {
    int row0 = m0 + wr + i * 16 + quad * 4;
#pragma unroll
    for (int j = 0; j < 4; ++j) {
      int col = n0 + wc + j * 16 + fr;
      float bv = bias[col];
      float v0 = (acc[i][j][0] + bv) * scale, v1 = (acc[i][j][1] + bv) * scale;
      float v2 = (acc[i][j][2] + bv) * scale, v3 = (acc[i][j][3] + bv) * scale;
      if (epi == 2) {
        float* C = (float*)Cout;
        C[(size_t)(row0 + 0) * DMODEL + col] = v0;
        C[(size_t)(row0 + 1) * DMODEL + col] = v1;
        C[(size_t)(row0 + 2) * DMODEL + col] = v2;
        C[(size_t)(row0 + 3) * DMODEL + col] = v3;
      } else if (epi == 0) {
        u16* C = (u16*)Cout;
        C[(size_t)(row0 + 0) * DMODEL + col] = f2bf(v0);
        C[(size_t)(row0 + 1) * DMODEL + col] = f2bf(v1);
        C[(size_t)(row0 + 2) * DMODEL + col] = f2bf(v2);
        C[(size_t)(row0 + 3) * DMODEL + col] = f2bf(v3);
      } else {
        u16* C = (u16*)Cout;
        int bi = row0 >> 11, s = row0 & 2047;
        // permuted s within 32-group: (b:1|c:2|r:2) -> (c:2|b:1|r:2)
        int sN = (s & ~31) | (((s >> 2) & 3) << 3) | (((s >> 4) & 1) << 2) | (s & 3);
        size_t vtr = ((size_t)(bi * NHEAD + (col >> 6)) * HDIM + (col & 63)) * SEQ + sN;
        *(uint2*)&C[vtr] = make_uint2(f2bf2(v0, v1), f2bf2(v2, v3));
      }
    }
  }
}

// single GEMM (Wo projections, final output)
__global__ __launch_bounds__(256, 2)
void gemm_bt(const u16* __restrict__ A, const u16* __restrict__ Bt,
             const float* __restrict__ bias, void* __restrict__ Cout,
             float scale, int epi)
{
  gemm_body<true>(A, Bt, bias, Cout, scale, epi, blockIdx.x);
}

// fused Q/K/V projections: 3 x 512 blocks; seg = bid>>9 picks operands (uniform)
__global__ __launch_bounds__(256, 2)
void gemm_qkv(const u16* __restrict__ Aq, const u16* __restrict__ Ak,
              const u16* __restrict__ Av, const u16* __restrict__ Btb,
              const float* __restrict__ bq, const float* __restrict__ bk,
              const float* __restrict__ bv, void* __restrict__ oq,
              void* __restrict__ ok, void* __restrict__ ov, float qscale)
{
  const int seg = blockIdx.x >> 9, inner = blockIdx.x & 511;
  const u16* A; const float* bias; void* Cout; float scale; int epi;
  if (seg == 0)      { A = Aq; bias = bq; Cout = oq; scale = qscale; epi = 0; }
  else if (seg == 1) { A = Ak; bias = bk; Cout = ok; scale = 1.0f;   epi = 0; }
  else               { A = Av; bias = bv; Cout = ov; scale = 1.0f;   epi = 1; }
  gemm_body<true>(A, Btb + (size_t)seg * NW, bias, Cout, scale, epi, inner);
}

// ---------------- flash attention v14 ----------------
// v13 + unroll-by-2 with compile-time CUR: all LDS addresses become hoisted bases
// + ds_read offset immediates (2 K-bases + 2 V-bases; db offsets fold into offset:N).
// Register pressure is low enough now (v13 shed lp/pa/epilogue temps) to avoid the
// round-7 spill. Split-K waves 2x2, swapped QK^T, zero-shuffle P, K=32 PV, MFMA
// row-sum. Causal: 1024 paired blocks. Cross: 2048 single-tile blocks (5/CU by LDS).

#define ATTN_STEP(CUR, TT)                                                      \
  do {                                                                          \
    const int kb_ = (TT) * 64;                                                  \
    if ((TT) + 1 < nsteps) {                                                    \
      gload16(kpre,              &KV[(CUR) ^ 1][(wid * 16 + 0) * 64]);          \
      gload16(kpre + 8 * DMODEL, &KV[(CUR) ^ 1][(wid * 16 + 8) * 64]);          \
      gload16(vpre,              &KV[2 + ((CUR) ^ 1)][(wid * 16 + 0) * 64]);    \
      gload16(vpre + 8 * SEQ,    &KV[2 + ((CUR) ^ 1)][(wid * 16 + 8) * 64]);    \
      kpre += 64 * DMODEL; vpre += 64;                                          \
    }                                                                           \
    const u16* kr_ = krb[(CUR)];                                                \
    f32x4 sa[2][2];                                                             \
    __builtin_amdgcn_s_setprio(1);                                              \
    {                                                                           \
      bf16x8 kfa = *(const bf16x8*)&kr_[xk0];                                   \
      bf16x8 kfb = *(const bf16x8*)&kr_[xk1];                                   \
      f32x4 s = {};                                                             \
      s = MFMA16(kfa, aq[0][0], s); s = MFMA16(kfb, aq[0][1], s); sa[0][0] = s; \
      s = (f32x4){};                                                            \
      s = MFMA16(kfa, aq[1][0], s); s = MFMA16(kfb, aq[1][1], s); sa[0][1] = s; \
      kfa = *(const bf16x8*)&kr_[16 * 64 + xk0];                                \
      kfb = *(const bf16x8*)&kr_[16 * 64 + xk1];                                \
      s = (f32x4){};                                                            \
      s = MFMA16(kfa, aq[0][0], s); s = MFMA16(kfb, aq[0][1], s); sa[1][0] = s; \
      s = (f32x4){};                                                            \
      s = MFMA16(kfa, aq[1][0], s); s = MFMA16(kfb, aq[1][1], s); sa[1][1] = s; \
    }                                                                           \
    __builtin_amdgcn_s_setprio(0);                                              \
    if (causal && kb_ + wk * 32 + 31 > qbase) {                                 \
      _Pragma("unroll")                                                         \
      for (int kblk = 0; kblk < 2; ++kblk)                                      \
        _Pragma("unroll")                                                       \
        for (int nb = 0; nb < 2; ++nb) {                                        \
          int key = kb_ + wk * 32 + kblk * 16 + quad * 4;                       \
          int q   = qbase + nb * 16 + fr;                                       \
          _Pragma("unroll")                                                     \
          for (int r = 0; r < 4; ++r)                                           \
            if (key + r > q) sa[kblk][nb][r] = MASKV;                           \
        }                                                                       \
    }                                                                           \
    float lm[2];                                                                \
    _Pragma("unroll")                                                           \
    for (int nb = 0; nb < 2; ++nb) {                                            \
      float m1 = max3f(sa[0][nb][0], sa[0][nb][1], sa[0][nb][2]);               \
      float m2 = max3f(sa[0][nb][3], sa[1][nb][0], sa[1][nb][1]);               \
      float m3 = max3f(sa[1][nb][2], sa[1][nb][3], m1);                         \
      lm[nb] = fmaxf(m2, m3);                                                   \
    }                                                                           \
    int ok = (lm[0] <= mrow[0] + 11.f) & (lm[1] <= mrow[1] + 11.f);             \
    if (!__all(ok)) {                                                           \
      _Pragma("unroll")                                                         \
      for (int nb = 0; nb < 2; ++nb) {                                          \
        float mx = lm[nb];                                                      \
        mx = fmaxf(mx, __shfl_xor(mx, 16));                                     \
        mx = fmaxf(mx, __shfl_xor(mx, 32));                                     \
        float mnew = fmaxf(mrow[nb], mx);                                       \
        float a = __builtin_amdgcn_exp2f(mrow[nb] - mnew);                      \
        mrow[nb] = mnew;                                                        \
        _Pragma("unroll")                                                       \
        for (int r = 0; r < 4; ++r) {                                           \
          float ar = __shfl(a, (lane & 48) | (quad * 4 + r));                   \
          oacc[nb][0][r] *= ar; oacc[nb][1][r] *= ar;                           \
          oacc[nb][2][r] *= ar; oacc[nb][3][r] *= ar;                           \
          oaccl[nb][r]   *= ar;                                                 \
        }                                                                       \
      }                                                                         \
    }                                                                           \
    bf16x8 pa32[2];                                                             \
    _Pragma("unroll")                                                           \
    for (int nb = 0; nb < 2; ++nb) {                                            \
      u32x4 pw;                                                                 \
      _Pragma("unroll")                                                         \
      for (int kblk = 0; kblk < 2; ++kblk) {                                    \
        float p0 = __builtin_amdgcn_exp2f(sa[kblk][nb][0] - mrow[nb]);          \
        float p1 = __builtin_amdgcn_exp2f(sa[kblk][nb][1] - mrow[nb]);          \
        float p2 = __builtin_amdgcn_exp2f(sa[kblk][nb][2] - mrow[nb]);          \
        float p3 = __builtin_amdgcn_exp2f(sa[kblk][nb][3] - mrow[nb]);          \
        pw[kblk * 2 + 0] = f2bf2(p0, p1);                                       \
        pw[kblk * 2 + 1] = f2bf2(p2, p3);                                       \
      }                                                                         \
      pa32[nb] = __builtin_bit_cast(bf16x8, pw);                                \
    }                                                                           \
    __builtin_amdgcn_s_setprio(1);                                              \
    oaccl[0] = MFMA16(pa32[0], vones, oaccl[0]);                                \
    oaccl[1] = MFMA16(pa32[1], vones, oaccl[1]);                                \
    {                                                                           \
      const u16* vr_ = vrb[(CUR)];                                              \
      _Pragma("unroll")                                                         \
      for (int db = 0; db < 4; ++db) {                                          \
        bf16x8 vv = *(const bf16x8*)&vr_[db * 16 * 64];                         \
        oacc[0][db] = MFMA16(pa32[0], vv, oacc[0][db]);                         \
        oacc[1][db] = MFMA16(pa32[1], vv, oacc[1][db]);                         \
      }                                                                         \
    }                                                                           \
    __builtin_amdgcn_s_setprio(0);                                              \
    __syncthreads();                                                            \
  } while (0)

__global__ __launch_bounds__(256, 4)
void attn_kernel(const u16* __restrict__ Q, const u16* __restrict__ K,
                 const u16* __restrict__ Vt, u16* __restrict__ O, int causal)
{
  __shared__ u16 KV[4][64 * 64];   // [0,1]=K dbuf, [2,3]=V dbuf; merge reuses as f32
  const int lane = threadIdx.x & 63, wid = threadIdx.x >> 6;
  const int fr = lane & 15, quad = lane >> 4;
  const int wq = wid >> 1, wk = wid & 1;

  const int flat = blockIdx.x;
  int bh, qb0, qb1, ntiles;
  if (causal) {                     // [bh_hi:3][pair:4][xcd:3]
    bh = ((flat >> 7) << 3) | (flat & 7);
    const int pair = (flat >> 3) & 15;
    qb0 = 31 - pair; qb1 = pair; ntiles = 2;
  } else {                          // [bh_hi:3][qb:5][xcd:3]
    bh = ((flat >> 8) << 3) | (flat & 7);
    qb0 = (flat >> 3) & 31; qb1 = 0; ntiles = 1;
  }
  const int b = bh >> 4, h = bh & 15;

  // constant all-ones B-frag (bf16 1.0 = 0x3F80)
  const short one = (short)0x3F80;
  const bf16x8 vones = {one, one, one, one, one, one, one, one};

  // loop-invariant swizzled LDS element offsets + hoisted per-buffer bases
  const int xk0 = ((quad    ) ^ (fr & 7)) * 8;
  const int xk1 = ((quad + 4) ^ (fr & 7)) * 8;
  const int xv  = ((wk * 4 + quad) ^ (fr & 7)) * 8;
  const u16* krb[2] = { &KV[0][(wk * 32 + fr) * 64], &KV[1][(wk * 32 + fr) * 64] };
  const u16* vrb[2] = { &KV[2][fr * 64 + xv],        &KV[3][fr * 64 + xv] };

  const int srow = wid * 16 + (lane >> 3);
  const int jg = (lane & 7) ^ (srow & 7);   // same for srow and srow+8
  const u16* kg = K + (size_t)b * SEQ * DMODEL + h * HDIM;
  const u16* vg = Vt + (size_t)bh * HDIM * SEQ;
  const u16* ks0 = kg + (size_t)srow * DMODEL + jg * 8;
  const u16* vs0 = vg + (size_t)srow * SEQ + jg * 8;
  float* mbuf = (float*)&KV[0][0];          // merge scratch (25.6KB < 32KB)

  for (int tile = 0; tile < ntiles; ++tile) {
    const int qb = tile == 0 ? qb0 : qb1;
    const int q0 = qb * 64;
    const int qbase = q0 + wq * 32;

    bf16x8 aq[2][2];
#pragma unroll
    for (int nb = 0; nb < 2; ++nb) {
      const u16* qp = Q + (size_t)(b * SEQ + qbase + nb * 16 + fr) * DMODEL + h * HDIM + quad * 8;
      aq[nb][0] = *(const bf16x8*)qp;
      aq[nb][1] = *(const bf16x8*)(qp + 32);
    }

    f32x4 oacc[2][4] = {};
    f32x4 oaccl[2] = {};              // MFMA-accumulated row sums (replicated cols)
    float mrow[2] = {-1e30f, -1e30f};

    const int nsteps = (causal ? (q0 + 64) : SEQ) >> 6;

    // prologue: stage tile 0 into bufs {0, 2}
    gload16(ks0,              &KV[0][(wid * 16 + 0) * 64]);
    gload16(ks0 + 8 * DMODEL, &KV[0][(wid * 16 + 8) * 64]);
    gload16(vs0,              &KV[2][(wid * 16 + 0) * 64]);
    gload16(vs0 + 8 * SEQ,    &KV[2][(wid * 16 + 8) * 64]);
    const u16* kpre = ks0 + 64 * DMODEL;
    const u16* vpre = vs0 + 64;
    __syncthreads();

    int t = 0;
    while (t + 2 <= nsteps) {
      ATTN_STEP(0, t);
      ATTN_STEP(1, t + 1);
      t += 2;
    }
    if (t < nsteps) ATTN_STEP(0, t);

    // ---- tile epilogue: 2-way split-K merge across wk (l free from oaccl) ----
    float mr2[2][4];
#pragma unroll
    for (int nb = 0; nb < 2; ++nb)
#pragma unroll
      for (int r = 0; r < 4; ++r) {
        int src = (lane & 48) | (quad * 4 + r);
        mr2[nb][r] = __shfl(mrow[nb], src);
      }
    float* mp = mbuf + (size_t)(wq * 64 + lane) * 50;
    if (wk) {
#pragma unroll
      for (int nb = 0; nb < 2; ++nb)
#pragma unroll
        for (int db = 0; db < 4; ++db) {
          *(float2*)&mp[(nb * 4 + db) * 4 + 0] = make_float2(oacc[nb][db][0], oacc[nb][db][1]);
          *(float2*)&mp[(nb * 4 + db) * 4 + 2] = make_float2(oacc[nb][db][2], oacc[nb][db][3]);
        }
#pragma unroll
      for (int nb = 0; nb < 2; ++nb) {
        *(float2*)&mp[32 + nb * 4 + 0] = make_float2(mr2[nb][0], mr2[nb][1]);
        *(float2*)&mp[32 + nb * 4 + 2] = make_float2(mr2[nb][2], mr2[nb][3]);
        *(float2*)&mp[40 + nb * 4 + 0] = make_float2(oaccl[nb][0], oaccl[nb][1]);
        *(float2*)&mp[40 + nb * 4 + 2] = make_float2(oaccl[nb][2], oaccl[nb][3]);
      }
    }
    __syncthreads();
    if (!wk) {
      float w0[2][4], w1[2][4];
#pragma unroll
      for (int nb = 0; nb < 2; ++nb)
#pragma unroll
        for (int r = 0; r < 4; ++r) {
          float m1 = mp[32 + nb * 4 + r];
          float l1 = mp[40 + nb * 4 + r];
          float M  = fmaxf(mr2[nb][r], m1);
          float c0 = __builtin_amdgcn_exp2f(mr2[nb][r] - M);
          float c1 = __builtin_amdgcn_exp2f(m1 - M);
          float inv = 1.0f / (oaccl[nb][r] * c0 + l1 * c1);
          w0[nb][r] = c0 * inv;
          w1[nb][r] = c1 * inv;
        }
#pragma unroll
      for (int nb = 0; nb < 2; ++nb) {
        u16* op = O + (size_t)(b * SEQ + qbase + nb * 16 + quad * 4) * DMODEL + h * HDIM + fr;
#pragma unroll
        for (int db = 0; db < 4; ++db) {
          float2 oa = *(float2*)&mp[(nb * 4 + db) * 4 + 0];
          float2 ob = *(float2*)&mp[(nb * 4 + db) * 4 + 2];
          float o1[4] = {oa.x, oa.y, ob.x, ob.y};
#pragma unroll
          for (int r = 0; r < 4; ++r)
            op[(size_t)r * DMODEL + db * 16] =
                f2bf(oacc[nb][db][r] * w0[nb][r] + o1[r] * w1[nb][r]);
        }
      }
    }
    __syncthreads();   // merge reads done before next tile's staging reuses KV
  }
}

// ---------------- launcher ----------------
extern "C" void kernel_launch(void* const* d_in, const int* in_sizes, int n_in,
                              void* d_out, int out_size, void* d_ws, size_t ws_size,
                              hipStream_t stream)
{
  const float* x   = (const float*)d_in[0];
  const float* ek  = (const float*)d_in[1];
  const float* ev  = (const float*)d_in[2];
  const float* Wq1 = (const float*)d_in[3];
  const float* bq1 = (const float*)d_in[4];
  const float* Wk1 = (const float*)d_in[5];
  const float* bk1 = (const float*)d_in[6];
  const float* Wv1 = (const float*)d_in[7];
  const float* bv1 = (const float*)d_in[8];
  const float* Wo1 = (const float*)d_in[9];
  const float* bo1 = (const float*)d_in[10];
  const float* Wq2 = (const float*)d_in[11];
  const float* bq2 = (const float*)d_in[12];
  const float* Wk2 = (const float*)d_in[13];
  const float* bk2 = (const float*)d_in[14];
  const float* Wv2 = (const float*)d_in[15];
  const float* bv2 = (const float*)d_in[16];
  const float* Wo2 = (const float*)d_in[17];
  const float* bo2 = (const float*)d_in[18];

  char* ws = (char*)d_ws;
  u16* wt  = (u16*)ws;
  u16* xb  = (u16*)(ws + (16u << 20));
  u16* ekb = (u16*)(ws + (32u << 20));
  u16* evb = (u16*)(ws + (48u << 20));
  u16* qb  = (u16*)(ws + (64u << 20));
  u16* kkb = (u16*)(ws + (80u << 20));
  u16* vtb = (u16*)(ws + (96u << 20));
  u16* hb  = (u16*)(ws + (112u << 20));
  u16* ob  = xb;   // x dead after layer-1 projections

  const int n4 = MTOT * DMODEL / 4;
  const float qscale = 0.125f * 1.4426950408889634f;   // 1/sqrt(HD) * log2(e)

  pack_act3<<<dim3(n4 / 256, 3), 256, 0, stream>>>(x, ek, ev, xb, ekb, evb, n4);
  pack_w8<<<dim3(16, 16, 8), 256, 0, stream>>>(Wq1, Wk1, Wv1, Wo1, Wq2, Wk2, Wv2, Wo2, wt);

  const int gblocks = (MTOT / 128) * (DMODEL / 128);   // 512, XCD-swizzled in-kernel
  const int ablocks_causal = (SEQ / 128) * BSZ * NHEAD; // 1024 pair-blocks
  const int ablocks_cross  = (SEQ / 64) * BSZ * NHEAD;  // 2048 single-tile blocks

  // layer 1: causal self-attention
  gemm_qkv<<<3 * gblocks, 256, 0, stream>>>(xb, xb, xb, wt, bq1, bk1, bv1,
                                            qb, kkb, vtb, qscale);
  attn_kernel<<<ablocks_causal, 256, 0, stream>>>(qb, kkb, vtb, ob, 1);
  gemm_bt<<<gblocks, 256, 0, stream>>>(ob, wt + 3 * NW, bo1, hb, 1.0f, 0);

  // layer 2: cross attention
  gemm_qkv<<<3 * gblocks, 256, 0, stream>>>(hb, ekb, evb, wt + 4 * NW, bq2, bk2, bv2,
                                            qb, kkb, vtb, qscale);
  attn_kernel<<<ablocks_cross, 256, 0, stream>>>(qb, kkb, vtb, ob, 0);
  gemm_bt<<<gblocks, 256, 0, stream>>>(ob, wt + 7 * NW, bo2, d_out, 1.0f, 2);
}